// Round 1
// baseline (2397.765 us; speedup 1.0000x reference)
//
#include <hip/hip_runtime.h>

#define BN_EPS 1e-5f

// ---------------- CSR build ----------------
__global__ void k_count(const int* __restrict__ dst, int* __restrict__ counts, int E) {
  int stride = gridDim.x * blockDim.x;
  for (int e = blockIdx.x * blockDim.x + threadIdx.x; e < E; e += stride)
    atomicAdd(&counts[dst[e]], 1);
}

// 1024 elements per block, 256 threads, 4 elems/thread. Exclusive scan within block.
__global__ void k_scan_blocks(const int* __restrict__ in, int* __restrict__ out,
                              int* __restrict__ partials, int n) {
  __shared__ int sdata[256];
  int tid = threadIdx.x;
  int base = blockIdx.x * 1024 + tid * 4;
  int v0 = 0, v1 = 0, v2 = 0, v3 = 0;
  if (base + 0 < n) v0 = in[base + 0];
  if (base + 1 < n) v1 = in[base + 1];
  if (base + 2 < n) v2 = in[base + 2];
  if (base + 3 < n) v3 = in[base + 3];
  int s = v0 + v1 + v2 + v3;
  sdata[tid] = s;
  __syncthreads();
  for (int off = 1; off < 256; off <<= 1) {
    int t = (tid >= off) ? sdata[tid - off] : 0;
    __syncthreads();
    sdata[tid] += t;
    __syncthreads();
  }
  int excl = sdata[tid] - s;
  if (base + 0 < n) out[base + 0] = excl;
  if (base + 1 < n) out[base + 1] = excl + v0;
  if (base + 2 < n) out[base + 2] = excl + v0 + v1;
  if (base + 3 < n) out[base + 3] = excl + v0 + v1 + v2;
  if (tid == 0) partials[blockIdx.x] = sdata[255];
}

__global__ void k_scan_partials(int* __restrict__ p, int nb) {
  __shared__ int sdata[128];
  int tid = threadIdx.x;
  int v = (tid < nb) ? p[tid] : 0;
  sdata[tid] = v;
  __syncthreads();
  for (int off = 1; off < 128; off <<= 1) {
    int t = (tid >= off) ? sdata[tid - off] : 0;
    __syncthreads();
    sdata[tid] += t;
    __syncthreads();
  }
  if (tid < nb) p[tid] = sdata[tid] - v;
}

__global__ void k_scan_add(int* __restrict__ out, const int* __restrict__ partials,
                           int n, int total) {
  int tid = threadIdx.x;
  int base = blockIdx.x * 1024 + tid * 4;
  int add = partials[blockIdx.x];
  if (base + 0 < n) out[base + 0] += add;
  if (base + 1 < n) out[base + 1] += add;
  if (base + 2 < n) out[base + 2] += add;
  if (base + 3 < n) out[base + 3] += add;
  if (blockIdx.x == 0 && tid == 0) out[n] = total;
}

__global__ void k_scatter(const int* __restrict__ src, const int* __restrict__ dst,
                          const int* __restrict__ row_ptr, int* __restrict__ cursor,
                          int* __restrict__ csr, int E) {
  int stride = gridDim.x * blockDim.x;
  for (int e = blockIdx.x * blockDim.x + threadIdx.x; e < E; e += stride) {
    int d = dst[e];
    int p = row_ptr[d] + atomicAdd(&cursor[d], 1);
    csr[p] = src[e];
  }
}

// ---------------- dual GEMM: T = A@Wl, R = A@Wr + b ----------------
// A [n,128], W [128,128]. Block: 256 thr, 64 rows. thread: 8 rows x 4 cols per matrix.
__global__ __launch_bounds__(256) void k_gemm_dual(
    const float* __restrict__ A, const float* __restrict__ Wl,
    const float* __restrict__ Wr, const float* __restrict__ bias,
    float* __restrict__ T, float* __restrict__ R, int nrows) {
  __shared__ float As[64 * 128];
  int tid = threadIdx.x;
  int row0 = blockIdx.x * 64;
  // stage A tile (zero-fill OOB rows)
  #pragma unroll
  for (int i = 0; i < 8; i++) {
    int f4 = tid + i * 256;       // 0..2047 float4 slots
    int r = f4 >> 5;              // 32 float4 per row
    int c4 = f4 & 31;
    float4 v = make_float4(0.f, 0.f, 0.f, 0.f);
    if (row0 + r < nrows) v = *(const float4*)(A + (size_t)(row0 + r) * 128 + c4 * 4);
    *(float4*)(As + f4 * 4) = v;
  }
  __syncthreads();

  int cg = tid & 31;   // 32 col groups * 4 cols
  int rg = tid >> 5;   // 8 row groups * 8 rows
  const float* As_base = As + rg * 8 * 128;
  float accL[8][4] = {}, accR[8][4] = {};

  for (int k0 = 0; k0 < 128; k0 += 4) {
    float4 a4[8];
    #pragma unroll
    for (int i = 0; i < 8; i++) a4[i] = *(const float4*)(As_base + i * 128 + k0);
    float4 wl[4], wr[4];
    #pragma unroll
    for (int kk = 0; kk < 4; kk++) {
      wl[kk] = *(const float4*)(Wl + (k0 + kk) * 128 + cg * 4);
      wr[kk] = *(const float4*)(Wr + (k0 + kk) * 128 + cg * 4);
    }
    #pragma unroll
    for (int kk = 0; kk < 4; kk++) {
      #pragma unroll
      for (int i = 0; i < 8; i++) {
        float a = (kk == 0) ? a4[i].x : (kk == 1) ? a4[i].y : (kk == 2) ? a4[i].z : a4[i].w;
        accL[i][0] += a * wl[kk].x; accL[i][1] += a * wl[kk].y;
        accL[i][2] += a * wl[kk].z; accL[i][3] += a * wl[kk].w;
        accR[i][0] += a * wr[kk].x; accR[i][1] += a * wr[kk].y;
        accR[i][2] += a * wr[kk].z; accR[i][3] += a * wr[kk].w;
      }
    }
  }

  float4 bv = *(const float4*)(bias + cg * 4);
  #pragma unroll
  for (int i = 0; i < 8; i++) {
    int r = row0 + rg * 8 + i;
    if (r < nrows) {
      float4 o = make_float4(accL[i][0], accL[i][1], accL[i][2], accL[i][3]);
      *(float4*)(T + (size_t)r * 128 + cg * 4) = o;
      float4 p = make_float4(accR[i][0] + bv.x, accR[i][1] + bv.y,
                             accR[i][2] + bv.z, accR[i][3] + bv.w);
      *(float4*)(R + (size_t)r * 128 + cg * 4) = p;
    }
  }
}

// ---------------- aggregate: Out[i] = R[i] + mean_{j in N(i)} T[j]; BN partial stats ----------------
__global__ __launch_bounds__(256) void k_aggregate(
    const float* __restrict__ T, const float* __restrict__ R,
    float* __restrict__ Out, const int* __restrict__ row_ptr,
    const int* __restrict__ csr, const int* __restrict__ counts,
    float* __restrict__ stats, int n) {
  int lane = threadIdx.x & 63;
  int wid = (blockIdx.x * blockDim.x + threadIdx.x) >> 6;
  int nw = (gridDim.x * blockDim.x) >> 6;
  float2 csum = make_float2(0.f, 0.f), csq = make_float2(0.f, 0.f);
  for (int i = wid; i < n; i += nw) {
    int beg = row_ptr[i], end = row_ptr[i + 1];
    float ax = 0.f, ay = 0.f;
    for (int e = beg; e < end; e++) {
      int j = csr[e];
      float2 v = *(const float2*)(T + (size_t)j * 128 + lane * 2);
      ax += v.x; ay += v.y;
    }
    float inv = 1.0f / fmaxf((float)counts[i], 1.0f);
    float2 rv = *(const float2*)(R + (size_t)i * 128 + lane * 2);
    float hx = rv.x + ax * inv;
    float hy = rv.y + ay * inv;
    *(float2*)(Out + (size_t)i * 128 + lane * 2) = make_float2(hx, hy);
    csum.x += hx; csum.y += hy;
    csq.x += hx * hx; csq.y += hy * hy;
  }
  atomicAdd(&stats[lane * 2 + 0], csum.x);
  atomicAdd(&stats[lane * 2 + 1], csum.y);
  atomicAdd(&stats[128 + lane * 2 + 0], csq.x);
  atomicAdd(&stats[128 + lane * 2 + 1], csq.y);
}

// ---------------- BN + ReLU (in place) ----------------
__global__ __launch_bounds__(256) void k_bn_relu(
    float* __restrict__ H, const float* __restrict__ stats,
    const float* __restrict__ gamma, const float* __restrict__ beta, int n) {
  __shared__ float sc[128], sh[128];
  int tid = threadIdx.x;
  if (tid < 128) {
    float invn = 1.0f / (float)n;
    float mu = stats[tid] * invn;
    float var = stats[128 + tid] * invn - mu * mu;
    float s = rsqrtf(var + BN_EPS) * gamma[tid];
    sc[tid] = s;
    sh[tid] = beta[tid] - mu * s;
  }
  __syncthreads();
  size_t total4 = (size_t)n * 32;
  size_t stride = (size_t)gridDim.x * blockDim.x;
  for (size_t idx = blockIdx.x * (size_t)blockDim.x + tid; idx < total4; idx += stride) {
    float4 v = ((const float4*)H)[idx];
    int c = ((int)(idx & 31)) * 4;
    v.x = fmaxf(v.x * sc[c + 0] + sh[c + 0], 0.f);
    v.y = fmaxf(v.y * sc[c + 1] + sh[c + 1], 0.f);
    v.z = fmaxf(v.z * sc[c + 2] + sh[c + 2], 0.f);
    v.w = fmaxf(v.w * sc[c + 3] + sh[c + 3], 0.f);
    ((float4*)H)[idx] = v;
  }
}

// ---------------- final GEMM: Out = A @ Wout + bout, [n,128]x[128,32] ----------------
__global__ __launch_bounds__(256) void k_gemm_out(
    const float* __restrict__ A, const float* __restrict__ W,
    const float* __restrict__ bias, float* __restrict__ Out, int nrows) {
  __shared__ float As[64 * 132];
  int tid = threadIdx.x;
  int row0 = blockIdx.x * 64;
  #pragma unroll
  for (int i = 0; i < 8; i++) {
    int f4 = tid + i * 256;
    int r = f4 >> 5;
    int c4 = f4 & 31;
    float4 v = make_float4(0.f, 0.f, 0.f, 0.f);
    if (row0 + r < nrows) v = *(const float4*)(A + (size_t)(row0 + r) * 128 + c4 * 4);
    *(float4*)(As + r * 132 + c4 * 4) = v;
  }
  __syncthreads();

  int cg = tid & 7;    // 8 col groups * 4 = 32 cols
  int rg = tid >> 3;   // 32 row groups * 2 rows
  float acc[2][4] = {};
  for (int k = 0; k < 128; k++) {
    float4 w = *(const float4*)(W + k * 32 + cg * 4);
    float a0 = As[(rg * 2 + 0) * 132 + k];
    float a1 = As[(rg * 2 + 1) * 132 + k];
    acc[0][0] += a0 * w.x; acc[0][1] += a0 * w.y; acc[0][2] += a0 * w.z; acc[0][3] += a0 * w.w;
    acc[1][0] += a1 * w.x; acc[1][1] += a1 * w.y; acc[1][2] += a1 * w.z; acc[1][3] += a1 * w.w;
  }
  float4 bv = *(const float4*)(bias + cg * 4);
  #pragma unroll
  for (int i = 0; i < 2; i++) {
    int r = row0 + rg * 2 + i;
    if (r < nrows) {
      float4 o = make_float4(acc[i][0] + bv.x, acc[i][1] + bv.y,
                             acc[i][2] + bv.z, acc[i][3] + bv.w);
      *(float4*)(Out + (size_t)r * 32 + cg * 4) = o;
    }
  }
}

extern "C" void kernel_launch(void* const* d_in, const int* in_sizes, int n_in,
                              void* d_out, int out_size, void* d_ws, size_t ws_size,
                              hipStream_t stream) {
  const float* x    = (const float*)d_in[0];
  const int*   e_sp = (const int*)d_in[1];
  const int*   e_tp = (const int*)d_in[2];
  const float* Wl[4]  = {(const float*)d_in[3],  (const float*)d_in[8],
                         (const float*)d_in[13], (const float*)d_in[18]};
  const float* Wr[4]  = {(const float*)d_in[4],  (const float*)d_in[9],
                         (const float*)d_in[14], (const float*)d_in[19]};
  const float* bb[4]  = {(const float*)d_in[5],  (const float*)d_in[10],
                         (const float*)d_in[15], (const float*)d_in[20]};
  const float* gm[4]  = {(const float*)d_in[6],  (const float*)d_in[11],
                         (const float*)d_in[16], (const float*)d_in[21]};
  const float* bt[4]  = {(const float*)d_in[7],  (const float*)d_in[12],
                         (const float*)d_in[17], (const float*)d_in[22]};
  const float* Wout = (const float*)d_in[23];
  const float* bout = (const float*)d_in[24];

  const int N = in_sizes[0] / 128;
  const int E = in_sizes[1] / 2;

  char* ws = (char*)d_ws;
  size_t off = 0;
  auto alloc = [&](size_t bytes) {
    void* p = ws + off;
    off += (bytes + 255) & ~(size_t)255;
    return p;
  };
  float* A = (float*)alloc((size_t)N * 128 * 4);
  float* B = (float*)alloc((size_t)N * 128 * 4);   // t = h @ Wl
  float* C = (float*)alloc((size_t)N * 128 * 4);   // r = h @ Wr + b
  int* counts_sp = (int*)alloc((size_t)N * 4);
  int* counts_tp = (int*)alloc((size_t)N * 4);
  int* row_sp    = (int*)alloc((size_t)(N + 1) * 4);
  int* row_tp    = (int*)alloc((size_t)(N + 1) * 4);
  int* cursor    = (int*)alloc((size_t)N * 4);
  int* csr_sp    = (int*)alloc((size_t)E * 4);
  int* csr_tp    = (int*)alloc((size_t)E * 4);
  int* partials  = (int*)alloc(128 * 4);
  float* stats   = (float*)alloc(256 * 4);

  const int nb = (N + 1023) / 1024;

  // ---- build CSR (spatial) ----
  hipMemsetAsync(counts_sp, 0, (size_t)N * 4, stream);
  k_count<<<1024, 256, 0, stream>>>(e_sp + E, counts_sp, E);
  k_scan_blocks<<<nb, 256, 0, stream>>>(counts_sp, row_sp, partials, N);
  k_scan_partials<<<1, 128, 0, stream>>>(partials, nb);
  k_scan_add<<<nb, 256, 0, stream>>>(row_sp, partials, N, E);
  hipMemsetAsync(cursor, 0, (size_t)N * 4, stream);
  k_scatter<<<1024, 256, 0, stream>>>(e_sp, e_sp + E, row_sp, cursor, csr_sp, E);

  // ---- build CSR (temporal) ----
  hipMemsetAsync(counts_tp, 0, (size_t)N * 4, stream);
  k_count<<<1024, 256, 0, stream>>>(e_tp + E, counts_tp, E);
  k_scan_blocks<<<nb, 256, 0, stream>>>(counts_tp, row_tp, partials, N);
  k_scan_partials<<<1, 128, 0, stream>>>(partials, nb);
  k_scan_add<<<nb, 256, 0, stream>>>(row_tp, partials, N, E);
  hipMemsetAsync(cursor, 0, (size_t)N * 4, stream);
  k_scatter<<<1024, 256, 0, stream>>>(e_tp, e_tp + E, row_tp, cursor, csr_tp, E);

  const int* rowp[4] = {row_sp, row_sp, row_tp, row_tp};
  const int* csr[4]  = {csr_sp, csr_sp, csr_tp, csr_tp};
  const int* cnts[4] = {counts_sp, counts_sp, counts_tp, counts_tp};

  const int gblocks = (N + 63) / 64;
  const float* cur = x;
  for (int l = 0; l < 4; l++) {
    k_gemm_dual<<<gblocks, 256, 0, stream>>>(cur, Wl[l], Wr[l], bb[l], B, C, N);
    hipMemsetAsync(stats, 0, 256 * 4, stream);
    k_aggregate<<<1024, 256, 0, stream>>>(B, C, A, rowp[l], csr[l], cnts[l], stats, N);
    k_bn_relu<<<2048, 256, 0, stream>>>(A, stats, gm[l], bt[l], N);
    cur = A;
  }
  k_gemm_out<<<gblocks, 256, 0, stream>>>(A, Wout, bout, (float*)d_out, N);
}

// Round 2
// 1264.887 us; speedup vs baseline: 1.8956x; 1.8956x over previous
//
#include <hip/hip_runtime.h>

#define BN_EPS 1e-5f

__device__ inline unsigned short f2bf(float x) {
  unsigned int u = __float_as_uint(x);
  u += 0x7fffu + ((u >> 16) & 1u);
  return (unsigned short)(u >> 16);
}
__device__ inline float bflo(unsigned int v) { return __uint_as_float(v << 16); }
__device__ inline float bfhi(unsigned int v) { return __uint_as_float(v & 0xffff0000u); }

// ---------------- CSR build ----------------
__global__ void k_count(const int* __restrict__ dst, int* __restrict__ counts, int E) {
  int stride = gridDim.x * blockDim.x;
  for (int e = blockIdx.x * blockDim.x + threadIdx.x; e < E; e += stride)
    atomicAdd(&counts[dst[e]], 1);
}

__global__ void k_scan_blocks(const int* __restrict__ in, int* __restrict__ out,
                              int* __restrict__ partials, int n) {
  __shared__ int sdata[256];
  int tid = threadIdx.x;
  int base = blockIdx.x * 1024 + tid * 4;
  int v0 = 0, v1 = 0, v2 = 0, v3 = 0;
  if (base + 0 < n) v0 = in[base + 0];
  if (base + 1 < n) v1 = in[base + 1];
  if (base + 2 < n) v2 = in[base + 2];
  if (base + 3 < n) v3 = in[base + 3];
  int s = v0 + v1 + v2 + v3;
  sdata[tid] = s;
  __syncthreads();
  for (int off = 1; off < 256; off <<= 1) {
    int t = (tid >= off) ? sdata[tid - off] : 0;
    __syncthreads();
    sdata[tid] += t;
    __syncthreads();
  }
  int excl = sdata[tid] - s;
  if (base + 0 < n) out[base + 0] = excl;
  if (base + 1 < n) out[base + 1] = excl + v0;
  if (base + 2 < n) out[base + 2] = excl + v0 + v1;
  if (base + 3 < n) out[base + 3] = excl + v0 + v1 + v2;
  if (tid == 0) partials[blockIdx.x] = sdata[255];
}

__global__ void k_scan_partials(int* __restrict__ p, int nb) {
  __shared__ int sdata[128];
  int tid = threadIdx.x;
  int v = (tid < nb) ? p[tid] : 0;
  sdata[tid] = v;
  __syncthreads();
  for (int off = 1; off < 128; off <<= 1) {
    int t = (tid >= off) ? sdata[tid - off] : 0;
    __syncthreads();
    sdata[tid] += t;
    __syncthreads();
  }
  if (tid < nb) p[tid] = sdata[tid] - v;
}

__global__ void k_scan_add(int* __restrict__ out, const int* __restrict__ partials,
                           int n, int total) {
  int tid = threadIdx.x;
  int base = blockIdx.x * 1024 + tid * 4;
  int add = partials[blockIdx.x];
  if (base + 0 < n) out[base + 0] += add;
  if (base + 1 < n) out[base + 1] += add;
  if (base + 2 < n) out[base + 2] += add;
  if (base + 3 < n) out[base + 3] += add;
  if (blockIdx.x == 0 && tid == 0) out[n] = total;
}

__global__ void k_scatter(const int* __restrict__ src, const int* __restrict__ dst,
                          const int* __restrict__ row_ptr, int* __restrict__ cursor,
                          int* __restrict__ csr, int E) {
  int stride = gridDim.x * blockDim.x;
  for (int e = blockIdx.x * blockDim.x + threadIdx.x; e < E; e += stride) {
    int d = dst[e];
    int p = row_ptr[d] + atomicAdd(&cursor[d], 1);
    csr[p] = src[e];
  }
}

// ---------------- dual GEMM: Tb(bf16) = A@Wl, R(f32) = A@Wr + b ----------------
__global__ __launch_bounds__(256) void k_gemm_dual(
    const float* __restrict__ A, const float* __restrict__ Wl,
    const float* __restrict__ Wr, const float* __restrict__ bias,
    unsigned short* __restrict__ Tb, float* __restrict__ R, int nrows) {
  __shared__ float As[64 * 128];
  int tid = threadIdx.x;
  int row0 = blockIdx.x * 64;
  #pragma unroll
  for (int i = 0; i < 8; i++) {
    int f4 = tid + i * 256;
    int r = f4 >> 5;
    int c4 = f4 & 31;
    float4 v = make_float4(0.f, 0.f, 0.f, 0.f);
    if (row0 + r < nrows) v = *(const float4*)(A + (size_t)(row0 + r) * 128 + c4 * 4);
    *(float4*)(As + f4 * 4) = v;
  }
  __syncthreads();

  int cg = tid & 31;
  int rg = tid >> 5;
  const float* As_base = As + rg * 8 * 128;
  float accL[8][4] = {}, accR[8][4] = {};

  for (int k0 = 0; k0 < 128; k0 += 4) {
    float4 a4[8];
    #pragma unroll
    for (int i = 0; i < 8; i++) a4[i] = *(const float4*)(As_base + i * 128 + k0);
    float4 wl[4], wr[4];
    #pragma unroll
    for (int kk = 0; kk < 4; kk++) {
      wl[kk] = *(const float4*)(Wl + (k0 + kk) * 128 + cg * 4);
      wr[kk] = *(const float4*)(Wr + (k0 + kk) * 128 + cg * 4);
    }
    #pragma unroll
    for (int kk = 0; kk < 4; kk++) {
      #pragma unroll
      for (int i = 0; i < 8; i++) {
        float a = (kk == 0) ? a4[i].x : (kk == 1) ? a4[i].y : (kk == 2) ? a4[i].z : a4[i].w;
        accL[i][0] += a * wl[kk].x; accL[i][1] += a * wl[kk].y;
        accL[i][2] += a * wl[kk].z; accL[i][3] += a * wl[kk].w;
        accR[i][0] += a * wr[kk].x; accR[i][1] += a * wr[kk].y;
        accR[i][2] += a * wr[kk].z; accR[i][3] += a * wr[kk].w;
      }
    }
  }

  float4 bv = *(const float4*)(bias + cg * 4);
  #pragma unroll
  for (int i = 0; i < 8; i++) {
    int r = row0 + rg * 8 + i;
    if (r < nrows) {
      ushort4 tv;
      tv.x = f2bf(accL[i][0]); tv.y = f2bf(accL[i][1]);
      tv.z = f2bf(accL[i][2]); tv.w = f2bf(accL[i][3]);
      *(ushort4*)(Tb + (size_t)r * 128 + cg * 4) = tv;
      float4 p = make_float4(accR[i][0] + bv.x, accR[i][1] + bv.y,
                             accR[i][2] + bv.z, accR[i][3] + bv.w);
      *(float4*)(R + (size_t)r * 128 + cg * 4) = p;
    }
  }
}

// ---------------- aggregate: Out[i] = R[i] + mean_{j in N(i)} Tb[j]; BN stats ----------------
__global__ __launch_bounds__(256) void k_aggregate(
    const unsigned short* __restrict__ Tb, const float* __restrict__ R,
    float* __restrict__ Out, const int* __restrict__ row_ptr,
    const int* __restrict__ csr, float* __restrict__ stats, int n) {
  __shared__ float sred[4][256];
  int lane = threadIdx.x & 63;
  int wlocal = threadIdx.x >> 6;
  int wid = (blockIdx.x * blockDim.x + threadIdx.x) >> 6;
  int nw = (gridDim.x * blockDim.x) >> 6;
  float sx = 0.f, sy = 0.f, qx = 0.f, qy = 0.f;

  for (int i = wid; i < n; i += nw) {
    int beg = row_ptr[i], end = row_ptr[i + 1];
    float ax = 0.f, ay = 0.f;
    int e = beg;
    for (; e + 4 <= end; e += 4) {
      int j0 = csr[e + 0], j1 = csr[e + 1], j2 = csr[e + 2], j3 = csr[e + 3];
      unsigned int v0 = *(const unsigned int*)(Tb + (size_t)j0 * 128 + lane * 2);
      unsigned int v1 = *(const unsigned int*)(Tb + (size_t)j1 * 128 + lane * 2);
      unsigned int v2 = *(const unsigned int*)(Tb + (size_t)j2 * 128 + lane * 2);
      unsigned int v3 = *(const unsigned int*)(Tb + (size_t)j3 * 128 + lane * 2);
      ax += bflo(v0) + bflo(v1) + bflo(v2) + bflo(v3);
      ay += bfhi(v0) + bfhi(v1) + bfhi(v2) + bfhi(v3);
    }
    for (; e < end; e++) {
      int j = csr[e];
      unsigned int v = *(const unsigned int*)(Tb + (size_t)j * 128 + lane * 2);
      ax += bflo(v);
      ay += bfhi(v);
    }
    int deg = end - beg;
    float inv = (deg > 0) ? (1.0f / (float)deg) : 0.0f;
    float2 rv = *(const float2*)(R + (size_t)i * 128 + lane * 2);
    float hx = rv.x + ax * inv;
    float hy = rv.y + ay * inv;
    *(float2*)(Out + (size_t)i * 128 + lane * 2) = make_float2(hx, hy);
    sx += hx; sy += hy;
    qx += hx * hx; qy += hy * hy;
  }

  // block-level stats reduction: wave partials -> LDS -> 256 atomics/block
  sred[wlocal][lane * 4 + 0] = sx;
  sred[wlocal][lane * 4 + 1] = sy;
  sred[wlocal][lane * 4 + 2] = qx;
  sred[wlocal][lane * 4 + 3] = qy;
  __syncthreads();
  int tid = threadIdx.x;
  float tot = sred[0][tid] + sred[1][tid] + sred[2][tid] + sred[3][tid];
  int l = tid >> 2;       // lane that owned features 2l, 2l+1
  int k = tid & 3;        // 0: sum x, 1: sum y, 2: sq x, 3: sq y
  int idx = (k < 2) ? (l * 2 + k) : (128 + l * 2 + (k - 2));
  atomicAdd(&stats[idx], tot);
}

// ---------------- BN + ReLU (in place) ----------------
__global__ __launch_bounds__(256) void k_bn_relu(
    float* __restrict__ H, const float* __restrict__ stats,
    const float* __restrict__ gamma, const float* __restrict__ beta, int n) {
  __shared__ float sc[128], sh[128];
  int tid = threadIdx.x;
  if (tid < 128) {
    float invn = 1.0f / (float)n;
    float mu = stats[tid] * invn;
    float var = stats[128 + tid] * invn - mu * mu;
    float s = rsqrtf(var + BN_EPS) * gamma[tid];
    sc[tid] = s;
    sh[tid] = beta[tid] - mu * s;
  }
  __syncthreads();
  size_t total4 = (size_t)n * 32;
  size_t stride = (size_t)gridDim.x * blockDim.x;
  for (size_t idx = blockIdx.x * (size_t)blockDim.x + tid; idx < total4; idx += stride) {
    float4 v = ((const float4*)H)[idx];
    int c = ((int)(idx & 31)) * 4;
    v.x = fmaxf(v.x * sc[c + 0] + sh[c + 0], 0.f);
    v.y = fmaxf(v.y * sc[c + 1] + sh[c + 1], 0.f);
    v.z = fmaxf(v.z * sc[c + 2] + sh[c + 2], 0.f);
    v.w = fmaxf(v.w * sc[c + 3] + sh[c + 3], 0.f);
    ((float4*)H)[idx] = v;
  }
}

// ---------------- final GEMM: Out = A @ Wout + bout ----------------
__global__ __launch_bounds__(256) void k_gemm_out(
    const float* __restrict__ A, const float* __restrict__ W,
    const float* __restrict__ bias, float* __restrict__ Out, int nrows) {
  __shared__ float As[64 * 132];
  int tid = threadIdx.x;
  int row0 = blockIdx.x * 64;
  #pragma unroll
  for (int i = 0; i < 8; i++) {
    int f4 = tid + i * 256;
    int r = f4 >> 5;
    int c4 = f4 & 31;
    float4 v = make_float4(0.f, 0.f, 0.f, 0.f);
    if (row0 + r < nrows) v = *(const float4*)(A + (size_t)(row0 + r) * 128 + c4 * 4);
    *(float4*)(As + r * 132 + c4 * 4) = v;
  }
  __syncthreads();

  int cg = tid & 7;
  int rg = tid >> 3;
  float acc[2][4] = {};
  for (int k = 0; k < 128; k++) {
    float4 w = *(const float4*)(W + k * 32 + cg * 4);
    float a0 = As[(rg * 2 + 0) * 132 + k];
    float a1 = As[(rg * 2 + 1) * 132 + k];
    acc[0][0] += a0 * w.x; acc[0][1] += a0 * w.y; acc[0][2] += a0 * w.z; acc[0][3] += a0 * w.w;
    acc[1][0] += a1 * w.x; acc[1][1] += a1 * w.y; acc[1][2] += a1 * w.z; acc[1][3] += a1 * w.w;
  }
  float4 bv = *(const float4*)(bias + cg * 4);
  #pragma unroll
  for (int i = 0; i < 2; i++) {
    int r = row0 + rg * 2 + i;
    if (r < nrows) {
      float4 o = make_float4(acc[i][0] + bv.x, acc[i][1] + bv.y,
                             acc[i][2] + bv.z, acc[i][3] + bv.w);
      *(float4*)(Out + (size_t)r * 32 + cg * 4) = o;
    }
  }
}

extern "C" void kernel_launch(void* const* d_in, const int* in_sizes, int n_in,
                              void* d_out, int out_size, void* d_ws, size_t ws_size,
                              hipStream_t stream) {
  const float* x    = (const float*)d_in[0];
  const int*   e_sp = (const int*)d_in[1];
  const int*   e_tp = (const int*)d_in[2];
  const float* Wl[4]  = {(const float*)d_in[3],  (const float*)d_in[8],
                         (const float*)d_in[13], (const float*)d_in[18]};
  const float* Wr[4]  = {(const float*)d_in[4],  (const float*)d_in[9],
                         (const float*)d_in[14], (const float*)d_in[19]};
  const float* bb[4]  = {(const float*)d_in[5],  (const float*)d_in[10],
                         (const float*)d_in[15], (const float*)d_in[20]};
  const float* gm[4]  = {(const float*)d_in[6],  (const float*)d_in[11],
                         (const float*)d_in[16], (const float*)d_in[21]};
  const float* bt[4]  = {(const float*)d_in[7],  (const float*)d_in[12],
                         (const float*)d_in[17], (const float*)d_in[22]};
  const float* Wout = (const float*)d_in[23];
  const float* bout = (const float*)d_in[24];

  const int N = in_sizes[0] / 128;
  const int E = in_sizes[1] / 2;

  char* ws = (char*)d_ws;
  size_t off = 0;
  auto alloc = [&](size_t bytes) {
    void* p = ws + off;
    off += (bytes + 255) & ~(size_t)255;
    return p;
  };
  float* A  = (float*)alloc((size_t)N * 128 * 4);            // h (f32)
  float* C  = (float*)alloc((size_t)N * 128 * 4);            // r = h@Wr + b (f32)
  unsigned short* Tb = (unsigned short*)alloc((size_t)N * 128 * 2);  // t = h@Wl (bf16)
  int* counts_sp = (int*)alloc((size_t)N * 4);
  int* counts_tp = (int*)alloc((size_t)N * 4);
  int* row_sp    = (int*)alloc((size_t)(N + 1) * 4);
  int* row_tp    = (int*)alloc((size_t)(N + 1) * 4);
  int* cursor    = (int*)alloc((size_t)N * 4);
  int* csr_sp    = (int*)alloc((size_t)E * 4);
  int* csr_tp    = (int*)alloc((size_t)E * 4);
  int* partials  = (int*)alloc(128 * 4);
  float* stats   = (float*)alloc(256 * 4);

  const int nb = (N + 1023) / 1024;

  // ---- build CSR (spatial) ----
  hipMemsetAsync(counts_sp, 0, (size_t)N * 4, stream);
  k_count<<<1024, 256, 0, stream>>>(e_sp + E, counts_sp, E);
  k_scan_blocks<<<nb, 256, 0, stream>>>(counts_sp, row_sp, partials, N);
  k_scan_partials<<<1, 128, 0, stream>>>(partials, nb);
  k_scan_add<<<nb, 256, 0, stream>>>(row_sp, partials, N, E);
  hipMemsetAsync(cursor, 0, (size_t)N * 4, stream);
  k_scatter<<<1024, 256, 0, stream>>>(e_sp, e_sp + E, row_sp, cursor, csr_sp, E);

  // ---- build CSR (temporal) ----
  hipMemsetAsync(counts_tp, 0, (size_t)N * 4, stream);
  k_count<<<1024, 256, 0, stream>>>(e_tp + E, counts_tp, E);
  k_scan_blocks<<<nb, 256, 0, stream>>>(counts_tp, row_tp, partials, N);
  k_scan_partials<<<1, 128, 0, stream>>>(partials, nb);
  k_scan_add<<<nb, 256, 0, stream>>>(row_tp, partials, N, E);
  hipMemsetAsync(cursor, 0, (size_t)N * 4, stream);
  k_scatter<<<1024, 256, 0, stream>>>(e_tp, e_tp + E, row_tp, cursor, csr_tp, E);

  const int* rowp[4] = {row_sp, row_sp, row_tp, row_tp};
  const int* csr[4]  = {csr_sp, csr_sp, csr_tp, csr_tp};

  const int gblocks = (N + 63) / 64;
  const float* cur = x;
  for (int l = 0; l < 4; l++) {
    k_gemm_dual<<<gblocks, 256, 0, stream>>>(cur, Wl[l], Wr[l], bb[l], Tb, C, N);
    hipMemsetAsync(stats, 0, 256 * 4, stream);
    k_aggregate<<<2048, 256, 0, stream>>>(Tb, C, A, rowp[l], csr[l], stats, N);
    k_bn_relu<<<2048, 256, 0, stream>>>(A, stats, gm[l], bt[l], N);
    cur = A;
  }
  k_gemm_out<<<gblocks, 256, 0, stream>>>(A, Wout, bout, (float*)d_out, N);
}

// Round 3
// 1093.774 us; speedup vs baseline: 2.1922x; 1.1564x over previous
//
#include <hip/hip_runtime.h>

#define BN_EPS 1e-5f

typedef __attribute__((ext_vector_type(8))) short short8;
typedef __attribute__((ext_vector_type(4))) float floatx4;

__device__ inline unsigned short f2bf(float x) {
  unsigned int u = __float_as_uint(x);
  u += 0x7fffu + ((u >> 16) & 1u);
  return (unsigned short)(u >> 16);
}
__device__ inline float bflo(unsigned int v) { return __uint_as_float(v << 16); }
__device__ inline float bfhi(unsigned int v) { return __uint_as_float(v & 0xffff0000u); }

// ---------------- weight pack: W[128][128] f32 -> bf16 fragment layout ----------------
// Wp[((ks*8+cf)*64 + lane)*8 + j] = bf16(W[ks*32 + (lane>>4)*8 + j][cf*16 + (lane&15)])
__global__ void k_wpack(const float* __restrict__ W, unsigned short* __restrict__ Wp) {
  int o = blockIdx.x * 256 + threadIdx.x;   // 0..16383
  int j = o & 7, l = (o >> 3) & 63, cf = (o >> 9) & 7, ks = o >> 12;
  int k = ks * 32 + (l >> 4) * 8 + j;
  int col = cf * 16 + (l & 15);
  Wp[o] = f2bf(W[k * 128 + col]);
}

// ---------------- CSR build ----------------
__global__ void k_count(const int* __restrict__ dst, int* __restrict__ counts, int E) {
  int e = blockIdx.x * 256 + threadIdx.x;
  if (e < E) atomicAdd(&counts[dst[e]], 1);
}

__global__ void k_scan_blocks(const int* __restrict__ in, int* __restrict__ out,
                              int* __restrict__ partials, int n) {
  __shared__ int sdata[256];
  int tid = threadIdx.x;
  int base = blockIdx.x * 1024 + tid * 4;
  int v0 = 0, v1 = 0, v2 = 0, v3 = 0;
  if (base + 0 < n) v0 = in[base + 0];
  if (base + 1 < n) v1 = in[base + 1];
  if (base + 2 < n) v2 = in[base + 2];
  if (base + 3 < n) v3 = in[base + 3];
  int s = v0 + v1 + v2 + v3;
  sdata[tid] = s;
  __syncthreads();
  for (int off = 1; off < 256; off <<= 1) {
    int t = (tid >= off) ? sdata[tid - off] : 0;
    __syncthreads();
    sdata[tid] += t;
    __syncthreads();
  }
  int excl = sdata[tid] - s;
  if (base + 0 < n) out[base + 0] = excl;
  if (base + 1 < n) out[base + 1] = excl + v0;
  if (base + 2 < n) out[base + 2] = excl + v0 + v1;
  if (base + 3 < n) out[base + 3] = excl + v0 + v1 + v2;
  if (tid == 0) partials[blockIdx.x] = sdata[255];
}

__global__ void k_scan_partials(int* __restrict__ p, int nb) {
  __shared__ int sdata[128];
  int tid = threadIdx.x;
  int v = (tid < nb) ? p[tid] : 0;
  sdata[tid] = v;
  __syncthreads();
  for (int off = 1; off < 128; off <<= 1) {
    int t = (tid >= off) ? sdata[tid - off] : 0;
    __syncthreads();
    sdata[tid] += t;
    __syncthreads();
  }
  if (tid < nb) p[tid] = sdata[tid] - v;
}

__global__ void k_scan_add(int* __restrict__ out, const int* __restrict__ partials,
                           int n, int total) {
  int tid = threadIdx.x;
  int base = blockIdx.x * 1024 + tid * 4;
  int add = partials[blockIdx.x];
  if (base + 0 < n) out[base + 0] += add;
  if (base + 1 < n) out[base + 1] += add;
  if (base + 2 < n) out[base + 2] += add;
  if (base + 3 < n) out[base + 3] += add;
  if (blockIdx.x == 0 && tid == 0) out[n] = total;
}

// cursor pre-initialized to row_ptr; single atomic yields final position
__global__ void k_scatter(const int* __restrict__ src, const int* __restrict__ dst,
                          int* __restrict__ cursor, int* __restrict__ csr, int E) {
  int e = blockIdx.x * 256 + threadIdx.x;
  if (e < E) {
    int d = dst[e];
    int p = atomicAdd(&cursor[d], 1);
    csr[p] = src[e];
  }
}

// ---------------- fused BN(+ReLU) -> dual MFMA GEMM: Tb = bn(H)@Wl (bf16), R = bn(H)@Wr + b (f32) ----------------
__global__ __launch_bounds__(256) void k_bn_gemm_dual(
    const float* __restrict__ H, const unsigned short* __restrict__ Wlp,
    const unsigned short* __restrict__ Wrp, const float* __restrict__ bias,
    const float* __restrict__ stats, const float* __restrict__ gamma,
    const float* __restrict__ beta, unsigned short* __restrict__ Tb,
    float* __restrict__ R, int n, int apply_bn) {
  __shared__ unsigned int As[64 * 64];   // 64 rows x 128 bf16, XOR-swizzled
  __shared__ float sc[128], sh[128];
  int tid = threadIdx.x;
  if (tid < 128) {
    if (apply_bn) {
      float invn = 1.0f / (float)n;
      float mu = stats[tid] * invn;
      float var = stats[128 + tid] * invn - mu * mu;
      float s = rsqrtf(var + BN_EPS) * gamma[tid];
      sc[tid] = s;
      sh[tid] = beta[tid] - mu * s;
    } else {
      sc[tid] = 1.0f;
      sh[tid] = 0.0f;
    }
  }
  __syncthreads();

  int row0 = blockIdx.x * 64;
  // stage: thread t handles row=t>>2, cols (t&3)*32 .. +31
  {
    int r = tid >> 2, cbase = (tid & 3) * 32;
    const float* src = H + (size_t)(row0 + r) * 128 + cbase;
    bool valid = (row0 + r) < n;
    unsigned int swz = (unsigned)((r & 7) << 2);
    unsigned int ubase = (unsigned)(r * 64 + (cbase >> 1));
    #pragma unroll
    for (int m = 0; m < 4; m++) {
      float4 v0 = make_float4(0.f, 0.f, 0.f, 0.f), v1 = v0;
      if (valid) {
        v0 = *(const float4*)(src + m * 8);
        v1 = *(const float4*)(src + m * 8 + 4);
      }
      int c = cbase + m * 8;
      if (apply_bn) {
        v0.x = fmaxf(v0.x * sc[c + 0] + sh[c + 0], 0.f);
        v0.y = fmaxf(v0.y * sc[c + 1] + sh[c + 1], 0.f);
        v0.z = fmaxf(v0.z * sc[c + 2] + sh[c + 2], 0.f);
        v0.w = fmaxf(v0.w * sc[c + 3] + sh[c + 3], 0.f);
        v1.x = fmaxf(v1.x * sc[c + 4] + sh[c + 4], 0.f);
        v1.y = fmaxf(v1.y * sc[c + 5] + sh[c + 5], 0.f);
        v1.z = fmaxf(v1.z * sc[c + 6] + sh[c + 6], 0.f);
        v1.w = fmaxf(v1.w * sc[c + 7] + sh[c + 7], 0.f);
      }
      uint4 pk;
      pk.x = (unsigned)f2bf(v0.x) | ((unsigned)f2bf(v0.y) << 16);
      pk.y = (unsigned)f2bf(v0.z) | ((unsigned)f2bf(v0.w) << 16);
      pk.z = (unsigned)f2bf(v1.x) | ((unsigned)f2bf(v1.y) << 16);
      pk.w = (unsigned)f2bf(v1.z) | ((unsigned)f2bf(v1.w) << 16);
      *(uint4*)(As + ((ubase + m * 4) ^ swz)) = pk;
    }
  }
  __syncthreads();

  int w = tid >> 6, lane = tid & 63;
  int wrow = (w << 4) + (lane & 15);           // LDS row this lane reads A from
  unsigned int aswz = (unsigned)((wrow & 7) << 2);
  floatx4 accT[8] = {}, accR[8] = {};

  #pragma unroll
  for (int ks = 0; ks < 4; ks++) {
    unsigned int aoff = (unsigned)(wrow * 64 + ks * 16 + ((lane >> 4) << 2)) ^ aswz;
    short8 a = *(const short8*)(As + aoff);
    #pragma unroll
    for (int cf = 0; cf < 8; cf++) {
      int wo = ((ks * 8 + cf) * 64 + lane) * 8;
      short8 wl = *(const short8*)(Wlp + wo);
      short8 wr = *(const short8*)(Wrp + wo);
      accT[cf] = __builtin_amdgcn_mfma_f32_16x16x32_bf16(a, wl, accT[cf], 0, 0, 0);
      accR[cf] = __builtin_amdgcn_mfma_f32_16x16x32_bf16(a, wr, accR[cf], 0, 0, 0);
    }
  }

  // epilogue: D col = lane&15 (+16*cf), row = (lane>>4)*4 + i
  int colb = lane & 15;
  int rb = row0 + (w << 4) + ((lane >> 4) << 2);
  #pragma unroll
  for (int cf = 0; cf < 8; cf++) {
    int col = cf * 16 + colb;
    float bv = bias[col];
    #pragma unroll
    for (int i = 0; i < 4; i++) {
      int r = rb + i;
      if (r < n) {
        Tb[(size_t)r * 128 + col] = f2bf(accT[cf][i]);
        R[(size_t)r * 128 + col] = accR[cf][i] + bv;
      }
    }
  }
}

// ---------------- aggregate: Out[i] = R[i] + mean_{j in N(i)} Tb[j]; BN stats ----------------
__global__ __launch_bounds__(256) void k_aggregate(
    const unsigned short* __restrict__ Tb, const float* __restrict__ R,
    float* __restrict__ Out, const int* __restrict__ row_ptr,
    const int* __restrict__ csr, float* __restrict__ stats, int n) {
  __shared__ float sred[4][256];
  int lane = threadIdx.x & 63;
  int wlocal = threadIdx.x >> 6;
  int wid = (blockIdx.x * blockDim.x + threadIdx.x) >> 6;
  int nw = (gridDim.x * blockDim.x) >> 6;
  float sx = 0.f, sy = 0.f, qx = 0.f, qy = 0.f;

  for (int i = wid; i < n; i += nw) {
    int beg = row_ptr[i], end = row_ptr[i + 1];
    float ax = 0.f, ay = 0.f;
    int e = beg;
    for (; e + 8 <= end; e += 8) {
      int j0 = csr[e + 0], j1 = csr[e + 1], j2 = csr[e + 2], j3 = csr[e + 3];
      int j4 = csr[e + 4], j5 = csr[e + 5], j6 = csr[e + 6], j7 = csr[e + 7];
      unsigned int v0 = *(const unsigned int*)(Tb + (size_t)j0 * 128 + lane * 2);
      unsigned int v1 = *(const unsigned int*)(Tb + (size_t)j1 * 128 + lane * 2);
      unsigned int v2 = *(const unsigned int*)(Tb + (size_t)j2 * 128 + lane * 2);
      unsigned int v3 = *(const unsigned int*)(Tb + (size_t)j3 * 128 + lane * 2);
      unsigned int v4 = *(const unsigned int*)(Tb + (size_t)j4 * 128 + lane * 2);
      unsigned int v5 = *(const unsigned int*)(Tb + (size_t)j5 * 128 + lane * 2);
      unsigned int v6 = *(const unsigned int*)(Tb + (size_t)j6 * 128 + lane * 2);
      unsigned int v7 = *(const unsigned int*)(Tb + (size_t)j7 * 128 + lane * 2);
      ax += bflo(v0) + bflo(v1) + bflo(v2) + bflo(v3) +
            bflo(v4) + bflo(v5) + bflo(v6) + bflo(v7);
      ay += bfhi(v0) + bfhi(v1) + bfhi(v2) + bfhi(v3) +
            bfhi(v4) + bfhi(v5) + bfhi(v6) + bfhi(v7);
    }
    for (; e < end; e++) {
      int j = csr[e];
      unsigned int v = *(const unsigned int*)(Tb + (size_t)j * 128 + lane * 2);
      ax += bflo(v);
      ay += bfhi(v);
    }
    int deg = end - beg;
    float inv = (deg > 0) ? (1.0f / (float)deg) : 0.0f;
    float2 rv = *(const float2*)(R + (size_t)i * 128 + lane * 2);
    float hx = rv.x + ax * inv;
    float hy = rv.y + ay * inv;
    *(float2*)(Out + (size_t)i * 128 + lane * 2) = make_float2(hx, hy);
    sx += hx; sy += hy;
    qx += hx * hx; qy += hy * hy;
  }

  sred[wlocal][lane * 4 + 0] = sx;
  sred[wlocal][lane * 4 + 1] = sy;
  sred[wlocal][lane * 4 + 2] = qx;
  sred[wlocal][lane * 4 + 3] = qy;
  __syncthreads();
  int tid = threadIdx.x;
  float tot = sred[0][tid] + sred[1][tid] + sred[2][tid] + sred[3][tid];
  int l = tid >> 2;
  int k = tid & 3;
  int idx = (k < 2) ? (l * 2 + k) : (128 + l * 2 + (k - 2));
  atomicAdd(&stats[idx], tot);
}

// ---------------- final: Out = bn_relu(A) @ Wout + bout ----------------
__global__ __launch_bounds__(256) void k_gemm_out(
    const float* __restrict__ A, const float* __restrict__ W,
    const float* __restrict__ bias, const float* __restrict__ stats,
    const float* __restrict__ gamma, const float* __restrict__ beta,
    float* __restrict__ Out, int nrows) {
  __shared__ float As[64 * 132];
  __shared__ float sc[128], sh[128];
  int tid = threadIdx.x;
  if (tid < 128) {
    float invn = 1.0f / (float)nrows;
    float mu = stats[tid] * invn;
    float var = stats[128 + tid] * invn - mu * mu;
    float s = rsqrtf(var + BN_EPS) * gamma[tid];
    sc[tid] = s;
    sh[tid] = beta[tid] - mu * s;
  }
  __syncthreads();
  int row0 = blockIdx.x * 64;
  #pragma unroll
  for (int i = 0; i < 8; i++) {
    int f4 = tid + i * 256;
    int r = f4 >> 5;
    int c4 = f4 & 31;
    float4 v = make_float4(0.f, 0.f, 0.f, 0.f);
    if (row0 + r < nrows) v = *(const float4*)(A + (size_t)(row0 + r) * 128 + c4 * 4);
    int c = c4 * 4;
    v.x = fmaxf(v.x * sc[c + 0] + sh[c + 0], 0.f);
    v.y = fmaxf(v.y * sc[c + 1] + sh[c + 1], 0.f);
    v.z = fmaxf(v.z * sc[c + 2] + sh[c + 2], 0.f);
    v.w = fmaxf(v.w * sc[c + 3] + sh[c + 3], 0.f);
    *(float4*)(As + r * 132 + c4 * 4) = v;
  }
  __syncthreads();

  int cg = tid & 7;
  int rg = tid >> 3;
  float acc[2][4] = {};
  for (int k = 0; k < 128; k++) {
    float4 w = *(const float4*)(W + k * 32 + cg * 4);
    float a0 = As[(rg * 2 + 0) * 132 + k];
    float a1 = As[(rg * 2 + 1) * 132 + k];
    acc[0][0] += a0 * w.x; acc[0][1] += a0 * w.y; acc[0][2] += a0 * w.z; acc[0][3] += a0 * w.w;
    acc[1][0] += a1 * w.x; acc[1][1] += a1 * w.y; acc[1][2] += a1 * w.z; acc[1][3] += a1 * w.w;
  }
  float4 bv = *(const float4*)(bias + cg * 4);
  #pragma unroll
  for (int i = 0; i < 2; i++) {
    int r = row0 + rg * 2 + i;
    if (r < nrows) {
      float4 o = make_float4(acc[i][0] + bv.x, acc[i][1] + bv.y,
                             acc[i][2] + bv.z, acc[i][3] + bv.w);
      *(float4*)(Out + (size_t)r * 32 + cg * 4) = o;
    }
  }
}

extern "C" void kernel_launch(void* const* d_in, const int* in_sizes, int n_in,
                              void* d_out, int out_size, void* d_ws, size_t ws_size,
                              hipStream_t stream) {
  const float* x    = (const float*)d_in[0];
  const int*   e_sp = (const int*)d_in[1];
  const int*   e_tp = (const int*)d_in[2];
  const float* Wl[4]  = {(const float*)d_in[3],  (const float*)d_in[8],
                         (const float*)d_in[13], (const float*)d_in[18]};
  const float* Wr[4]  = {(const float*)d_in[4],  (const float*)d_in[9],
                         (const float*)d_in[14], (const float*)d_in[19]};
  const float* bb[4]  = {(const float*)d_in[5],  (const float*)d_in[10],
                         (const float*)d_in[15], (const float*)d_in[20]};
  const float* gm[4]  = {(const float*)d_in[6],  (const float*)d_in[11],
                         (const float*)d_in[16], (const float*)d_in[21]};
  const float* bt[4]  = {(const float*)d_in[7],  (const float*)d_in[12],
                         (const float*)d_in[17], (const float*)d_in[22]};
  const float* Wout = (const float*)d_in[23];
  const float* bout = (const float*)d_in[24];

  const int N = in_sizes[0] / 128;
  const int E = in_sizes[1] / 2;

  char* ws = (char*)d_ws;
  size_t off = 0;
  auto alloc = [&](size_t bytes) {
    void* p = ws + off;
    off += (bytes + 255) & ~(size_t)255;
    return p;
  };
  float* A  = (float*)alloc((size_t)N * 128 * 4);                    // h (pre-BN, f32)
  float* C  = (float*)alloc((size_t)N * 128 * 4);                    // r (f32)
  unsigned short* Tb = (unsigned short*)alloc((size_t)N * 128 * 2);  // t (bf16)
  int* counts_sp = (int*)alloc((size_t)N * 4);
  int* counts_tp = (int*)alloc((size_t)N * 4);
  int* row_sp    = (int*)alloc((size_t)(N + 1) * 4);
  int* row_tp    = (int*)alloc((size_t)(N + 1) * 4);
  int* cursor    = (int*)alloc((size_t)N * 4);
  int* csr_sp    = (int*)alloc((size_t)E * 4);
  int* csr_tp    = (int*)alloc((size_t)E * 4);
  int* partials  = (int*)alloc(128 * 4);
  float* statsB  = (float*)alloc(4 * 256 * 4);
  unsigned short* Wlp[4], *Wrp[4];
  for (int l = 0; l < 4; l++) {
    Wlp[l] = (unsigned short*)alloc(16384 * 2);
    Wrp[l] = (unsigned short*)alloc(16384 * 2);
  }

  const int nb = (N + 1023) / 1024;
  const int eb = (E + 255) / 256;

  // ---- pack weights to bf16 fragment layout ----
  for (int l = 0; l < 4; l++) {
    k_wpack<<<64, 256, 0, stream>>>(Wl[l], Wlp[l]);
    k_wpack<<<64, 256, 0, stream>>>(Wr[l], Wrp[l]);
  }
  hipMemsetAsync(statsB, 0, 4 * 256 * 4, stream);

  // ---- build CSR (spatial) ----
  hipMemsetAsync(counts_sp, 0, (size_t)N * 4, stream);
  k_count<<<eb, 256, 0, stream>>>(e_sp + E, counts_sp, E);
  k_scan_blocks<<<nb, 256, 0, stream>>>(counts_sp, row_sp, partials, N);
  k_scan_partials<<<1, 128, 0, stream>>>(partials, nb);
  k_scan_add<<<nb, 256, 0, stream>>>(row_sp, partials, N, E);
  hipMemcpyAsync(cursor, row_sp, (size_t)N * 4, hipMemcpyDeviceToDevice, stream);
  k_scatter<<<eb, 256, 0, stream>>>(e_sp, e_sp + E, cursor, csr_sp, E);

  // ---- build CSR (temporal) ----
  hipMemsetAsync(counts_tp, 0, (size_t)N * 4, stream);
  k_count<<<eb, 256, 0, stream>>>(e_tp + E, counts_tp, E);
  k_scan_blocks<<<nb, 256, 0, stream>>>(counts_tp, row_tp, partials, N);
  k_scan_partials<<<1, 128, 0, stream>>>(partials, nb);
  k_scan_add<<<nb, 256, 0, stream>>>(row_tp, partials, N, E);
  hipMemcpyAsync(cursor, row_tp, (size_t)N * 4, hipMemcpyDeviceToDevice, stream);
  k_scatter<<<eb, 256, 0, stream>>>(e_tp, e_tp + E, cursor, csr_tp, E);

  const int* rowp[4] = {row_sp, row_sp, row_tp, row_tp};
  const int* csr[4]  = {csr_sp, csr_sp, csr_tp, csr_tp};

  const int gblocks = (N + 63) / 64;
  const float* cur = x;
  for (int l = 0; l < 4; l++) {
    const float* st = (l == 0) ? statsB : (statsB + (l - 1) * 256);
    const float* g  = (l == 0) ? gm[0] : gm[l - 1];   // unused when apply_bn=0
    const float* be = (l == 0) ? bt[0] : bt[l - 1];
    k_bn_gemm_dual<<<gblocks, 256, 0, stream>>>(cur, Wlp[l], Wrp[l], bb[l],
                                                st, g, be, Tb, C, N, l == 0 ? 0 : 1);
    k_aggregate<<<2048, 256, 0, stream>>>(Tb, C, A, rowp[l], csr[l],
                                          statsB + l * 256, N);
    cur = A;
  }
  k_gemm_out<<<gblocks, 256, 0, stream>>>(A, Wout, bout, statsB + 3 * 256,
                                          gm[3], bt[3], (float*)d_out, N);
}

// Round 4
// 1061.706 us; speedup vs baseline: 2.2584x; 1.0302x over previous
//
#include <hip/hip_runtime.h>

#define BN_EPS 1e-5f
#define BSHIFT 11   // nodes per bin = 2048

typedef __attribute__((ext_vector_type(8))) short short8;
typedef __attribute__((ext_vector_type(4))) float floatx4;

__device__ inline unsigned short f2bf(float x) {
  unsigned int u = __float_as_uint(x);
  u += 0x7fffu + ((u >> 16) & 1u);
  return (unsigned short)(u >> 16);
}
__device__ inline float bflo(unsigned int v) { return __uint_as_float(v << 16); }
__device__ inline float bfhi(unsigned int v) { return __uint_as_float(v & 0xffff0000u); }
__device__ inline float bfs(short s) { return __uint_as_float(((unsigned)(unsigned short)s) << 16); }

// ---------------- f32 -> bf16 array ----------------
__global__ void k_f2bf_arr(const float* __restrict__ in, unsigned short* __restrict__ out,
                           long long n8) {
  long long i = blockIdx.x * 256LL + threadIdx.x;
  if (i < n8) {
    float4 a = *(const float4*)(in + i * 8);
    float4 b = *(const float4*)(in + i * 8 + 4);
    ushort4 lo, hi;
    lo.x = f2bf(a.x); lo.y = f2bf(a.y); lo.z = f2bf(a.z); lo.w = f2bf(a.w);
    hi.x = f2bf(b.x); hi.y = f2bf(b.y); hi.z = f2bf(b.z); hi.w = f2bf(b.w);
    *(ushort4*)(out + i * 8) = lo;
    *(ushort4*)(out + i * 8 + 4) = hi;
  }
}

// ---------------- weight pack: W[128][128] f32 -> bf16 fragment layout ----------------
__global__ void k_wpack(const float* __restrict__ W, unsigned short* __restrict__ Wp) {
  int o = blockIdx.x * 256 + threadIdx.x;
  int j = o & 7, l = (o >> 3) & 63, cf = (o >> 9) & 7, ks = o >> 12;
  int k = ks * 32 + (l >> 4) * 8 + j;
  int col = cf * 16 + (l & 15);
  Wp[o] = f2bf(W[k * 128 + col]);
}

// ---------------- CSR build ----------------
__global__ void k_count(const int* __restrict__ dst, int* __restrict__ counts, int E) {
  int e = blockIdx.x * 256 + threadIdx.x;
  if (e < E) atomicAdd(&counts[dst[e]], 1);
}

__global__ void k_scan_blocks(const int* __restrict__ in, int* __restrict__ out,
                              int* __restrict__ partials, int n) {
  __shared__ int sdata[256];
  int tid = threadIdx.x;
  int base = blockIdx.x * 1024 + tid * 4;
  int v0 = 0, v1 = 0, v2 = 0, v3 = 0;
  if (base + 0 < n) v0 = in[base + 0];
  if (base + 1 < n) v1 = in[base + 1];
  if (base + 2 < n) v2 = in[base + 2];
  if (base + 3 < n) v3 = in[base + 3];
  int s = v0 + v1 + v2 + v3;
  sdata[tid] = s;
  __syncthreads();
  for (int off = 1; off < 256; off <<= 1) {
    int t = (tid >= off) ? sdata[tid - off] : 0;
    __syncthreads();
    sdata[tid] += t;
    __syncthreads();
  }
  int excl = sdata[tid] - s;
  if (base + 0 < n) out[base + 0] = excl;
  if (base + 1 < n) out[base + 1] = excl + v0;
  if (base + 2 < n) out[base + 2] = excl + v0 + v1;
  if (base + 3 < n) out[base + 3] = excl + v0 + v1 + v2;
  if (tid == 0) partials[blockIdx.x] = sdata[255];
}

__global__ void k_scan_partials(int* __restrict__ p, int nb) {
  __shared__ int sdata[128];
  int tid = threadIdx.x;
  int v = (tid < nb) ? p[tid] : 0;
  sdata[tid] = v;
  __syncthreads();
  for (int off = 1; off < 128; off <<= 1) {
    int t = (tid >= off) ? sdata[tid - off] : 0;
    __syncthreads();
    sdata[tid] += t;
    __syncthreads();
  }
  if (tid < nb) p[tid] = sdata[tid] - v;
}

__global__ void k_scan_add(int* __restrict__ out, const int* __restrict__ partials,
                           int n, int total) {
  int tid = threadIdx.x;
  int base = blockIdx.x * 1024 + tid * 4;
  int add = partials[blockIdx.x];
  if (base + 0 < n) out[base + 0] += add;
  if (base + 1 < n) out[base + 1] += add;
  if (base + 2 < n) out[base + 2] += add;
  if (base + 3 < n) out[base + 3] += add;
  if (blockIdx.x == 0 && tid == 0) out[n] = total;
}

// binStart[b] = row_ptr[min(b<<BSHIFT, N)]; binCursor likewise
__global__ void k_bininit(const int* __restrict__ row_ptr, int* __restrict__ binStart,
                          int* __restrict__ binCursor, int nbins, int N) {
  int b = threadIdx.x;
  if (b <= nbins) {
    int idx = b << BSHIFT;
    if (idx > N) idx = N;
    int v = row_ptr[idx];
    binStart[b] = v;
    if (b < nbins) binCursor[b] = v;
  }
}

// phase 1: bin (dst,src) pairs into bin-major buffer; coalesced-in-L2 chunk writes
__global__ __launch_bounds__(256) void k_bin_pairs(
    const int* __restrict__ src, const int* __restrict__ dst,
    int* __restrict__ binCursor, long long* __restrict__ binbuf, int E) {
  __shared__ int hist[64], base[64];
  int tid = threadIdx.x;
  int b0 = blockIdx.x * 2048;
  if (tid < 64) hist[tid] = 0;
  __syncthreads();
  int s[8], d[8], rk[8], bn[8];
  #pragma unroll
  for (int i = 0; i < 8; i++) {
    int e = b0 + tid + i * 256;
    if (e < E) {
      s[i] = src[e];
      d[i] = dst[e];
      bn[i] = d[i] >> BSHIFT;
      rk[i] = atomicAdd(&hist[bn[i]], 1);
    }
  }
  __syncthreads();
  if (tid < 64 && hist[tid] > 0)
    base[tid] = atomicAdd(&binCursor[tid], hist[tid]);
  __syncthreads();
  #pragma unroll
  for (int i = 0; i < 8; i++) {
    int e = b0 + tid + i * 256;
    if (e < E)
      binbuf[(size_t)base[bn[i]] + rk[i]] =
          ((long long)d[i] << 32) | (unsigned int)s[i];
  }
}

// phase 2: scatter within bin (CSR window L2-resident). 4 WGs per bin.
__global__ __launch_bounds__(1024) void k_scatter2(
    const long long* __restrict__ binbuf, const int* __restrict__ binStart,
    int* __restrict__ cursor, int* __restrict__ csr) {
  int b = blockIdx.x >> 2, sub = blockIdx.x & 3;
  int lo = binStart[b], hi = binStart[b + 1];
  for (int e = lo + sub * 1024 + threadIdx.x; e < hi; e += 4096) {
    long long pr = binbuf[e];
    int d = (int)(pr >> 32);
    int sv = (int)(pr & 0xffffffffLL);
    int p = atomicAdd(&cursor[d], 1);
    csr[p] = sv;
  }
}

// ---------------- fused BN(+ReLU) -> dual MFMA GEMM (bf16 input H) ----------------
__global__ __launch_bounds__(256) void k_bn_gemm_dual(
    const unsigned short* __restrict__ Hb, const unsigned short* __restrict__ Wlp,
    const unsigned short* __restrict__ Wrp, const float* __restrict__ bias,
    const float* __restrict__ stats, const float* __restrict__ gamma,
    const float* __restrict__ beta, unsigned short* __restrict__ Tb,
    float* __restrict__ R, int n, int apply_bn) {
  __shared__ unsigned int As[64 * 64];   // 64 rows x 128 bf16, XOR-swizzled
  __shared__ float sc[128], sh[128];
  int tid = threadIdx.x;
  if (tid < 128) {
    if (apply_bn) {
      float invn = 1.0f / (float)n;
      float mu = stats[tid] * invn;
      float var = stats[128 + tid] * invn - mu * mu;
      float s = rsqrtf(var + BN_EPS) * gamma[tid];
      sc[tid] = s;
      sh[tid] = beta[tid] - mu * s;
    }
  }
  __syncthreads();

  int row0 = blockIdx.x * 64;
  {
    int r = tid >> 2, cbase = (tid & 3) * 32;
    const unsigned short* srcp = Hb + (size_t)(row0 + r) * 128 + cbase;
    bool valid = (row0 + r) < n;
    unsigned int swz = (unsigned)((r & 7) << 2);
    unsigned int ubase = (unsigned)(r * 64 + (cbase >> 1));
    #pragma unroll
    for (int m = 0; m < 4; m++) {
      uint4 raw = make_uint4(0u, 0u, 0u, 0u);
      if (valid) raw = *(const uint4*)(srcp + m * 8);
      uint4 pk;
      if (apply_bn) {
        int c = cbase + m * 8;
        float f0 = fmaxf(bflo(raw.x) * sc[c + 0] + sh[c + 0], 0.f);
        float f1 = fmaxf(bfhi(raw.x) * sc[c + 1] + sh[c + 1], 0.f);
        float f2 = fmaxf(bflo(raw.y) * sc[c + 2] + sh[c + 2], 0.f);
        float f3 = fmaxf(bfhi(raw.y) * sc[c + 3] + sh[c + 3], 0.f);
        float f4 = fmaxf(bflo(raw.z) * sc[c + 4] + sh[c + 4], 0.f);
        float f5 = fmaxf(bfhi(raw.z) * sc[c + 5] + sh[c + 5], 0.f);
        float f6 = fmaxf(bflo(raw.w) * sc[c + 6] + sh[c + 6], 0.f);
        float f7 = fmaxf(bfhi(raw.w) * sc[c + 7] + sh[c + 7], 0.f);
        pk.x = (unsigned)f2bf(f0) | ((unsigned)f2bf(f1) << 16);
        pk.y = (unsigned)f2bf(f2) | ((unsigned)f2bf(f3) << 16);
        pk.z = (unsigned)f2bf(f4) | ((unsigned)f2bf(f5) << 16);
        pk.w = (unsigned)f2bf(f6) | ((unsigned)f2bf(f7) << 16);
      } else {
        pk = raw;   // x already bf16, no BN on layer 0
      }
      *(uint4*)(As + ((ubase + m * 4) ^ swz)) = pk;
    }
  }
  __syncthreads();

  int w = tid >> 6, lane = tid & 63;
  int wrow = (w << 4) + (lane & 15);
  unsigned int aswz = (unsigned)((wrow & 7) << 2);
  floatx4 accT[8] = {}, accR[8] = {};

  #pragma unroll
  for (int ks = 0; ks < 4; ks++) {
    unsigned int aoff = (unsigned)(wrow * 64 + ks * 16 + ((lane >> 4) << 2)) ^ aswz;
    short8 a = *(const short8*)(As + aoff);
    #pragma unroll
    for (int cf = 0; cf < 8; cf++) {
      int wo = ((ks * 8 + cf) * 64 + lane) * 8;
      short8 wl = *(const short8*)(Wlp + wo);
      short8 wr = *(const short8*)(Wrp + wo);
      accT[cf] = __builtin_amdgcn_mfma_f32_16x16x32_bf16(a, wl, accT[cf], 0, 0, 0);
      accR[cf] = __builtin_amdgcn_mfma_f32_16x16x32_bf16(a, wr, accR[cf], 0, 0, 0);
    }
  }

  int colb = lane & 15;
  int rb = row0 + (w << 4) + ((lane >> 4) << 2);
  #pragma unroll
  for (int cf = 0; cf < 8; cf++) {
    int col = cf * 16 + colb;
    float bv = bias[col];
    #pragma unroll
    for (int i = 0; i < 4; i++) {
      int r = rb + i;
      if (r < n) {
        Tb[(size_t)r * 128 + col] = f2bf(accT[cf][i]);
        R[(size_t)r * 128 + col] = accR[cf][i] + bv;
      }
    }
  }
}

// ---------------- aggregate: Hb[i] = bf16(R[i] + mean_{j in N(i)} Tb[j]); BN stats ----------------
__global__ __launch_bounds__(256) void k_aggregate(
    const unsigned short* __restrict__ Tb, const float* __restrict__ R,
    unsigned short* __restrict__ Hb, const int* __restrict__ row_ptr,
    const int* __restrict__ csr, float* __restrict__ stats, int n) {
  __shared__ float sred[4][256];
  int lane = threadIdx.x & 63;
  int wlocal = threadIdx.x >> 6;
  int wid = (blockIdx.x * blockDim.x + threadIdx.x) >> 6;
  int nw = (gridDim.x * blockDim.x) >> 6;
  float sx = 0.f, sy = 0.f, qx = 0.f, qy = 0.f;

  for (int i = wid; i < n; i += nw) {
    int beg = row_ptr[i], end = row_ptr[i + 1];
    float ax = 0.f, ay = 0.f;
    int e = beg;
    for (; e + 8 <= end; e += 8) {
      int j0 = csr[e + 0], j1 = csr[e + 1], j2 = csr[e + 2], j3 = csr[e + 3];
      int j4 = csr[e + 4], j5 = csr[e + 5], j6 = csr[e + 6], j7 = csr[e + 7];
      unsigned int v0 = *(const unsigned int*)(Tb + (size_t)j0 * 128 + lane * 2);
      unsigned int v1 = *(const unsigned int*)(Tb + (size_t)j1 * 128 + lane * 2);
      unsigned int v2 = *(const unsigned int*)(Tb + (size_t)j2 * 128 + lane * 2);
      unsigned int v3 = *(const unsigned int*)(Tb + (size_t)j3 * 128 + lane * 2);
      unsigned int v4 = *(const unsigned int*)(Tb + (size_t)j4 * 128 + lane * 2);
      unsigned int v5 = *(const unsigned int*)(Tb + (size_t)j5 * 128 + lane * 2);
      unsigned int v6 = *(const unsigned int*)(Tb + (size_t)j6 * 128 + lane * 2);
      unsigned int v7 = *(const unsigned int*)(Tb + (size_t)j7 * 128 + lane * 2);
      ax += bflo(v0) + bflo(v1) + bflo(v2) + bflo(v3) +
            bflo(v4) + bflo(v5) + bflo(v6) + bflo(v7);
      ay += bfhi(v0) + bfhi(v1) + bfhi(v2) + bfhi(v3) +
            bfhi(v4) + bfhi(v5) + bfhi(v6) + bfhi(v7);
    }
    for (; e < end; e++) {
      int j = csr[e];
      unsigned int v = *(const unsigned int*)(Tb + (size_t)j * 128 + lane * 2);
      ax += bflo(v);
      ay += bfhi(v);
    }
    int deg = end - beg;
    float inv = (deg > 0) ? (1.0f / (float)deg) : 0.0f;
    float2 rv = *(const float2*)(R + (size_t)i * 128 + lane * 2);
    float hx = rv.x + ax * inv;
    float hy = rv.y + ay * inv;
    unsigned int pk = (unsigned)f2bf(hx) | ((unsigned)f2bf(hy) << 16);
    *(unsigned int*)(Hb + (size_t)i * 128 + lane * 2) = pk;
    sx += hx; sy += hy;
    qx += hx * hx; qy += hy * hy;
  }

  sred[wlocal][lane * 4 + 0] = sx;
  sred[wlocal][lane * 4 + 1] = sy;
  sred[wlocal][lane * 4 + 2] = qx;
  sred[wlocal][lane * 4 + 3] = qy;
  __syncthreads();
  int tid = threadIdx.x;
  float tot = sred[0][tid] + sred[1][tid] + sred[2][tid] + sred[3][tid];
  int l = tid >> 2;
  int k = tid & 3;
  int idx = (k < 2) ? (l * 2 + k) : (128 + l * 2 + (k - 2));
  atomicAdd(&stats[idx], tot);
}

// ---------------- final: Out = bn_relu(Hb) @ Wout + bout ----------------
__global__ __launch_bounds__(256) void k_gemm_out(
    const unsigned short* __restrict__ Hb, const float* __restrict__ W,
    const float* __restrict__ bias, const float* __restrict__ stats,
    const float* __restrict__ gamma, const float* __restrict__ beta,
    float* __restrict__ Out, int nrows) {
  __shared__ float As[64 * 132];
  __shared__ float sc[128], sh[128];
  int tid = threadIdx.x;
  if (tid < 128) {
    float invn = 1.0f / (float)nrows;
    float mu = stats[tid] * invn;
    float var = stats[128 + tid] * invn - mu * mu;
    float s = rsqrtf(var + BN_EPS) * gamma[tid];
    sc[tid] = s;
    sh[tid] = beta[tid] - mu * s;
  }
  __syncthreads();
  int row0 = blockIdx.x * 64;
  #pragma unroll
  for (int i = 0; i < 4; i++) {
    int g = tid + i * 256;        // ushort8 granule, 16 per row
    int r = g >> 4;
    int c8 = g & 15;
    uint4 raw = make_uint4(0u, 0u, 0u, 0u);
    if (row0 + r < nrows)
      raw = *(const uint4*)(Hb + (size_t)(row0 + r) * 128 + c8 * 8);
    int c = c8 * 8;
    float* dstp = As + r * 132 + c;
    dstp[0] = fmaxf(bflo(raw.x) * sc[c + 0] + sh[c + 0], 0.f);
    dstp[1] = fmaxf(bfhi(raw.x) * sc[c + 1] + sh[c + 1], 0.f);
    dstp[2] = fmaxf(bflo(raw.y) * sc[c + 2] + sh[c + 2], 0.f);
    dstp[3] = fmaxf(bfhi(raw.y) * sc[c + 3] + sh[c + 3], 0.f);
    dstp[4] = fmaxf(bflo(raw.z) * sc[c + 4] + sh[c + 4], 0.f);
    dstp[5] = fmaxf(bfhi(raw.z) * sc[c + 5] + sh[c + 5], 0.f);
    dstp[6] = fmaxf(bflo(raw.w) * sc[c + 6] + sh[c + 6], 0.f);
    dstp[7] = fmaxf(bfhi(raw.w) * sc[c + 7] + sh[c + 7], 0.f);
  }
  __syncthreads();

  int cg = tid & 7;
  int rg = tid >> 3;
  float acc[2][4] = {};
  for (int k = 0; k < 128; k++) {
    float4 w = *(const float4*)(W + k * 32 + cg * 4);
    float a0 = As[(rg * 2 + 0) * 132 + k];
    float a1 = As[(rg * 2 + 1) * 132 + k];
    acc[0][0] += a0 * w.x; acc[0][1] += a0 * w.y; acc[0][2] += a0 * w.z; acc[0][3] += a0 * w.w;
    acc[1][0] += a1 * w.x; acc[1][1] += a1 * w.y; acc[1][2] += a1 * w.z; acc[1][3] += a1 * w.w;
  }
  float4 bv = *(const float4*)(bias + cg * 4);
  #pragma unroll
  for (int i = 0; i < 2; i++) {
    int r = row0 + rg * 2 + i;
    if (r < nrows) {
      float4 o = make_float4(acc[i][0] + bv.x, acc[i][1] + bv.y,
                             acc[i][2] + bv.z, acc[i][3] + bv.w);
      *(float4*)(Out + (size_t)r * 32 + cg * 4) = o;
    }
  }
}

extern "C" void kernel_launch(void* const* d_in, const int* in_sizes, int n_in,
                              void* d_out, int out_size, void* d_ws, size_t ws_size,
                              hipStream_t stream) {
  const float* x    = (const float*)d_in[0];
  const int*   e_sp = (const int*)d_in[1];
  const int*   e_tp = (const int*)d_in[2];
  const float* Wl[4]  = {(const float*)d_in[3],  (const float*)d_in[8],
                         (const float*)d_in[13], (const float*)d_in[18]};
  const float* Wr[4]  = {(const float*)d_in[4],  (const float*)d_in[9],
                         (const float*)d_in[14], (const float*)d_in[19]};
  const float* bb[4]  = {(const float*)d_in[5],  (const float*)d_in[10],
                         (const float*)d_in[15], (const float*)d_in[20]};
  const float* gm[4]  = {(const float*)d_in[6],  (const float*)d_in[11],
                         (const float*)d_in[16], (const float*)d_in[21]};
  const float* bt[4]  = {(const float*)d_in[7],  (const float*)d_in[12],
                         (const float*)d_in[17], (const float*)d_in[22]};
  const float* Wout = (const float*)d_in[23];
  const float* bout = (const float*)d_in[24];

  const int N = in_sizes[0] / 128;
  const int E = in_sizes[1] / 2;
  const int nbins = (N + ((1 << BSHIFT) - 1)) >> BSHIFT;

  char* ws = (char*)d_ws;
  size_t off = 0;
  auto alloc = [&](size_t bytes) {
    void* p = ws + off;
    off += (bytes + 255) & ~(size_t)255;
    return p;
  };
  unsigned short* Hb = (unsigned short*)alloc((size_t)N * 128 * 2);  // h (bf16)
  unsigned short* xb = (unsigned short*)alloc((size_t)N * 128 * 2);  // x (bf16)
  float* C  = (float*)alloc((size_t)N * 128 * 4);                    // r (f32)
  unsigned short* Tb = (unsigned short*)alloc((size_t)N * 128 * 2);  // t (bf16)
  int* counts_sp = (int*)alloc((size_t)N * 4);
  int* counts_tp = (int*)alloc((size_t)N * 4);
  int* row_sp    = (int*)alloc((size_t)(N + 1) * 4);
  int* row_tp    = (int*)alloc((size_t)(N + 1) * 4);
  int* cursor    = (int*)alloc((size_t)N * 4);
  int* csr_sp    = (int*)alloc((size_t)E * 4);
  int* csr_tp    = (int*)alloc((size_t)E * 4);
  long long* binbuf = (long long*)alloc((size_t)E * 8);
  int* binStart  = (int*)alloc(256 * 4);
  int* binCursor = (int*)alloc(256 * 4);
  int* partials  = (int*)alloc(128 * 4);
  float* statsB  = (float*)alloc(4 * 256 * 4);
  unsigned short* Wlp[4], *Wrp[4];
  for (int l = 0; l < 4; l++) {
    Wlp[l] = (unsigned short*)alloc(16384 * 2);
    Wrp[l] = (unsigned short*)alloc(16384 * 2);
  }

  const int nb = (N + 1023) / 1024;
  const int eb = (E + 255) / 256;
  const int pb = (E + 2047) / 2048;

  for (int l = 0; l < 4; l++) {
    k_wpack<<<64, 256, 0, stream>>>(Wl[l], Wlp[l]);
    k_wpack<<<64, 256, 0, stream>>>(Wr[l], Wrp[l]);
  }
  k_f2bf_arr<<<(int)(((size_t)N * 16 + 255) / 256), 256, 0, stream>>>(x, xb, (size_t)N * 16);
  hipMemsetAsync(statsB, 0, 4 * 256 * 4, stream);

  // ---- build CSR (spatial) ----
  hipMemsetAsync(counts_sp, 0, (size_t)N * 4, stream);
  k_count<<<eb, 256, 0, stream>>>(e_sp + E, counts_sp, E);
  k_scan_blocks<<<nb, 256, 0, stream>>>(counts_sp, row_sp, partials, N);
  k_scan_partials<<<1, 128, 0, stream>>>(partials, nb);
  k_scan_add<<<nb, 256, 0, stream>>>(row_sp, partials, N, E);
  k_bininit<<<1, 256, 0, stream>>>(row_sp, binStart, binCursor, nbins, N);
  k_bin_pairs<<<pb, 256, 0, stream>>>(e_sp, e_sp + E, binCursor, binbuf, E);
  hipMemcpyAsync(cursor, row_sp, (size_t)N * 4, hipMemcpyDeviceToDevice, stream);
  k_scatter2<<<nbins * 4, 1024, 0, stream>>>(binbuf, binStart, cursor, csr_sp);

  // ---- build CSR (temporal) ----
  hipMemsetAsync(counts_tp, 0, (size_t)N * 4, stream);
  k_count<<<eb, 256, 0, stream>>>(e_tp + E, counts_tp, E);
  k_scan_blocks<<<nb, 256, 0, stream>>>(counts_tp, row_tp, partials, N);
  k_scan_partials<<<1, 128, 0, stream>>>(partials, nb);
  k_scan_add<<<nb, 256, 0, stream>>>(row_tp, partials, N, E);
  k_bininit<<<1, 256, 0, stream>>>(row_tp, binStart, binCursor, nbins, N);
  k_bin_pairs<<<pb, 256, 0, stream>>>(e_tp, e_tp + E, binCursor, binbuf, E);
  hipMemcpyAsync(cursor, row_tp, (size_t)N * 4, hipMemcpyDeviceToDevice, stream);
  k_scatter2<<<nbins * 4, 1024, 0, stream>>>(binbuf, binStart, cursor, csr_tp);

  const int* rowp[4] = {row_sp, row_sp, row_tp, row_tp};
  const int* csr[4]  = {csr_sp, csr_sp, csr_tp, csr_tp};

  const int gblocks = (N + 63) / 64;
  const unsigned short* cur = xb;
  for (int l = 0; l < 4; l++) {
    const float* st = (l == 0) ? statsB : (statsB + (l - 1) * 256);
    const float* g  = (l == 0) ? gm[0] : gm[l - 1];
    const float* be = (l == 0) ? bt[0] : bt[l - 1];
    k_bn_gemm_dual<<<gblocks, 256, 0, stream>>>(cur, Wlp[l], Wrp[l], bb[l],
                                                st, g, be, Tb, C, N, l == 0 ? 0 : 1);
    k_aggregate<<<2048, 256, 0, stream>>>(Tb, C, Hb, rowp[l], csr[l],
                                          statsB + l * 256, N);
    cur = Hb;
  }
  k_gemm_out<<<gblocks, 256, 0, stream>>>(Hb, Wout, bout, statsB + 3 * 256,
                                          gm[3], bt[3], (float*)d_out, N);
}

// Round 5
// 732.628 us; speedup vs baseline: 3.2728x; 1.4492x over previous
//
#include <hip/hip_runtime.h>

#define BN_EPS 1e-5f
#define BSHIFT 9              // nodes per bin = 512
#define BINCAP 10240          // >22 sigma above mean 8192 edges/bin

typedef __attribute__((ext_vector_type(8))) short short8;
typedef __attribute__((ext_vector_type(4))) float floatx4;

__device__ inline unsigned short f2bf(float x) {
  unsigned int u = __float_as_uint(x);
  u += 0x7fffu + ((u >> 16) & 1u);
  return (unsigned short)(u >> 16);
}
__device__ inline float bflo(unsigned int v) { return __uint_as_float(v << 16); }
__device__ inline float bfhi(unsigned int v) { return __uint_as_float(v & 0xffff0000u); }

// ---------------- f32 -> bf16 array ----------------
__global__ void k_f2bf_arr(const float* __restrict__ in, unsigned short* __restrict__ out,
                           long long n8) {
  long long i = blockIdx.x * 256LL + threadIdx.x;
  if (i < n8) {
    float4 a = *(const float4*)(in + i * 8);
    float4 b = *(const float4*)(in + i * 8 + 4);
    ushort4 lo, hi;
    lo.x = f2bf(a.x); lo.y = f2bf(a.y); lo.z = f2bf(a.z); lo.w = f2bf(a.w);
    hi.x = f2bf(b.x); hi.y = f2bf(b.y); hi.z = f2bf(b.z); hi.w = f2bf(b.w);
    *(ushort4*)(out + i * 8) = lo;
    *(ushort4*)(out + i * 8 + 4) = hi;
  }
}

// ---------------- weight pack: W[128][128] f32 -> bf16 fragment layout ----------------
__global__ void k_wpack(const float* __restrict__ W, unsigned short* __restrict__ Wp) {
  int o = blockIdx.x * 256 + threadIdx.x;
  int j = o & 7, l = (o >> 3) & 63, cf = (o >> 9) & 7, ks = o >> 12;
  int k = ks * 32 + (l >> 4) * 8 + j;
  int col = cf * 16 + (l & 15);
  Wp[o] = f2bf(W[k * 128 + col]);
}

// ---------------- CSR build: atomic-free binned counting sort ----------------
// phase 1: bin (dst,src) pairs into fixed-capacity bin-major buffer.
// LDS ranks; one global atomic per (block,bin) only.
__global__ __launch_bounds__(1024) void k_bin_pairs(
    const int* __restrict__ src, const int* __restrict__ dst,
    int* __restrict__ binCount, long long* __restrict__ binbuf, int E, int nbins) {
  __shared__ int hist[256], base[256];
  int tid = threadIdx.x;
  int b0 = blockIdx.x * 8192;
  if (tid < 256) hist[tid] = 0;
  __syncthreads();
  int s[8], d[8], rk[8], bn[8];
  #pragma unroll
  for (int i = 0; i < 8; i++) {
    int e = b0 + tid + i * 1024;
    if (e < E) {
      s[i] = src[e];
      d[i] = dst[e];
      bn[i] = d[i] >> BSHIFT;
      rk[i] = atomicAdd(&hist[bn[i]], 1);
    }
  }
  __syncthreads();
  if (tid < nbins && hist[tid] > 0)
    base[tid] = atomicAdd(&binCount[tid], hist[tid]);
  __syncthreads();
  #pragma unroll
  for (int i = 0; i < 8; i++) {
    int e = b0 + tid + i * 1024;
    if (e < E)
      binbuf[(size_t)bn[i] * BINCAP + base[bn[i]] + rk[i]] =
          ((long long)d[i] << 32) | (unsigned int)s[i];
  }
}

// exclusive scan of binCount -> binBase[nbins+1]; also row_ptr[N] = E
__global__ void k_binscan(const int* __restrict__ binCount, int* __restrict__ binBase,
                          int* __restrict__ row_ptr, int nbins, int N, int E) {
  __shared__ int sd[256];
  int tid = threadIdx.x;
  int v = (tid < nbins) ? binCount[tid] : 0;
  sd[tid] = v;
  __syncthreads();
  for (int off = 1; off < 256; off <<= 1) {
    int t = (tid >= off) ? sd[tid - off] : 0;
    __syncthreads();
    sd[tid] += t;
    __syncthreads();
  }
  if (tid < nbins) binBase[tid] = sd[tid] - v;
  if (tid == nbins) binBase[nbins] = sd[nbins - 1];
  if (tid == 0) row_ptr[N] = E;
}

// phase 2: one WG per bin. LDS hist+scan -> row_ptr; LDS-ranked scatter -> csr.
__global__ __launch_bounds__(1024) void k_csr_bin(
    const long long* __restrict__ binbuf, const int* __restrict__ binCount,
    const int* __restrict__ binBase, int* __restrict__ row_ptr,
    int* __restrict__ csr, int N) {
  __shared__ int hist[512];
  __shared__ int incl[512];
  int b = blockIdx.x;
  int tid = threadIdx.x;
  int nE = binCount[b];
  int eb = binBase[b];
  const long long* p = binbuf + (size_t)b * BINCAP;
  if (tid < 512) hist[tid] = 0;
  __syncthreads();
  for (int e = tid; e < nE; e += 1024) {
    int d = (int)(p[e] >> 32);
    atomicAdd(&hist[d & 511], 1);
  }
  __syncthreads();
  if (tid < 512) incl[tid] = hist[tid];
  __syncthreads();
  for (int off = 1; off < 512; off <<= 1) {
    int t = 0;
    if (tid < 512 && tid >= off) t = incl[tid - off];
    __syncthreads();
    if (tid < 512) incl[tid] += t;
    __syncthreads();
  }
  int node0 = b << BSHIFT;
  if (tid < 512) {
    int ex = incl[tid] - hist[tid];
    if (node0 + tid < N) row_ptr[node0 + tid] = eb + ex;
    hist[tid] = ex;             // reuse as bin-local cursor
  }
  __syncthreads();
  for (int e = tid; e < nE; e += 1024) {
    long long pr = p[e];
    int d = ((int)(pr >> 32)) & 511;
    int sv = (int)(pr & 0xffffffffLL);
    int r = atomicAdd(&hist[d], 1);
    csr[eb + r] = sv;
  }
}

// ---------------- fused BN(+ReLU) -> dual MFMA GEMM (bf16 input H) ----------------
__global__ __launch_bounds__(256) void k_bn_gemm_dual(
    const unsigned short* __restrict__ Hb, const unsigned short* __restrict__ Wlp,
    const unsigned short* __restrict__ Wrp, const float* __restrict__ bias,
    const float* __restrict__ stats, const float* __restrict__ gamma,
    const float* __restrict__ beta, unsigned short* __restrict__ Tb,
    float* __restrict__ R, int n, int apply_bn) {
  __shared__ unsigned int As[64 * 64];   // 64 rows x 128 bf16, XOR-swizzled
  __shared__ float sc[128], sh[128];
  int tid = threadIdx.x;
  if (tid < 128) {
    if (apply_bn) {
      float invn = 1.0f / (float)n;
      float mu = stats[tid] * invn;
      float var = stats[128 + tid] * invn - mu * mu;
      float s = rsqrtf(var + BN_EPS) * gamma[tid];
      sc[tid] = s;
      sh[tid] = beta[tid] - mu * s;
    }
  }
  __syncthreads();

  int row0 = blockIdx.x * 64;
  {
    int r = tid >> 2, cbase = (tid & 3) * 32;
    const unsigned short* srcp = Hb + (size_t)(row0 + r) * 128 + cbase;
    bool valid = (row0 + r) < n;
    unsigned int swz = (unsigned)((r & 7) << 2);
    unsigned int ubase = (unsigned)(r * 64 + (cbase >> 1));
    #pragma unroll
    for (int m = 0; m < 4; m++) {
      uint4 raw = make_uint4(0u, 0u, 0u, 0u);
      if (valid) raw = *(const uint4*)(srcp + m * 8);
      uint4 pk;
      if (apply_bn) {
        int c = cbase + m * 8;
        float f0 = fmaxf(bflo(raw.x) * sc[c + 0] + sh[c + 0], 0.f);
        float f1 = fmaxf(bfhi(raw.x) * sc[c + 1] + sh[c + 1], 0.f);
        float f2 = fmaxf(bflo(raw.y) * sc[c + 2] + sh[c + 2], 0.f);
        float f3 = fmaxf(bfhi(raw.y) * sc[c + 3] + sh[c + 3], 0.f);
        float f4 = fmaxf(bflo(raw.z) * sc[c + 4] + sh[c + 4], 0.f);
        float f5 = fmaxf(bfhi(raw.z) * sc[c + 5] + sh[c + 5], 0.f);
        float f6 = fmaxf(bflo(raw.w) * sc[c + 6] + sh[c + 6], 0.f);
        float f7 = fmaxf(bfhi(raw.w) * sc[c + 7] + sh[c + 7], 0.f);
        pk.x = (unsigned)f2bf(f0) | ((unsigned)f2bf(f1) << 16);
        pk.y = (unsigned)f2bf(f2) | ((unsigned)f2bf(f3) << 16);
        pk.z = (unsigned)f2bf(f4) | ((unsigned)f2bf(f5) << 16);
        pk.w = (unsigned)f2bf(f6) | ((unsigned)f2bf(f7) << 16);
      } else {
        pk = raw;   // x already bf16, no BN on layer 0
      }
      *(uint4*)(As + ((ubase + m * 4) ^ swz)) = pk;
    }
  }
  __syncthreads();

  int w = tid >> 6, lane = tid & 63;
  int wrow = (w << 4) + (lane & 15);
  unsigned int aswz = (unsigned)((wrow & 7) << 2);
  floatx4 accT[8] = {}, accR[8] = {};

  #pragma unroll
  for (int ks = 0; ks < 4; ks++) {
    unsigned int aoff = (unsigned)(wrow * 64 + ks * 16 + ((lane >> 4) << 2)) ^ aswz;
    short8 a = *(const short8*)(As + aoff);
    #pragma unroll
    for (int cf = 0; cf < 8; cf++) {
      int wo = ((ks * 8 + cf) * 64 + lane) * 8;
      short8 wl = *(const short8*)(Wlp + wo);
      short8 wr = *(const short8*)(Wrp + wo);
      accT[cf] = __builtin_amdgcn_mfma_f32_16x16x32_bf16(a, wl, accT[cf], 0, 0, 0);
      accR[cf] = __builtin_amdgcn_mfma_f32_16x16x32_bf16(a, wr, accR[cf], 0, 0, 0);
    }
  }

  int colb = lane & 15;
  int rb = row0 + (w << 4) + ((lane >> 4) << 2);
  #pragma unroll
  for (int cf = 0; cf < 8; cf++) {
    int col = cf * 16 + colb;
    float bv = bias[col];
    #pragma unroll
    for (int i = 0; i < 4; i++) {
      int r = rb + i;
      if (r < n) {
        Tb[(size_t)r * 128 + col] = f2bf(accT[cf][i]);
        R[(size_t)r * 128 + col] = accR[cf][i] + bv;
      }
    }
  }
}

// ---------------- aggregate: Hb[i] = bf16(R[i] + mean_{j in N(i)} Tb[j]); BN stats ----------------
__global__ __launch_bounds__(256) void k_aggregate(
    const unsigned short* __restrict__ Tb, const float* __restrict__ R,
    unsigned short* __restrict__ Hb, const int* __restrict__ row_ptr,
    const int* __restrict__ csr, float* __restrict__ stats, int n) {
  __shared__ float sred[4][256];
  int lane = threadIdx.x & 63;
  int wlocal = threadIdx.x >> 6;
  int wid = (blockIdx.x * blockDim.x + threadIdx.x) >> 6;
  int nw = (gridDim.x * blockDim.x) >> 6;
  float sx = 0.f, sy = 0.f, qx = 0.f, qy = 0.f;

  for (int i = wid; i < n; i += nw) {
    int beg = row_ptr[i], end = row_ptr[i + 1];
    float ax = 0.f, ay = 0.f;
    int e = beg;
    for (; e + 8 <= end; e += 8) {
      int j0 = csr[e + 0], j1 = csr[e + 1], j2 = csr[e + 2], j3 = csr[e + 3];
      int j4 = csr[e + 4], j5 = csr[e + 5], j6 = csr[e + 6], j7 = csr[e + 7];
      unsigned int v0 = *(const unsigned int*)(Tb + (size_t)j0 * 128 + lane * 2);
      unsigned int v1 = *(const unsigned int*)(Tb + (size_t)j1 * 128 + lane * 2);
      unsigned int v2 = *(const unsigned int*)(Tb + (size_t)j2 * 128 + lane * 2);
      unsigned int v3 = *(const unsigned int*)(Tb + (size_t)j3 * 128 + lane * 2);
      unsigned int v4 = *(const unsigned int*)(Tb + (size_t)j4 * 128 + lane * 2);
      unsigned int v5 = *(const unsigned int*)(Tb + (size_t)j5 * 128 + lane * 2);
      unsigned int v6 = *(const unsigned int*)(Tb + (size_t)j6 * 128 + lane * 2);
      unsigned int v7 = *(const unsigned int*)(Tb + (size_t)j7 * 128 + lane * 2);
      ax += bflo(v0) + bflo(v1) + bflo(v2) + bflo(v3) +
            bflo(v4) + bflo(v5) + bflo(v6) + bflo(v7);
      ay += bfhi(v0) + bfhi(v1) + bfhi(v2) + bfhi(v3) +
            bfhi(v4) + bfhi(v5) + bfhi(v6) + bfhi(v7);
    }
    for (; e < end; e++) {
      int j = csr[e];
      unsigned int v = *(const unsigned int*)(Tb + (size_t)j * 128 + lane * 2);
      ax += bflo(v);
      ay += bfhi(v);
    }
    int deg = end - beg;
    float inv = (deg > 0) ? (1.0f / (float)deg) : 0.0f;
    float2 rv = *(const float2*)(R + (size_t)i * 128 + lane * 2);
    float hx = rv.x + ax * inv;
    float hy = rv.y + ay * inv;
    unsigned int pk = (unsigned)f2bf(hx) | ((unsigned)f2bf(hy) << 16);
    *(unsigned int*)(Hb + (size_t)i * 128 + lane * 2) = pk;
    sx += hx; sy += hy;
    qx += hx * hx; qy += hy * hy;
  }

  sred[wlocal][lane * 4 + 0] = sx;
  sred[wlocal][lane * 4 + 1] = sy;
  sred[wlocal][lane * 4 + 2] = qx;
  sred[wlocal][lane * 4 + 3] = qy;
  __syncthreads();
  int tid = threadIdx.x;
  float tot = sred[0][tid] + sred[1][tid] + sred[2][tid] + sred[3][tid];
  int l = tid >> 2;
  int k = tid & 3;
  int idx = (k < 2) ? (l * 2 + k) : (128 + l * 2 + (k - 2));
  atomicAdd(&stats[idx], tot);
}

// ---------------- final: Out = bn_relu(Hb) @ Wout + bout ----------------
__global__ __launch_bounds__(256) void k_gemm_out(
    const unsigned short* __restrict__ Hb, const float* __restrict__ W,
    const float* __restrict__ bias, const float* __restrict__ stats,
    const float* __restrict__ gamma, const float* __restrict__ beta,
    float* __restrict__ Out, int nrows) {
  __shared__ float As[64 * 132];
  __shared__ float sc[128], sh[128];
  int tid = threadIdx.x;
  if (tid < 128) {
    float invn = 1.0f / (float)nrows;
    float mu = stats[tid] * invn;
    float var = stats[128 + tid] * invn - mu * mu;
    float s = rsqrtf(var + BN_EPS) * gamma[tid];
    sc[tid] = s;
    sh[tid] = beta[tid] - mu * s;
  }
  __syncthreads();
  int row0 = blockIdx.x * 64;
  #pragma unroll
  for (int i = 0; i < 4; i++) {
    int g = tid + i * 256;
    int r = g >> 4;
    int c8 = g & 15;
    uint4 raw = make_uint4(0u, 0u, 0u, 0u);
    if (row0 + r < nrows)
      raw = *(const uint4*)(Hb + (size_t)(row0 + r) * 128 + c8 * 8);
    int c = c8 * 8;
    float* dstp = As + r * 132 + c;
    dstp[0] = fmaxf(bflo(raw.x) * sc[c + 0] + sh[c + 0], 0.f);
    dstp[1] = fmaxf(bfhi(raw.x) * sc[c + 1] + sh[c + 1], 0.f);
    dstp[2] = fmaxf(bflo(raw.y) * sc[c + 2] + sh[c + 2], 0.f);
    dstp[3] = fmaxf(bfhi(raw.y) * sc[c + 3] + sh[c + 3], 0.f);
    dstp[4] = fmaxf(bflo(raw.z) * sc[c + 4] + sh[c + 4], 0.f);
    dstp[5] = fmaxf(bfhi(raw.z) * sc[c + 5] + sh[c + 5], 0.f);
    dstp[6] = fmaxf(bflo(raw.w) * sc[c + 6] + sh[c + 6], 0.f);
    dstp[7] = fmaxf(bfhi(raw.w) * sc[c + 7] + sh[c + 7], 0.f);
  }
  __syncthreads();

  int cg = tid & 7;
  int rg = tid >> 3;
  float acc[2][4] = {};
  for (int k = 0; k < 128; k++) {
    float4 w = *(const float4*)(W + k * 32 + cg * 4);
    float a0 = As[(rg * 2 + 0) * 132 + k];
    float a1 = As[(rg * 2 + 1) * 132 + k];
    acc[0][0] += a0 * w.x; acc[0][1] += a0 * w.y; acc[0][2] += a0 * w.z; acc[0][3] += a0 * w.w;
    acc[1][0] += a1 * w.x; acc[1][1] += a1 * w.y; acc[1][2] += a1 * w.z; acc[1][3] += a1 * w.w;
  }
  float4 bv = *(const float4*)(bias + cg * 4);
  #pragma unroll
  for (int i = 0; i < 2; i++) {
    int r = row0 + rg * 2 + i;
    if (r < nrows) {
      float4 o = make_float4(acc[i][0] + bv.x, acc[i][1] + bv.y,
                             acc[i][2] + bv.z, acc[i][3] + bv.w);
      *(float4*)(Out + (size_t)r * 32 + cg * 4) = o;
    }
  }
}

extern "C" void kernel_launch(void* const* d_in, const int* in_sizes, int n_in,
                              void* d_out, int out_size, void* d_ws, size_t ws_size,
                              hipStream_t stream) {
  const float* x    = (const float*)d_in[0];
  const int*   e_sp = (const int*)d_in[1];
  const int*   e_tp = (const int*)d_in[2];
  const float* Wl[4]  = {(const float*)d_in[3],  (const float*)d_in[8],
                         (const float*)d_in[13], (const float*)d_in[18]};
  const float* Wr[4]  = {(const float*)d_in[4],  (const float*)d_in[9],
                         (const float*)d_in[14], (const float*)d_in[19]};
  const float* bb[4]  = {(const float*)d_in[5],  (const float*)d_in[10],
                         (const float*)d_in[15], (const float*)d_in[20]};
  const float* gm[4]  = {(const float*)d_in[6],  (const float*)d_in[11],
                         (const float*)d_in[16], (const float*)d_in[21]};
  const float* bt[4]  = {(const float*)d_in[7],  (const float*)d_in[12],
                         (const float*)d_in[17], (const float*)d_in[22]};
  const float* Wout = (const float*)d_in[23];
  const float* bout = (const float*)d_in[24];

  const int N = in_sizes[0] / 128;
  const int E = in_sizes[1] / 2;
  const int nbins = (N + ((1 << BSHIFT) - 1)) >> BSHIFT;   // 196 for N=100000

  char* ws = (char*)d_ws;
  size_t off = 0;
  auto alloc = [&](size_t bytes) {
    void* p = ws + off;
    off += (bytes + 255) & ~(size_t)255;
    return p;
  };
  unsigned short* Hb = (unsigned short*)alloc((size_t)N * 128 * 2);  // h (bf16)
  unsigned short* xb = (unsigned short*)alloc((size_t)N * 128 * 2);  // x (bf16)
  float* C  = (float*)alloc((size_t)N * 128 * 4);                    // r (f32)
  unsigned short* Tb = (unsigned short*)alloc((size_t)N * 128 * 2);  // t (bf16)
  int* row_sp    = (int*)alloc((size_t)(N + 1) * 4);
  int* row_tp    = (int*)alloc((size_t)(N + 1) * 4);
  int* csr_sp    = (int*)alloc((size_t)E * 4);
  int* csr_tp    = (int*)alloc((size_t)E * 4);
  int* binCount  = (int*)alloc(256 * 4);
  int* binBase   = (int*)alloc(257 * 4);
  float* statsB  = (float*)alloc(4 * 256 * 4);
  unsigned short* Wlp[4], *Wrp[4];
  for (int l = 0; l < 4; l++) {
    Wlp[l] = (unsigned short*)alloc(16384 * 2);
    Wrp[l] = (unsigned short*)alloc(16384 * 2);
  }
  // binbuf aliases C: CSR build completes before any GEMM writes C.
  long long* binbuf = (long long*)C;   // needs nbins*BINCAP*8 = 16.1 MB <= 51.2 MB

  const int pb = (E + 8191) / 8192;

  for (int l = 0; l < 4; l++) {
    k_wpack<<<64, 256, 0, stream>>>(Wl[l], Wlp[l]);
    k_wpack<<<64, 256, 0, stream>>>(Wr[l], Wrp[l]);
  }
  k_f2bf_arr<<<(int)(((size_t)N * 16 + 255) / 256), 256, 0, stream>>>(x, xb, (size_t)N * 16);
  hipMemsetAsync(statsB, 0, 4 * 256 * 4, stream);

  // ---- build CSR (spatial) ----
  hipMemsetAsync(binCount, 0, 256 * 4, stream);
  k_bin_pairs<<<pb, 1024, 0, stream>>>(e_sp, e_sp + E, binCount, binbuf, E, nbins);
  k_binscan<<<1, 256, 0, stream>>>(binCount, binBase, row_sp, nbins, N, E);
  k_csr_bin<<<nbins, 1024, 0, stream>>>(binbuf, binCount, binBase, row_sp, csr_sp, N);

  // ---- build CSR (temporal) ----
  hipMemsetAsync(binCount, 0, 256 * 4, stream);
  k_bin_pairs<<<pb, 1024, 0, stream>>>(e_tp, e_tp + E, binCount, binbuf, E, nbins);
  k_binscan<<<1, 256, 0, stream>>>(binCount, binBase, row_tp, nbins, N, E);
  k_csr_bin<<<nbins, 1024, 0, stream>>>(binbuf, binCount, binBase, row_tp, csr_tp, N);

  const int* rowp[4] = {row_sp, row_sp, row_tp, row_tp};
  const int* csr[4]  = {csr_sp, csr_sp, csr_tp, csr_tp};

  const int gblocks = (N + 63) / 64;
  const unsigned short* cur = xb;
  for (int l = 0; l < 4; l++) {
    const float* st = (l == 0) ? statsB : (statsB + (l - 1) * 256);
    const float* g  = (l == 0) ? gm[0] : gm[l - 1];
    const float* be = (l == 0) ? bt[0] : bt[l - 1];
    k_bn_gemm_dual<<<gblocks, 256, 0, stream>>>(cur, Wlp[l], Wrp[l], bb[l],
                                                st, g, be, Tb, C, N, l == 0 ? 0 : 1);
    k_aggregate<<<2048, 256, 0, stream>>>(Tb, C, Hb, rowp[l], csr[l],
                                          statsB + l * 256, N);
    cur = Hb;
  }
  k_gemm_out<<<gblocks, 256, 0, stream>>>(Hb, Wout, bout, statsB + 3 * 256,
                                          gm[3], bt[3], (float*)d_out, N);
}

// Round 6
// 715.937 us; speedup vs baseline: 3.3491x; 1.0233x over previous
//
#include <hip/hip_runtime.h>

#define BN_EPS 1e-5f
#define BSHIFT 9              // nodes per bin = 512
#define BINCAP 10240          // >22 sigma above mean 8192 edges/bin

typedef __attribute__((ext_vector_type(8))) short short8;
typedef __attribute__((ext_vector_type(4))) float floatx4;

__device__ inline unsigned short f2bf(float x) {
  unsigned int u = __float_as_uint(x);
  u += 0x7fffu + ((u >> 16) & 1u);
  return (unsigned short)(u >> 16);
}
__device__ inline float bflo(unsigned int v) { return __uint_as_float(v << 16); }
__device__ inline float bfhi(unsigned int v) { return __uint_as_float(v & 0xffff0000u); }

// ---------------- f32 -> bf16 array ----------------
__global__ void k_f2bf_arr(const float* __restrict__ in, unsigned short* __restrict__ out,
                           long long n8) {
  long long i = blockIdx.x * 256LL + threadIdx.x;
  if (i < n8) {
    float4 a = *(const float4*)(in + i * 8);
    float4 b = *(const float4*)(in + i * 8 + 4);
    ushort4 lo, hi;
    lo.x = f2bf(a.x); lo.y = f2bf(a.y); lo.z = f2bf(a.z); lo.w = f2bf(a.w);
    hi.x = f2bf(b.x); hi.y = f2bf(b.y); hi.z = f2bf(b.z); hi.w = f2bf(b.w);
    *(ushort4*)(out + i * 8) = lo;
    *(ushort4*)(out + i * 8 + 4) = hi;
  }
}

// ---------------- weight pack: W[128][128] f32 -> bf16 fragment layout ----------------
__global__ void k_wpack(const float* __restrict__ W, unsigned short* __restrict__ Wp) {
  int o = blockIdx.x * 256 + threadIdx.x;
  int j = o & 7, l = (o >> 3) & 63, cf = (o >> 9) & 7, ks = o >> 12;
  int k = ks * 32 + (l >> 4) * 8 + j;
  int col = cf * 16 + (l & 15);
  Wp[o] = f2bf(W[k * 128 + col]);
}

// ---------------- CSR build: atomic-free binned counting sort ----------------
__global__ __launch_bounds__(1024) void k_bin_pairs(
    const int* __restrict__ src, const int* __restrict__ dst,
    int* __restrict__ binCount, long long* __restrict__ binbuf, int E, int nbins) {
  __shared__ int hist[256], base[256];
  int tid = threadIdx.x;
  int b0 = blockIdx.x * 8192;
  if (tid < 256) hist[tid] = 0;
  __syncthreads();
  int s[8], d[8], rk[8], bn[8];
  #pragma unroll
  for (int i = 0; i < 8; i++) {
    int e = b0 + tid + i * 1024;
    if (e < E) {
      s[i] = src[e];
      d[i] = dst[e];
      bn[i] = d[i] >> BSHIFT;
      rk[i] = atomicAdd(&hist[bn[i]], 1);
    }
  }
  __syncthreads();
  if (tid < nbins && hist[tid] > 0)
    base[tid] = atomicAdd(&binCount[tid], hist[tid]);
  __syncthreads();
  #pragma unroll
  for (int i = 0; i < 8; i++) {
    int e = b0 + tid + i * 1024;
    if (e < E)
      binbuf[(size_t)bn[i] * BINCAP + base[bn[i]] + rk[i]] =
          ((long long)d[i] << 32) | (unsigned int)s[i];
  }
}

__global__ void k_binscan(const int* __restrict__ binCount, int* __restrict__ binBase,
                          int* __restrict__ row_ptr, int nbins, int N, int E) {
  __shared__ int sd[256];
  int tid = threadIdx.x;
  int v = (tid < nbins) ? binCount[tid] : 0;
  sd[tid] = v;
  __syncthreads();
  for (int off = 1; off < 256; off <<= 1) {
    int t = (tid >= off) ? sd[tid - off] : 0;
    __syncthreads();
    sd[tid] += t;
    __syncthreads();
  }
  if (tid < nbins) binBase[tid] = sd[tid] - v;
  if (tid == nbins) binBase[nbins] = sd[nbins - 1];
  if (tid == 0) row_ptr[N] = E;
}

__global__ __launch_bounds__(1024) void k_csr_bin(
    const long long* __restrict__ binbuf, const int* __restrict__ binCount,
    const int* __restrict__ binBase, int* __restrict__ row_ptr,
    int* __restrict__ csr, int N) {
  __shared__ int hist[512];
  __shared__ int incl[512];
  int b = blockIdx.x;
  int tid = threadIdx.x;
  int nE = binCount[b];
  int eb = binBase[b];
  const long long* p = binbuf + (size_t)b * BINCAP;
  if (tid < 512) hist[tid] = 0;
  __syncthreads();
  for (int e = tid; e < nE; e += 1024) {
    int d = (int)(p[e] >> 32);
    atomicAdd(&hist[d & 511], 1);
  }
  __syncthreads();
  if (tid < 512) incl[tid] = hist[tid];
  __syncthreads();
  for (int off = 1; off < 512; off <<= 1) {
    int t = 0;
    if (tid < 512 && tid >= off) t = incl[tid - off];
    __syncthreads();
    if (tid < 512) incl[tid] += t;
    __syncthreads();
  }
  int node0 = b << BSHIFT;
  if (tid < 512) {
    int ex = incl[tid] - hist[tid];
    if (node0 + tid < N) row_ptr[node0 + tid] = eb + ex;
    hist[tid] = ex;             // reuse as bin-local cursor
  }
  __syncthreads();
  for (int e = tid; e < nE; e += 1024) {
    long long pr = p[e];
    int d = ((int)(pr >> 32)) & 511;
    int sv = (int)(pr & 0xffffffffLL);
    int r = atomicAdd(&hist[d], 1);
    csr[eb + r] = sv;
  }
}

// ---------------- fused BN(+ReLU) -> dual MFMA GEMM (bf16 in, bf16 out x2) ----------------
__global__ __launch_bounds__(256) void k_bn_gemm_dual(
    const unsigned short* __restrict__ Hb, const unsigned short* __restrict__ Wlp,
    const unsigned short* __restrict__ Wrp, const float* __restrict__ bias,
    const float* __restrict__ stats, const float* __restrict__ gamma,
    const float* __restrict__ beta, unsigned short* __restrict__ Tb,
    unsigned short* __restrict__ Rb, int n, int apply_bn) {
  __shared__ unsigned int As[64 * 64];   // 64 rows x 128 bf16, XOR-swizzled
  __shared__ float sc[128], sh[128];
  int tid = threadIdx.x;
  if (tid < 128) {
    if (apply_bn) {
      float invn = 1.0f / (float)n;
      float mu = stats[tid] * invn;
      float var = stats[128 + tid] * invn - mu * mu;
      float s = rsqrtf(var + BN_EPS) * gamma[tid];
      sc[tid] = s;
      sh[tid] = beta[tid] - mu * s;
    }
  }
  __syncthreads();

  int row0 = blockIdx.x * 64;
  {
    int r = tid >> 2, cbase = (tid & 3) * 32;
    const unsigned short* srcp = Hb + (size_t)(row0 + r) * 128 + cbase;
    bool valid = (row0 + r) < n;
    unsigned int swz = (unsigned)((r & 7) << 2);
    unsigned int ubase = (unsigned)(r * 64 + (cbase >> 1));
    #pragma unroll
    for (int m = 0; m < 4; m++) {
      uint4 raw = make_uint4(0u, 0u, 0u, 0u);
      if (valid) raw = *(const uint4*)(srcp + m * 8);
      uint4 pk;
      if (apply_bn) {
        int c = cbase + m * 8;
        float f0 = fmaxf(bflo(raw.x) * sc[c + 0] + sh[c + 0], 0.f);
        float f1 = fmaxf(bfhi(raw.x) * sc[c + 1] + sh[c + 1], 0.f);
        float f2 = fmaxf(bflo(raw.y) * sc[c + 2] + sh[c + 2], 0.f);
        float f3 = fmaxf(bfhi(raw.y) * sc[c + 3] + sh[c + 3], 0.f);
        float f4 = fmaxf(bflo(raw.z) * sc[c + 4] + sh[c + 4], 0.f);
        float f5 = fmaxf(bfhi(raw.z) * sc[c + 5] + sh[c + 5], 0.f);
        float f6 = fmaxf(bflo(raw.w) * sc[c + 6] + sh[c + 6], 0.f);
        float f7 = fmaxf(bfhi(raw.w) * sc[c + 7] + sh[c + 7], 0.f);
        pk.x = (unsigned)f2bf(f0) | ((unsigned)f2bf(f1) << 16);
        pk.y = (unsigned)f2bf(f2) | ((unsigned)f2bf(f3) << 16);
        pk.z = (unsigned)f2bf(f4) | ((unsigned)f2bf(f5) << 16);
        pk.w = (unsigned)f2bf(f6) | ((unsigned)f2bf(f7) << 16);
      } else {
        pk = raw;   // x already bf16, no BN on layer 0
      }
      *(uint4*)(As + ((ubase + m * 4) ^ swz)) = pk;
    }
  }
  __syncthreads();

  int w = tid >> 6, lane = tid & 63;
  int wrow = (w << 4) + (lane & 15);
  unsigned int aswz = (unsigned)((wrow & 7) << 2);
  floatx4 accT[8] = {}, accR[8] = {};

  #pragma unroll
  for (int ks = 0; ks < 4; ks++) {
    unsigned int aoff = (unsigned)(wrow * 64 + ks * 16 + ((lane >> 4) << 2)) ^ aswz;
    short8 a = *(const short8*)(As + aoff);
    #pragma unroll
    for (int cf = 0; cf < 8; cf++) {
      int wo = ((ks * 8 + cf) * 64 + lane) * 8;
      short8 wl = *(const short8*)(Wlp + wo);
      short8 wr = *(const short8*)(Wrp + wo);
      accT[cf] = __builtin_amdgcn_mfma_f32_16x16x32_bf16(a, wl, accT[cf], 0, 0, 0);
      accR[cf] = __builtin_amdgcn_mfma_f32_16x16x32_bf16(a, wr, accR[cf], 0, 0, 0);
    }
  }

  int colb = lane & 15;
  int rb = row0 + (w << 4) + ((lane >> 4) << 2);
  #pragma unroll
  for (int cf = 0; cf < 8; cf++) {
    int col = cf * 16 + colb;
    float bv = bias[col];
    #pragma unroll
    for (int i = 0; i < 4; i++) {
      int r = rb + i;
      if (r < n) {
        Tb[(size_t)r * 128 + col] = f2bf(accT[cf][i]);
        Rb[(size_t)r * 128 + col] = f2bf(accR[cf][i] + bv);
      }
    }
  }
}

// ---------------- aggregate: Hb[i] = bf16(Rb[i] + mean_{j in N(i)} Tb[j]); BN stats ----------------
// Half-wave per edge: 32 lanes x uint2 (8B) cover a 256B row; csr indices
// lane-loaded once per 64-edge batch and broadcast via shfl (no uniform-load RT).
__global__ __launch_bounds__(256) void k_aggregate(
    const unsigned short* __restrict__ Tb, const unsigned short* __restrict__ Rb,
    unsigned short* __restrict__ Hb, const int* __restrict__ row_ptr,
    const int* __restrict__ csr, float* __restrict__ stats, int n) {
  __shared__ float sred[4][256];
  int tid = threadIdx.x;
  int lane = tid & 63;
  int half = lane >> 5;
  int sl = lane & 31;            // features sl*4 .. sl*4+3
  int wlocal = tid >> 6;
  int wid = (blockIdx.x * blockDim.x + tid) >> 6;
  int nw = (gridDim.x * blockDim.x) >> 6;
  float s0 = 0, s1 = 0, s2 = 0, s3 = 0, q0 = 0, q1 = 0, q2 = 0, q3 = 0;

  for (int i = wid; i < n; i += nw) {
    int beg = row_ptr[i], end = row_ptr[i + 1];
    float a0 = 0, a1 = 0, a2 = 0, a3 = 0;
    for (int base = beg; base < end; base += 64) {
      int cnt = end - base;
      if (cnt > 64) cnt = 64;
      int myidx = 0;
      if (lane < cnt) myidx = csr[base + lane];
      for (int k = 0; k < cnt; k += 16) {
        #pragma unroll
        for (int m = 0; m < 8; m++) {
          int ls = k + half + 2 * m;
          int j = __shfl(myidx, ls);
          if (ls < cnt) {
            uint2 v = *(const uint2*)(Tb + (size_t)j * 128 + sl * 4);
            a0 += bflo(v.x); a1 += bfhi(v.x);
            a2 += bflo(v.y); a3 += bfhi(v.y);
          }
        }
      }
    }
    a0 += __shfl_xor(a0, 32);
    a1 += __shfl_xor(a1, 32);
    a2 += __shfl_xor(a2, 32);
    a3 += __shfl_xor(a3, 32);
    if (half == 0) {
      int deg = end - beg;
      float inv = (deg > 0) ? (1.0f / (float)deg) : 0.0f;
      uint2 rv = *(const uint2*)(Rb + (size_t)i * 128 + sl * 4);
      float h0 = bflo(rv.x) + a0 * inv;
      float h1 = bfhi(rv.x) + a1 * inv;
      float h2 = bflo(rv.y) + a2 * inv;
      float h3 = bfhi(rv.y) + a3 * inv;
      uint2 pk;
      pk.x = (unsigned)f2bf(h0) | ((unsigned)f2bf(h1) << 16);
      pk.y = (unsigned)f2bf(h2) | ((unsigned)f2bf(h3) << 16);
      *(uint2*)(Hb + (size_t)i * 128 + sl * 4) = pk;
      s0 += h0; s1 += h1; s2 += h2; s3 += h3;
      q0 += h0 * h0; q1 += h1 * h1; q2 += h2 * h2; q3 += h3 * h3;
    }
  }

  if (half == 0) {
    sred[wlocal][sl * 8 + 0] = s0; sred[wlocal][sl * 8 + 1] = s1;
    sred[wlocal][sl * 8 + 2] = s2; sred[wlocal][sl * 8 + 3] = s3;
    sred[wlocal][sl * 8 + 4] = q0; sred[wlocal][sl * 8 + 5] = q1;
    sred[wlocal][sl * 8 + 6] = q2; sred[wlocal][sl * 8 + 7] = q3;
  }
  __syncthreads();
  float tot = sred[0][tid] + sred[1][tid] + sred[2][tid] + sred[3][tid];
  int slx = tid >> 3, k2 = tid & 7;
  int f = slx * 4 + (k2 & 3);
  int idx = (k2 >> 2) ? (128 + f) : f;
  atomicAdd(&stats[idx], tot);
}

// ---------------- final: Out = bn_relu(Hb) @ Wout + bout ----------------
__global__ __launch_bounds__(256) void k_gemm_out(
    const unsigned short* __restrict__ Hb, const float* __restrict__ W,
    const float* __restrict__ bias, const float* __restrict__ stats,
    const float* __restrict__ gamma, const float* __restrict__ beta,
    float* __restrict__ Out, int nrows) {
  __shared__ float As[64 * 132];
  __shared__ float sc[128], sh[128];
  int tid = threadIdx.x;
  if (tid < 128) {
    float invn = 1.0f / (float)nrows;
    float mu = stats[tid] * invn;
    float var = stats[128 + tid] * invn - mu * mu;
    float s = rsqrtf(var + BN_EPS) * gamma[tid];
    sc[tid] = s;
    sh[tid] = beta[tid] - mu * s;
  }
  __syncthreads();
  int row0 = blockIdx.x * 64;
  #pragma unroll
  for (int i = 0; i < 4; i++) {
    int g = tid + i * 256;
    int r = g >> 4;
    int c8 = g & 15;
    uint4 raw = make_uint4(0u, 0u, 0u, 0u);
    if (row0 + r < nrows)
      raw = *(const uint4*)(Hb + (size_t)(row0 + r) * 128 + c8 * 8);
    int c = c8 * 8;
    float* dstp = As + r * 132 + c;
    dstp[0] = fmaxf(bflo(raw.x) * sc[c + 0] + sh[c + 0], 0.f);
    dstp[1] = fmaxf(bfhi(raw.x) * sc[c + 1] + sh[c + 1], 0.f);
    dstp[2] = fmaxf(bflo(raw.y) * sc[c + 2] + sh[c + 2], 0.f);
    dstp[3] = fmaxf(bfhi(raw.y) * sc[c + 3] + sh[c + 3], 0.f);
    dstp[4] = fmaxf(bflo(raw.z) * sc[c + 4] + sh[c + 4], 0.f);
    dstp[5] = fmaxf(bfhi(raw.z) * sc[c + 5] + sh[c + 5], 0.f);
    dstp[6] = fmaxf(bflo(raw.w) * sc[c + 6] + sh[c + 6], 0.f);
    dstp[7] = fmaxf(bfhi(raw.w) * sc[c + 7] + sh[c + 7], 0.f);
  }
  __syncthreads();

  int cg = tid & 7;
  int rg = tid >> 3;
  float acc[2][4] = {};
  for (int k = 0; k < 128; k++) {
    float4 w = *(const float4*)(W + k * 32 + cg * 4);
    float a0 = As[(rg * 2 + 0) * 132 + k];
    float a1 = As[(rg * 2 + 1) * 132 + k];
    acc[0][0] += a0 * w.x; acc[0][1] += a0 * w.y; acc[0][2] += a0 * w.z; acc[0][3] += a0 * w.w;
    acc[1][0] += a1 * w.x; acc[1][1] += a1 * w.y; acc[1][2] += a1 * w.z; acc[1][3] += a1 * w.w;
  }
  float4 bv = *(const float4*)(bias + cg * 4);
  #pragma unroll
  for (int i = 0; i < 2; i++) {
    int r = row0 + rg * 2 + i;
    if (r < nrows) {
      float4 o = make_float4(acc[i][0] + bv.x, acc[i][1] + bv.y,
                             acc[i][2] + bv.z, acc[i][3] + bv.w);
      *(float4*)(Out + (size_t)r * 32 + cg * 4) = o;
    }
  }
}

extern "C" void kernel_launch(void* const* d_in, const int* in_sizes, int n_in,
                              void* d_out, int out_size, void* d_ws, size_t ws_size,
                              hipStream_t stream) {
  const float* x    = (const float*)d_in[0];
  const int*   e_sp = (const int*)d_in[1];
  const int*   e_tp = (const int*)d_in[2];
  const float* Wl[4]  = {(const float*)d_in[3],  (const float*)d_in[8],
                         (const float*)d_in[13], (const float*)d_in[18]};
  const float* Wr[4]  = {(const float*)d_in[4],  (const float*)d_in[9],
                         (const float*)d_in[14], (const float*)d_in[19]};
  const float* bb[4]  = {(const float*)d_in[5],  (const float*)d_in[10],
                         (const float*)d_in[15], (const float*)d_in[20]};
  const float* gm[4]  = {(const float*)d_in[6],  (const float*)d_in[11],
                         (const float*)d_in[16], (const float*)d_in[21]};
  const float* bt[4]  = {(const float*)d_in[7],  (const float*)d_in[12],
                         (const float*)d_in[17], (const float*)d_in[22]};
  const float* Wout = (const float*)d_in[23];
  const float* bout = (const float*)d_in[24];

  const int N = in_sizes[0] / 128;
  const int E = in_sizes[1] / 2;
  const int nbins = (N + ((1 << BSHIFT) - 1)) >> BSHIFT;   // 196 for N=100000

  char* ws = (char*)d_ws;
  size_t off = 0;
  auto alloc = [&](size_t bytes) {
    void* p = ws + off;
    off += (bytes + 255) & ~(size_t)255;
    return p;
  };
  unsigned short* Hb = (unsigned short*)alloc((size_t)N * 128 * 2);  // h (bf16)
  unsigned short* xb = (unsigned short*)alloc((size_t)N * 128 * 2);  // x (bf16)
  unsigned short* Rb = (unsigned short*)alloc((size_t)N * 128 * 2);  // r (bf16)
  unsigned short* Tb = (unsigned short*)alloc((size_t)N * 128 * 2);  // t (bf16)
  int* row_sp    = (int*)alloc((size_t)(N + 1) * 4);
  int* row_tp    = (int*)alloc((size_t)(N + 1) * 4);
  int* csr_sp    = (int*)alloc((size_t)E * 4);
  int* csr_tp    = (int*)alloc((size_t)E * 4);
  long long* binbuf = (long long*)alloc((size_t)256 * BINCAP * 8);   // 21 MB
  int* binCount  = (int*)alloc(256 * 4);
  int* binBase   = (int*)alloc(257 * 4);
  float* statsB  = (float*)alloc(4 * 256 * 4);
  unsigned short* Wlp[4], *Wrp[4];
  for (int l = 0; l < 4; l++) {
    Wlp[l] = (unsigned short*)alloc(16384 * 2);
    Wrp[l] = (unsigned short*)alloc(16384 * 2);
  }

  const int pb = (E + 8191) / 8192;

  for (int l = 0; l < 4; l++) {
    k_wpack<<<64, 256, 0, stream>>>(Wl[l], Wlp[l]);
    k_wpack<<<64, 256, 0, stream>>>(Wr[l], Wrp[l]);
  }
  k_f2bf_arr<<<(int)(((size_t)N * 16 + 255) / 256), 256, 0, stream>>>(x, xb, (size_t)N * 16);
  hipMemsetAsync(statsB, 0, 4 * 256 * 4, stream);

  // ---- build CSR (spatial) ----
  hipMemsetAsync(binCount, 0, 256 * 4, stream);
  k_bin_pairs<<<pb, 1024, 0, stream>>>(e_sp, e_sp + E, binCount, binbuf, E, nbins);
  k_binscan<<<1, 256, 0, stream>>>(binCount, binBase, row_sp, nbins, N, E);
  k_csr_bin<<<nbins, 1024, 0, stream>>>(binbuf, binCount, binBase, row_sp, csr_sp, N);

  // ---- build CSR (temporal) ----
  hipMemsetAsync(binCount, 0, 256 * 4, stream);
  k_bin_pairs<<<pb, 1024, 0, stream>>>(e_tp, e_tp + E, binCount, binbuf, E, nbins);
  k_binscan<<<1, 256, 0, stream>>>(binCount, binBase, row_tp, nbins, N, E);
  k_csr_bin<<<nbins, 1024, 0, stream>>>(binbuf, binCount, binBase, row_tp, csr_tp, N);

  const int* rowp[4] = {row_sp, row_sp, row_tp, row_tp};
  const int* csr[4]  = {csr_sp, csr_sp, csr_tp, csr_tp};

  const int gblocks = (N + 63) / 64;
  const unsigned short* cur = xb;
  for (int l = 0; l < 4; l++) {
    const float* st = (l == 0) ? statsB : (statsB + (l - 1) * 256);
    const float* g  = (l == 0) ? gm[0] : gm[l - 1];
    const float* be = (l == 0) ? bt[0] : bt[l - 1];
    k_bn_gemm_dual<<<gblocks, 256, 0, stream>>>(cur, Wlp[l], Wrp[l], bb[l],
                                                st, g, be, Tb, Rb, N, l == 0 ? 0 : 1);
    k_aggregate<<<2048, 256, 0, stream>>>(Tb, Rb, Hb, rowp[l], csr[l],
                                          statsB + l * 256, N);
    cur = Hb;
  }
  k_gemm_out<<<gblocks, 256, 0, stream>>>(Hb, Wout, bout, statsB + 3 * 256,
                                          gm[3], bt[3], (float*)d_out, N);
}

// Round 7
// 699.425 us; speedup vs baseline: 3.4282x; 1.0236x over previous
//
#include <hip/hip_runtime.h>

#define BN_EPS 1e-5f
#define BSHIFT 9              // nodes per bin = 512
#define BINCAP 10240          // >22 sigma above mean 8192 edges/bin

typedef __attribute__((ext_vector_type(8))) short short8;
typedef __attribute__((ext_vector_type(4))) float floatx4;

__device__ inline unsigned short f2bf(float x) {
  unsigned int u = __float_as_uint(x);
  u += 0x7fffu + ((u >> 16) & 1u);
  return (unsigned short)(u >> 16);
}
__device__ inline float bflo(unsigned int v) { return __uint_as_float(v << 16); }
__device__ inline float bfhi(unsigned int v) { return __uint_as_float(v & 0xffff0000u); }

// ---------------- f32 -> bf16 array ----------------
__global__ void k_f2bf_arr(const float* __restrict__ in, unsigned short* __restrict__ out,
                           long long n8) {
  long long i = blockIdx.x * 256LL + threadIdx.x;
  if (i < n8) {
    float4 a = *(const float4*)(in + i * 8);
    float4 b = *(const float4*)(in + i * 8 + 4);
    ushort4 lo, hi;
    lo.x = f2bf(a.x); lo.y = f2bf(a.y); lo.z = f2bf(a.z); lo.w = f2bf(a.w);
    hi.x = f2bf(b.x); hi.y = f2bf(b.y); hi.z = f2bf(b.z); hi.w = f2bf(b.w);
    *(ushort4*)(out + i * 8) = lo;
    *(ushort4*)(out + i * 8 + 4) = hi;
  }
}

// ---------------- weight pack: W[128][128] f32 -> bf16 fragment layout ----------------
__global__ void k_wpack(const float* __restrict__ W, unsigned short* __restrict__ Wp) {
  int o = blockIdx.x * 256 + threadIdx.x;
  int j = o & 7, l = (o >> 3) & 63, cf = (o >> 9) & 7, ks = o >> 12;
  int k = ks * 32 + (l >> 4) * 8 + j;
  int col = cf * 16 + (l & 15);
  Wp[o] = f2bf(W[k * 128 + col]);
}

// ---------------- CSR build: atomic-free binned counting sort ----------------
// packed entry: (dst & 511) << 23 | src   (valid for N < 2^23)
__global__ __launch_bounds__(1024) void k_bin_pairs(
    const int* __restrict__ src, const int* __restrict__ dst,
    int* __restrict__ binCount, unsigned int* __restrict__ binbuf, int E, int nbins) {
  __shared__ int hist[256], base[256];
  int tid = threadIdx.x;
  int b0 = blockIdx.x * 8192;
  if (tid < 256) hist[tid] = 0;
  __syncthreads();
  int s[8], d[8], rk[8], bn[8];
  #pragma unroll
  for (int i = 0; i < 8; i++) {
    int e = b0 + tid + i * 1024;
    if (e < E) {
      s[i] = src[e];
      d[i] = dst[e];
      bn[i] = d[i] >> BSHIFT;
      rk[i] = atomicAdd(&hist[bn[i]], 1);
    }
  }
  __syncthreads();
  if (tid < nbins && hist[tid] > 0)
    base[tid] = atomicAdd(&binCount[tid], hist[tid]);
  __syncthreads();
  #pragma unroll
  for (int i = 0; i < 8; i++) {
    int e = b0 + tid + i * 1024;
    if (e < E)
      binbuf[(size_t)bn[i] * BINCAP + base[bn[i]] + rk[i]] =
          ((unsigned)(d[i] & 511) << 23) | (unsigned)s[i];
  }
}

__global__ void k_binscan(const int* __restrict__ binCount, int* __restrict__ binBase,
                          int* __restrict__ row_ptr, int nbins, int N, int E) {
  __shared__ int sd[256];
  int tid = threadIdx.x;
  int v = (tid < nbins) ? binCount[tid] : 0;
  sd[tid] = v;
  __syncthreads();
  for (int off = 1; off < 256; off <<= 1) {
    int t = (tid >= off) ? sd[tid - off] : 0;
    __syncthreads();
    sd[tid] += t;
    __syncthreads();
  }
  if (tid < nbins) binBase[tid] = sd[tid] - v;
  if (tid == nbins) binBase[nbins] = sd[nbins - 1];
  if (tid == 0) row_ptr[N] = E;
}

__global__ __launch_bounds__(1024) void k_csr_bin(
    const unsigned int* __restrict__ binbuf, const int* __restrict__ binCount,
    const int* __restrict__ binBase, int* __restrict__ row_ptr,
    int* __restrict__ csr, int N) {
  __shared__ int hist[512];
  __shared__ int incl[512];
  int b = blockIdx.x;
  int tid = threadIdx.x;
  int nE = binCount[b];
  int eb = binBase[b];
  const unsigned int* p = binbuf + (size_t)b * BINCAP;
  if (tid < 512) hist[tid] = 0;
  __syncthreads();
  for (int e = tid; e < nE; e += 1024) {
    int dl = (int)(p[e] >> 23);
    atomicAdd(&hist[dl], 1);
  }
  __syncthreads();
  if (tid < 512) incl[tid] = hist[tid];
  __syncthreads();
  for (int off = 1; off < 512; off <<= 1) {
    int t = 0;
    if (tid < 512 && tid >= off) t = incl[tid - off];
    __syncthreads();
    if (tid < 512) incl[tid] += t;
    __syncthreads();
  }
  int node0 = b << BSHIFT;
  if (tid < 512) {
    int ex = incl[tid] - hist[tid];
    if (node0 + tid < N) row_ptr[node0 + tid] = eb + ex;
    hist[tid] = ex;             // reuse as bin-local cursor
  }
  __syncthreads();
  for (int e = tid; e < nE; e += 1024) {
    unsigned int pr = p[e];
    int dl = (int)(pr >> 23);
    int sv = (int)(pr & 0x7fffffu);
    int r = atomicAdd(&hist[dl], 1);
    csr[eb + r] = sv;
  }
}

// ---------------- fused BN(+ReLU) -> dual MFMA GEMM (bf16 in, bf16 out x2) ----------------
__global__ __launch_bounds__(256) void k_bn_gemm_dual(
    const unsigned short* __restrict__ Hb, const unsigned short* __restrict__ Wlp,
    const unsigned short* __restrict__ Wrp, const float* __restrict__ bias,
    const float* __restrict__ stats, const float* __restrict__ gamma,
    const float* __restrict__ beta, unsigned short* __restrict__ Tb,
    unsigned short* __restrict__ Rb, int n, int apply_bn) {
  __shared__ unsigned int As[64 * 64];   // 64 rows x 128 bf16, XOR-swizzled
  __shared__ float sc[128], sh[128];
  int tid = threadIdx.x;
  if (tid < 128) {
    if (apply_bn) {
      float invn = 1.0f / (float)n;
      float mu = stats[tid] * invn;
      float var = stats[128 + tid] * invn - mu * mu;
      float s = rsqrtf(var + BN_EPS) * gamma[tid];
      sc[tid] = s;
      sh[tid] = beta[tid] - mu * s;
    }
  }
  __syncthreads();

  int row0 = blockIdx.x * 64;
  {
    int r = tid >> 2, cbase = (tid & 3) * 32;
    const unsigned short* srcp = Hb + (size_t)(row0 + r) * 128 + cbase;
    bool valid = (row0 + r) < n;
    unsigned int swz = (unsigned)((r & 7) << 2);
    unsigned int ubase = (unsigned)(r * 64 + (cbase >> 1));
    #pragma unroll
    for (int m = 0; m < 4; m++) {
      uint4 raw = make_uint4(0u, 0u, 0u, 0u);
      if (valid) raw = *(const uint4*)(srcp + m * 8);
      uint4 pk;
      if (apply_bn) {
        int c = cbase + m * 8;
        float f0 = fmaxf(bflo(raw.x) * sc[c + 0] + sh[c + 0], 0.f);
        float f1 = fmaxf(bfhi(raw.x) * sc[c + 1] + sh[c + 1], 0.f);
        float f2 = fmaxf(bflo(raw.y) * sc[c + 2] + sh[c + 2], 0.f);
        float f3 = fmaxf(bfhi(raw.y) * sc[c + 3] + sh[c + 3], 0.f);
        float f4 = fmaxf(bflo(raw.z) * sc[c + 4] + sh[c + 4], 0.f);
        float f5 = fmaxf(bfhi(raw.z) * sc[c + 5] + sh[c + 5], 0.f);
        float f6 = fmaxf(bflo(raw.w) * sc[c + 6] + sh[c + 6], 0.f);
        float f7 = fmaxf(bfhi(raw.w) * sc[c + 7] + sh[c + 7], 0.f);
        pk.x = (unsigned)f2bf(f0) | ((unsigned)f2bf(f1) << 16);
        pk.y = (unsigned)f2bf(f2) | ((unsigned)f2bf(f3) << 16);
        pk.z = (unsigned)f2bf(f4) | ((unsigned)f2bf(f5) << 16);
        pk.w = (unsigned)f2bf(f6) | ((unsigned)f2bf(f7) << 16);
      } else {
        pk = raw;   // x already bf16, no BN on layer 0
      }
      *(uint4*)(As + ((ubase + m * 4) ^ swz)) = pk;
    }
  }
  __syncthreads();

  int w = tid >> 6, lane = tid & 63;
  int wrow = (w << 4) + (lane & 15);
  unsigned int aswz = (unsigned)((wrow & 7) << 2);
  floatx4 accT[8] = {}, accR[8] = {};

  #pragma unroll
  for (int ks = 0; ks < 4; ks++) {
    unsigned int aoff = (unsigned)(wrow * 64 + ks * 16 + ((lane >> 4) << 2)) ^ aswz;
    short8 a = *(const short8*)(As + aoff);
    #pragma unroll
    for (int cf = 0; cf < 8; cf++) {
      int wo = ((ks * 8 + cf) * 64 + lane) * 8;
      short8 wl = *(const short8*)(Wlp + wo);
      short8 wr = *(const short8*)(Wrp + wo);
      accT[cf] = __builtin_amdgcn_mfma_f32_16x16x32_bf16(a, wl, accT[cf], 0, 0, 0);
      accR[cf] = __builtin_amdgcn_mfma_f32_16x16x32_bf16(a, wr, accR[cf], 0, 0, 0);
    }
  }

  int colb = lane & 15;
  int rb = row0 + (w << 4) + ((lane >> 4) << 2);
  #pragma unroll
  for (int cf = 0; cf < 8; cf++) {
    int col = cf * 16 + colb;
    float bv = bias[col];
    #pragma unroll
    for (int i = 0; i < 4; i++) {
      int r = rb + i;
      if (r < n) {
        Tb[(size_t)r * 128 + col] = f2bf(accT[cf][i]);
        Rb[(size_t)r * 128 + col] = f2bf(accR[cf][i] + bv);
      }
    }
  }
}

// ---------------- aggregate: Hb[i] = bf16(Rb[i] + mean_{j in N(i)} Tb[j]); BN stats ----------------
// Half-wave per edge (32 lanes x uint2 = 256B row). 2-deep software pipeline:
// row_ptr fetched 2 nodes ahead, csr indices + Rb row fetched 1 node ahead,
// so index-chain latency overlaps the previous node's gather burst.
__global__ __launch_bounds__(256) void k_aggregate(
    const unsigned short* __restrict__ Tb, const unsigned short* __restrict__ Rb,
    unsigned short* __restrict__ Hb, const int* __restrict__ row_ptr,
    const int* __restrict__ csr, float* __restrict__ stats, int n) {
  __shared__ float sred[4][256];
  int tid = threadIdx.x;
  int lane = tid & 63;
  int half = lane >> 5;
  int sl = lane & 31;            // features sl*4 .. sl*4+3
  int wlocal = tid >> 6;
  int wid = (blockIdx.x * blockDim.x + tid) >> 6;
  int nw = (gridDim.x * blockDim.x) >> 6;
  float s0 = 0, s1 = 0, s2 = 0, s3 = 0, q0 = 0, q1 = 0, q2 = 0, q3 = 0;

  int i = wid;
  int beg = 0, end = 0, myidx = 0;
  uint2 rv = make_uint2(0u, 0u);
  int begA = 0, endA = 0;
  if (i < n) {
    beg = row_ptr[i];
    end = row_ptr[i + 1];
    int c = end - beg; if (c > 64) c = 64;
    myidx = (lane < c) ? csr[beg + lane] : 0;
    if (half == 0) rv = *(const uint2*)(Rb + (size_t)i * 128 + sl * 4);
  }
  if (i + nw < n) {
    begA = row_ptr[i + nw];
    endA = row_ptr[i + nw + 1];
  }

  while (i < n) {
    int inext = i + nw;
    int innext = i + 2 * nw;
    // prefetch row_ptr two ahead (independent)
    int begB = 0, endB = 0;
    if (innext < n) {
      begB = row_ptr[innext];
      endB = row_ptr[innext + 1];
    }
    // prefetch csr + Rb one ahead (begA/endA already resident -> no wait)
    int myidx2 = 0;
    uint2 rv2 = make_uint2(0u, 0u);
    if (inext < n) {
      int c2 = endA - begA; if (c2 > 64) c2 = 64;
      myidx2 = (lane < c2) ? csr[begA + lane] : 0;
      if (half == 0) rv2 = *(const uint2*)(Rb + (size_t)inext * 128 + sl * 4);
    }

    float a0 = 0, a1 = 0, a2 = 0, a3 = 0;
    int cnt0 = end - beg; if (cnt0 > 64) cnt0 = 64;
    for (int k = 0; k < cnt0; k += 16) {
      #pragma unroll
      for (int m = 0; m < 8; m++) {
        int ls = k + half + 2 * m;
        int j = __shfl(myidx, ls);
        if (ls < cnt0) {
          uint2 v = *(const uint2*)(Tb + (size_t)j * 128 + sl * 4);
          a0 += bflo(v.x); a1 += bfhi(v.x);
          a2 += bflo(v.y); a3 += bfhi(v.y);
        }
      }
    }
    for (int base = beg + 64; base < end; base += 64) {   // rare tail (deg > 64)
      int cnt = end - base; if (cnt > 64) cnt = 64;
      int idx = (lane < cnt) ? csr[base + lane] : 0;
      for (int k = 0; k < cnt; k += 16) {
        #pragma unroll
        for (int m = 0; m < 8; m++) {
          int ls = k + half + 2 * m;
          int j = __shfl(idx, ls);
          if (ls < cnt) {
            uint2 v = *(const uint2*)(Tb + (size_t)j * 128 + sl * 4);
            a0 += bflo(v.x); a1 += bfhi(v.x);
            a2 += bflo(v.y); a3 += bfhi(v.y);
          }
        }
      }
    }
    a0 += __shfl_xor(a0, 32);
    a1 += __shfl_xor(a1, 32);
    a2 += __shfl_xor(a2, 32);
    a3 += __shfl_xor(a3, 32);
    if (half == 0) {
      int deg = end - beg;
      float inv = (deg > 0) ? (1.0f / (float)deg) : 0.0f;
      float h0 = bflo(rv.x) + a0 * inv;
      float h1 = bfhi(rv.x) + a1 * inv;
      float h2 = bflo(rv.y) + a2 * inv;
      float h3 = bfhi(rv.y) + a3 * inv;
      uint2 pk;
      pk.x = (unsigned)f2bf(h0) | ((unsigned)f2bf(h1) << 16);
      pk.y = (unsigned)f2bf(h2) | ((unsigned)f2bf(h3) << 16);
      *(uint2*)(Hb + (size_t)i * 128 + sl * 4) = pk;
      s0 += h0; s1 += h1; s2 += h2; s3 += h3;
      q0 += h0 * h0; q1 += h1 * h1; q2 += h2 * h2; q3 += h3 * h3;
    }
    i = inext;
    beg = begA; end = endA; myidx = myidx2; rv = rv2;
    begA = begB; endA = endB;
  }

  if (half == 0) {
    sred[wlocal][sl * 8 + 0] = s0; sred[wlocal][sl * 8 + 1] = s1;
    sred[wlocal][sl * 8 + 2] = s2; sred[wlocal][sl * 8 + 3] = s3;
    sred[wlocal][sl * 8 + 4] = q0; sred[wlocal][sl * 8 + 5] = q1;
    sred[wlocal][sl * 8 + 6] = q2; sred[wlocal][sl * 8 + 7] = q3;
  }
  __syncthreads();
  float tot = sred[0][tid] + sred[1][tid] + sred[2][tid] + sred[3][tid];
  int slx = tid >> 3, k2 = tid & 7;
  int f = slx * 4 + (k2 & 3);
  int idx = (k2 >> 2) ? (128 + f) : f;
  atomicAdd(&stats[idx], tot);
}

// ---------------- final: Out = bn_relu(Hb) @ Wout + bout ----------------
__global__ __launch_bounds__(256) void k_gemm_out(
    const unsigned short* __restrict__ Hb, const float* __restrict__ W,
    const float* __restrict__ bias, const float* __restrict__ stats,
    const float* __restrict__ gamma, const float* __restrict__ beta,
    float* __restrict__ Out, int nrows) {
  __shared__ float As[64 * 132];
  __shared__ float sc[128], sh[128];
  int tid = threadIdx.x;
  if (tid < 128) {
    float invn = 1.0f / (float)nrows;
    float mu = stats[tid] * invn;
    float var = stats[128 + tid] * invn - mu * mu;
    float s = rsqrtf(var + BN_EPS) * gamma[tid];
    sc[tid] = s;
    sh[tid] = beta[tid] - mu * s;
  }
  __syncthreads();
  int row0 = blockIdx.x * 64;
  #pragma unroll
  for (int i = 0; i < 4; i++) {
    int g = tid + i * 256;
    int r = g >> 4;
    int c8 = g & 15;
    uint4 raw = make_uint4(0u, 0u, 0u, 0u);
    if (row0 + r < nrows)
      raw = *(const uint4*)(Hb + (size_t)(row0 + r) * 128 + c8 * 8);
    int c = c8 * 8;
    float* dstp = As + r * 132 + c;
    dstp[0] = fmaxf(bflo(raw.x) * sc[c + 0] + sh[c + 0], 0.f);
    dstp[1] = fmaxf(bfhi(raw.x) * sc[c + 1] + sh[c + 1], 0.f);
    dstp[2] = fmaxf(bflo(raw.y) * sc[c + 2] + sh[c + 2], 0.f);
    dstp[3] = fmaxf(bfhi(raw.y) * sc[c + 3] + sh[c + 3], 0.f);
    dstp[4] = fmaxf(bflo(raw.z) * sc[c + 4] + sh[c + 4], 0.f);
    dstp[5] = fmaxf(bfhi(raw.z) * sc[c + 5] + sh[c + 5], 0.f);
    dstp[6] = fmaxf(bflo(raw.w) * sc[c + 6] + sh[c + 6], 0.f);
    dstp[7] = fmaxf(bfhi(raw.w) * sc[c + 7] + sh[c + 7], 0.f);
  }
  __syncthreads();

  int cg = tid & 7;
  int rg = tid >> 3;
  float acc[2][4] = {};
  for (int k = 0; k < 128; k++) {
    float4 w = *(const float4*)(W + k * 32 + cg * 4);
    float a0 = As[(rg * 2 + 0) * 132 + k];
    float a1 = As[(rg * 2 + 1) * 132 + k];
    acc[0][0] += a0 * w.x; acc[0][1] += a0 * w.y; acc[0][2] += a0 * w.z; acc[0][3] += a0 * w.w;
    acc[1][0] += a1 * w.x; acc[1][1] += a1 * w.y; acc[1][2] += a1 * w.z; acc[1][3] += a1 * w.w;
  }
  float4 bv = *(const float4*)(bias + cg * 4);
  #pragma unroll
  for (int i = 0; i < 2; i++) {
    int r = row0 + rg * 2 + i;
    if (r < nrows) {
      float4 o = make_float4(acc[i][0] + bv.x, acc[i][1] + bv.y,
                             acc[i][2] + bv.z, acc[i][3] + bv.w);
      *(float4*)(Out + (size_t)r * 32 + cg * 4) = o;
    }
  }
}

extern "C" void kernel_launch(void* const* d_in, const int* in_sizes, int n_in,
                              void* d_out, int out_size, void* d_ws, size_t ws_size,
                              hipStream_t stream) {
  const float* x    = (const float*)d_in[0];
  const int*   e_sp = (const int*)d_in[1];
  const int*   e_tp = (const int*)d_in[2];
  const float* Wl[4]  = {(const float*)d_in[3],  (const float*)d_in[8],
                         (const float*)d_in[13], (const float*)d_in[18]};
  const float* Wr[4]  = {(const float*)d_in[4],  (const float*)d_in[9],
                         (const float*)d_in[14], (const float*)d_in[19]};
  const float* bb[4]  = {(const float*)d_in[5],  (const float*)d_in[10],
                         (const float*)d_in[15], (const float*)d_in[20]};
  const float* gm[4]  = {(const float*)d_in[6],  (const float*)d_in[11],
                         (const float*)d_in[16], (const float*)d_in[21]};
  const float* bt[4]  = {(const float*)d_in[7],  (const float*)d_in[12],
                         (const float*)d_in[17], (const float*)d_in[22]};
  const float* Wout = (const float*)d_in[23];
  const float* bout = (const float*)d_in[24];

  const int N = in_sizes[0] / 128;
  const int E = in_sizes[1] / 2;
  const int nbins = (N + ((1 << BSHIFT) - 1)) >> BSHIFT;   // 196 for N=100000

  char* ws = (char*)d_ws;
  size_t off = 0;
  auto alloc = [&](size_t bytes) {
    void* p = ws + off;
    off += (bytes + 255) & ~(size_t)255;
    return p;
  };
  unsigned short* Hb = (unsigned short*)alloc((size_t)N * 128 * 2);  // h (bf16)
  unsigned short* xb = (unsigned short*)alloc((size_t)N * 128 * 2);  // x (bf16)
  unsigned short* Rb = (unsigned short*)alloc((size_t)N * 128 * 2);  // r (bf16)
  unsigned short* Tb = (unsigned short*)alloc((size_t)N * 128 * 2);  // t (bf16)
  int* row_sp    = (int*)alloc((size_t)(N + 1) * 4);
  int* row_tp    = (int*)alloc((size_t)(N + 1) * 4);
  int* csr_sp    = (int*)alloc((size_t)E * 4);
  int* csr_tp    = (int*)alloc((size_t)E * 4);
  unsigned int* binbuf = (unsigned int*)alloc((size_t)256 * BINCAP * 4);  // 10.5 MB
  int* binCount  = (int*)alloc(256 * 4);
  int* binBase   = (int*)alloc(257 * 4);
  float* statsB  = (float*)alloc(4 * 256 * 4);
  unsigned short* Wlp[4], *Wrp[4];
  for (int l = 0; l < 4; l++) {
    Wlp[l] = (unsigned short*)alloc(16384 * 2);
    Wrp[l] = (unsigned short*)alloc(16384 * 2);
  }

  const int pb = (E + 8191) / 8192;

  for (int l = 0; l < 4; l++) {
    k_wpack<<<64, 256, 0, stream>>>(Wl[l], Wlp[l]);
    k_wpack<<<64, 256, 0, stream>>>(Wr[l], Wrp[l]);
  }
  k_f2bf_arr<<<(int)(((size_t)N * 16 + 255) / 256), 256, 0, stream>>>(x, xb, (size_t)N * 16);
  hipMemsetAsync(statsB, 0, 4 * 256 * 4, stream);

  // ---- build CSR (spatial) ----
  hipMemsetAsync(binCount, 0, 256 * 4, stream);
  k_bin_pairs<<<pb, 1024, 0, stream>>>(e_sp, e_sp + E, binCount, binbuf, E, nbins);
  k_binscan<<<1, 256, 0, stream>>>(binCount, binBase, row_sp, nbins, N, E);
  k_csr_bin<<<nbins, 1024, 0, stream>>>(binbuf, binCount, binBase, row_sp, csr_sp, N);

  // ---- build CSR (temporal) ----
  hipMemsetAsync(binCount, 0, 256 * 4, stream);
  k_bin_pairs<<<pb, 1024, 0, stream>>>(e_tp, e_tp + E, binCount, binbuf, E, nbins);
  k_binscan<<<1, 256, 0, stream>>>(binCount, binBase, row_tp, nbins, N, E);
  k_csr_bin<<<nbins, 1024, 0, stream>>>(binbuf, binCount, binBase, row_tp, csr_tp, N);

  const int* rowp[4] = {row_sp, row_sp, row_tp, row_tp};
  const int* csr[4]  = {csr_sp, csr_sp, csr_tp, csr_tp};

  const int gblocks = (N + 63) / 64;
  const unsigned short* cur = xb;
  for (int l = 0; l < 4; l++) {
    const float* st = (l == 0) ? statsB : (statsB + (l - 1) * 256);
    const float* g  = (l == 0) ? gm[0] : gm[l - 1];
    const float* be = (l == 0) ? bt[0] : bt[l - 1];
    k_bn_gemm_dual<<<gblocks, 256, 0, stream>>>(cur, Wlp[l], Wrp[l], bb[l],
                                                st, g, be, Tb, Rb, N, l == 0 ? 0 : 1);
    k_aggregate<<<2048, 256, 0, stream>>>(Tb, Rb, Hb, rowp[l], csr[l],
                                          statsB + l * 256, N);
    cur = Hb;
  }
  k_gemm_out<<<gblocks, 256, 0, stream>>>(Hb, Wout, bout, statsB + 3 * 256,
                                          gm[3], bt[3], (float*)d_out, N);
}

// Round 8
// 640.026 us; speedup vs baseline: 3.7464x; 1.0928x over previous
//
#include <hip/hip_runtime.h>

#define BN_EPS 1e-5f
#define BSHIFT 9              // nodes per bin = 512
#define BINCAP 10240          // >22 sigma above mean 8192 edges/bin

typedef __attribute__((ext_vector_type(8))) short short8;
typedef __attribute__((ext_vector_type(4))) float floatx4;

__device__ inline unsigned short f2bf(float x) {
  unsigned int u = __float_as_uint(x);
  u += 0x7fffu + ((u >> 16) & 1u);
  return (unsigned short)(u >> 16);
}
__device__ inline float bflo(unsigned int v) { return __uint_as_float(v << 16); }
__device__ inline float bfhi(unsigned int v) { return __uint_as_float(v & 0xffff0000u); }

// ---------------- f32 -> bf16 array ----------------
__global__ void k_f2bf_arr(const float* __restrict__ in, unsigned short* __restrict__ out,
                           long long n8) {
  long long i = blockIdx.x * 256LL + threadIdx.x;
  if (i < n8) {
    float4 a = *(const float4*)(in + i * 8);
    float4 b = *(const float4*)(in + i * 8 + 4);
    ushort4 lo, hi;
    lo.x = f2bf(a.x); lo.y = f2bf(a.y); lo.z = f2bf(a.z); lo.w = f2bf(a.w);
    hi.x = f2bf(b.x); hi.y = f2bf(b.y); hi.z = f2bf(b.z); hi.w = f2bf(b.w);
    *(ushort4*)(out + i * 8) = lo;
    *(ushort4*)(out + i * 8 + 4) = hi;
  }
}

// ---------------- weight pack: W[128][128] f32 -> bf16 fragment layout ----------------
__global__ void k_wpack(const float* __restrict__ W, unsigned short* __restrict__ Wp) {
  int o = blockIdx.x * 256 + threadIdx.x;
  int j = o & 7, l = (o >> 3) & 63, cf = (o >> 9) & 7, ks = o >> 12;
  int k = ks * 32 + (l >> 4) * 8 + j;
  int col = cf * 16 + (l & 15);
  Wp[o] = f2bf(W[k * 128 + col]);
}

// ---------------- CSR build: atomic-free binned counting sort ----------------
// packed entry: (dst & 511) << 23 | src   (valid for N < 2^23)
__global__ __launch_bounds__(1024) void k_bin_pairs(
    const int* __restrict__ src, const int* __restrict__ dst,
    int* __restrict__ binCount, unsigned int* __restrict__ binbuf, int E, int nbins) {
  __shared__ int hist[256], base[256];
  int tid = threadIdx.x;
  int b0 = blockIdx.x * 8192;
  if (tid < 256) hist[tid] = 0;
  __syncthreads();
  int s[8], d[8], rk[8], bn[8];
  #pragma unroll
  for (int i = 0; i < 8; i++) {
    int e = b0 + tid + i * 1024;
    if (e < E) {
      s[i] = src[e];
      d[i] = dst[e];
      bn[i] = d[i] >> BSHIFT;
      rk[i] = atomicAdd(&hist[bn[i]], 1);
    }
  }
  __syncthreads();
  if (tid < nbins && hist[tid] > 0)
    base[tid] = atomicAdd(&binCount[tid], hist[tid]);
  __syncthreads();
  #pragma unroll
  for (int i = 0; i < 8; i++) {
    int e = b0 + tid + i * 1024;
    if (e < E)
      binbuf[(size_t)bn[i] * BINCAP + base[bn[i]] + rk[i]] =
          ((unsigned)(d[i] & 511) << 23) | (unsigned)s[i];
  }
}

__global__ void k_binscan(const int* __restrict__ binCount, int* __restrict__ binBase,
                          int* __restrict__ row_ptr, int nbins, int N, int E) {
  __shared__ int sd[256];
  int tid = threadIdx.x;
  int v = (tid < nbins) ? binCount[tid] : 0;
  sd[tid] = v;
  __syncthreads();
  for (int off = 1; off < 256; off <<= 1) {
    int t = (tid >= off) ? sd[tid - off] : 0;
    __syncthreads();
    sd[tid] += t;
    __syncthreads();
  }
  if (tid < nbins) binBase[tid] = sd[tid] - v;
  if (tid == nbins) binBase[nbins] = sd[nbins - 1];
  if (tid == 0) row_ptr[N] = E;
}

__global__ __launch_bounds__(1024) void k_csr_bin(
    const unsigned int* __restrict__ binbuf, const int* __restrict__ binCount,
    const int* __restrict__ binBase, int* __restrict__ row_ptr,
    int* __restrict__ csr, int N) {
  __shared__ int hist[512];
  __shared__ int incl[512];
  int b = blockIdx.x;
  int tid = threadIdx.x;
  int nE = binCount[b];
  int eb = binBase[b];
  const unsigned int* p = binbuf + (size_t)b * BINCAP;
  if (tid < 512) hist[tid] = 0;
  __syncthreads();
  for (int e = tid; e < nE; e += 1024) {
    int dl = (int)(p[e] >> 23);
    atomicAdd(&hist[dl], 1);
  }
  __syncthreads();
  if (tid < 512) incl[tid] = hist[tid];
  __syncthreads();
  for (int off = 1; off < 512; off <<= 1) {
    int t = 0;
    if (tid < 512 && tid >= off) t = incl[tid - off];
    __syncthreads();
    if (tid < 512) incl[tid] += t;
    __syncthreads();
  }
  int node0 = b << BSHIFT;
  if (tid < 512) {
    int ex = incl[tid] - hist[tid];
    if (node0 + tid < N) row_ptr[node0 + tid] = eb + ex;
    hist[tid] = ex;             // reuse as bin-local cursor
  }
  __syncthreads();
  for (int e = tid; e < nE; e += 1024) {
    unsigned int pr = p[e];
    int dl = (int)(pr >> 23);
    int sv = (int)(pr & 0x7fffffu);
    int r = atomicAdd(&hist[dl], 1);
    csr[eb + r] = sv;
  }
}

// ---------------- fused BN(+ReLU) -> dual MFMA GEMM (bf16 in, bf16 out x2) ----------------
__global__ __launch_bounds__(256) void k_bn_gemm_dual(
    const unsigned short* __restrict__ Hb, const unsigned short* __restrict__ Wlp,
    const unsigned short* __restrict__ Wrp, const float* __restrict__ bias,
    const float* __restrict__ stats, const float* __restrict__ gamma,
    const float* __restrict__ beta, unsigned short* __restrict__ Tb,
    unsigned short* __restrict__ Rb, int n, int apply_bn) {
  __shared__ unsigned int As[64 * 64];   // 64 rows x 128 bf16, XOR-swizzled
  __shared__ float sc[128], sh[128];
  int tid = threadIdx.x;
  if (tid < 128) {
    if (apply_bn) {
      float invn = 1.0f / (float)n;
      float mu = stats[tid] * invn;
      float var = stats[128 + tid] * invn - mu * mu;
      float s = rsqrtf(var + BN_EPS) * gamma[tid];
      sc[tid] = s;
      sh[tid] = beta[tid] - mu * s;
    }
  }
  __syncthreads();

  int row0 = blockIdx.x * 64;
  {
    int r = tid >> 2, cbase = (tid & 3) * 32;
    const unsigned short* srcp = Hb + (size_t)(row0 + r) * 128 + cbase;
    bool valid = (row0 + r) < n;
    unsigned int swz = (unsigned)((r & 7) << 2);
    unsigned int ubase = (unsigned)(r * 64 + (cbase >> 1));
    #pragma unroll
    for (int m = 0; m < 4; m++) {
      uint4 raw = make_uint4(0u, 0u, 0u, 0u);
      if (valid) raw = *(const uint4*)(srcp + m * 8);
      uint4 pk;
      if (apply_bn) {
        int c = cbase + m * 8;
        float f0 = fmaxf(bflo(raw.x) * sc[c + 0] + sh[c + 0], 0.f);
        float f1 = fmaxf(bfhi(raw.x) * sc[c + 1] + sh[c + 1], 0.f);
        float f2 = fmaxf(bflo(raw.y) * sc[c + 2] + sh[c + 2], 0.f);
        float f3 = fmaxf(bfhi(raw.y) * sc[c + 3] + sh[c + 3], 0.f);
        float f4 = fmaxf(bflo(raw.z) * sc[c + 4] + sh[c + 4], 0.f);
        float f5 = fmaxf(bfhi(raw.z) * sc[c + 5] + sh[c + 5], 0.f);
        float f6 = fmaxf(bflo(raw.w) * sc[c + 6] + sh[c + 6], 0.f);
        float f7 = fmaxf(bfhi(raw.w) * sc[c + 7] + sh[c + 7], 0.f);
        pk.x = (unsigned)f2bf(f0) | ((unsigned)f2bf(f1) << 16);
        pk.y = (unsigned)f2bf(f2) | ((unsigned)f2bf(f3) << 16);
        pk.z = (unsigned)f2bf(f4) | ((unsigned)f2bf(f5) << 16);
        pk.w = (unsigned)f2bf(f6) | ((unsigned)f2bf(f7) << 16);
      } else {
        pk = raw;   // x already bf16, no BN on layer 0
      }
      *(uint4*)(As + ((ubase + m * 4) ^ swz)) = pk;
    }
  }
  __syncthreads();

  int w = tid >> 6, lane = tid & 63;
  int wrow = (w << 4) + (lane & 15);
  unsigned int aswz = (unsigned)((wrow & 7) << 2);
  floatx4 accT[8] = {}, accR[8] = {};

  #pragma unroll
  for (int ks = 0; ks < 4; ks++) {
    unsigned int aoff = (unsigned)(wrow * 64 + ks * 16 + ((lane >> 4) << 2)) ^ aswz;
    short8 a = *(const short8*)(As + aoff);
    #pragma unroll
    for (int cf = 0; cf < 8; cf++) {
      int wo = ((ks * 8 + cf) * 64 + lane) * 8;
      short8 wl = *(const short8*)(Wlp + wo);
      short8 wr = *(const short8*)(Wrp + wo);
      accT[cf] = __builtin_amdgcn_mfma_f32_16x16x32_bf16(a, wl, accT[cf], 0, 0, 0);
      accR[cf] = __builtin_amdgcn_mfma_f32_16x16x32_bf16(a, wr, accR[cf], 0, 0, 0);
    }
  }

  int colb = lane & 15;
  int rb = row0 + (w << 4) + ((lane >> 4) << 2);
  #pragma unroll
  for (int cf = 0; cf < 8; cf++) {
    int col = cf * 16 + colb;
    float bv = bias[col];
    #pragma unroll
    for (int i = 0; i < 4; i++) {
      int r = rb + i;
      if (r < n) {
        Tb[(size_t)r * 128 + col] = f2bf(accT[cf][i]);
        Rb[(size_t)r * 128 + col] = f2bf(accR[cf][i] + bv);
      }
    }
  }
}

// ---------------- aggregate: Hb[i] = bf16(Rb[i] + mean_{j in N(i)} Tb[j]); BN stats ----------------
// Node-PAIR per wave (consecutive nodes): issue A's 8 gathers + B's 8 gathers
// back-to-back (16 rows / 2x MLP in flight), then accumulate A while B's loads
// fly. Next-pair csr/Rb/row_ptr prefetches issue in the same burst.
__global__ __launch_bounds__(256) void k_aggregate(
    const unsigned short* __restrict__ Tb, const unsigned short* __restrict__ Rb,
    unsigned short* __restrict__ Hb, const int* __restrict__ row_ptr,
    const int* __restrict__ csr, float* __restrict__ stats, int n) {
  __shared__ float sred[4][256];
  int tid = threadIdx.x;
  int lane = tid & 63;
  int half = lane >> 5;
  int sl = lane & 31;            // features sl*4 .. sl*4+3
  int wlocal = tid >> 6;
  int wid = (blockIdx.x * blockDim.x + tid) >> 6;
  int nw = (gridDim.x * blockDim.x) >> 6;
  float s0 = 0, s1 = 0, s2 = 0, s3 = 0, q0 = 0, q1 = 0, q2 = 0, q3 = 0;

  int i2 = 2 * wid;
  int step = 2 * nw;

  // ---- prologue: pair p (rowptr/idx/rv) + pair p+1 rowptr ----
  int begA = 0, endA = 0, begB = 0, endB = 0;
  int idxA = 0, idxB = 0;
  uint2 rvA = make_uint2(0u, 0u), rvB = make_uint2(0u, 0u);
  if (i2 < n) {
    begA = row_ptr[i2]; endA = row_ptr[i2 + 1];
    if (i2 + 1 < n) { begB = endA; endB = row_ptr[i2 + 2]; }
    int cA = endA - begA; if (cA > 64) cA = 64;
    idxA = (lane < cA) ? csr[begA + lane] : 0;
    if (half == 0) rvA = *(const uint2*)(Rb + (size_t)i2 * 128 + sl * 4);
    if (i2 + 1 < n) {
      int cB = endB - begB; if (cB > 64) cB = 64;
      idxB = (lane < cB) ? csr[begB + lane] : 0;
      if (half == 0) rvB = *(const uint2*)(Rb + (size_t)(i2 + 1) * 128 + sl * 4);
    }
  }
  int j2 = i2 + step;
  int r0n = 0, r1n = 0, r2n = 0;
  if (j2 < n) {
    r0n = row_ptr[j2];
    r1n = row_ptr[j2 + 1];
    r2n = (j2 + 1 < n) ? row_ptr[j2 + 2] : r1n;
  }

  while (i2 < n) {
    int cA = endA - begA;
    int c0A = cA > 64 ? 64 : cA;
    bool hasB = (i2 + 1 < n);
    int cB = hasB ? (endB - begB) : 0;
    int c0B = cB > 64 ? 64 : cB;

    // 1) issue step-0 gathers for A then B (16 rows in flight)
    uint2 dA[8], dB[8];
    #pragma unroll
    for (int m = 0; m < 8; m++) {
      int ls = half + 2 * m;
      int j = __shfl(idxA, ls);
      dA[m] = (2 * m < c0A) ? *(const uint2*)(Tb + (size_t)j * 128 + sl * 4)
                            : make_uint2(0u, 0u);
    }
    #pragma unroll
    for (int m = 0; m < 8; m++) {
      int ls = half + 2 * m;
      int j = __shfl(idxB, ls);
      dB[m] = (2 * m < c0B) ? *(const uint2*)(Tb + (size_t)j * 128 + sl * 4)
                            : make_uint2(0u, 0u);
    }

    // 2) next-pair idx + rv prefetch (rowptrs resolved from last iteration)
    int idxA2 = 0, idxB2 = 0;
    uint2 rvA2 = make_uint2(0u, 0u), rvB2 = make_uint2(0u, 0u);
    if (j2 < n) {
      int cA2 = r1n - r0n; if (cA2 > 64) cA2 = 64;
      idxA2 = (lane < cA2) ? csr[r0n + lane] : 0;
      if (half == 0) rvA2 = *(const uint2*)(Rb + (size_t)j2 * 128 + sl * 4);
      if (j2 + 1 < n) {
        int cB2 = r2n - r1n; if (cB2 > 64) cB2 = 64;
        idxB2 = (lane < cB2) ? csr[r1n + lane] : 0;
        if (half == 0) rvB2 = *(const uint2*)(Rb + (size_t)(j2 + 1) * 128 + sl * 4);
      }
    }
    // 3) rowptr prefetch for pair p+2
    int k2 = j2 + step;
    int r0nn = 0, r1nn = 0, r2nn = 0;
    if (k2 < n) {
      r0nn = row_ptr[k2];
      r1nn = row_ptr[k2 + 1];
      r2nn = (k2 + 1 < n) ? row_ptr[k2 + 2] : r1nn;
    }

    // 4) accumulate A (B's loads + prefetches still in flight)
    float a0 = 0, a1 = 0, a2 = 0, a3 = 0;
    #pragma unroll
    for (int m = 0; m < 8; m++) {
      int ls = half + 2 * m;
      if (ls < c0A) {
        a0 += bflo(dA[m].x); a1 += bfhi(dA[m].x);
        a2 += bflo(dA[m].y); a3 += bfhi(dA[m].y);
      }
    }
    for (int k = 16; k < c0A; k += 16) {
      #pragma unroll
      for (int m = 0; m < 8; m++) {
        int ls = k + half + 2 * m;
        int j = __shfl(idxA, ls);
        if (ls < c0A) {
          uint2 v = *(const uint2*)(Tb + (size_t)j * 128 + sl * 4);
          a0 += bflo(v.x); a1 += bfhi(v.x);
          a2 += bflo(v.y); a3 += bfhi(v.y);
        }
      }
    }
    for (int base = begA + 64; base < endA; base += 64) {   // deg>64 (rare)
      int cnt = endA - base; if (cnt > 64) cnt = 64;
      int idx = (lane < cnt) ? csr[base + lane] : 0;
      for (int k = 0; k < cnt; k += 16) {
        #pragma unroll
        for (int m = 0; m < 8; m++) {
          int ls = k + half + 2 * m;
          int j = __shfl(idx, ls);
          if (ls < cnt) {
            uint2 v = *(const uint2*)(Tb + (size_t)j * 128 + sl * 4);
            a0 += bflo(v.x); a1 += bfhi(v.x);
            a2 += bflo(v.y); a3 += bfhi(v.y);
          }
        }
      }
    }
    a0 += __shfl_xor(a0, 32);
    a1 += __shfl_xor(a1, 32);
    a2 += __shfl_xor(a2, 32);
    a3 += __shfl_xor(a3, 32);
    if (half == 0) {
      float inv = (cA > 0) ? (1.0f / (float)cA) : 0.0f;
      float h0 = bflo(rvA.x) + a0 * inv;
      float h1 = bfhi(rvA.x) + a1 * inv;
      float h2 = bflo(rvA.y) + a2 * inv;
      float h3 = bfhi(rvA.y) + a3 * inv;
      uint2 pk;
      pk.x = (unsigned)f2bf(h0) | ((unsigned)f2bf(h1) << 16);
      pk.y = (unsigned)f2bf(h2) | ((unsigned)f2bf(h3) << 16);
      *(uint2*)(Hb + (size_t)i2 * 128 + sl * 4) = pk;
      s0 += h0; s1 += h1; s2 += h2; s3 += h3;
      q0 += h0 * h0; q1 += h1 * h1; q2 += h2 * h2; q3 += h3 * h3;
    }

    // 5) accumulate B
    if (hasB) {
      float b0 = 0, b1 = 0, b2 = 0, b3 = 0;
      #pragma unroll
      for (int m = 0; m < 8; m++) {
        int ls = half + 2 * m;
        if (ls < c0B) {
          b0 += bflo(dB[m].x); b1 += bfhi(dB[m].x);
          b2 += bflo(dB[m].y); b3 += bfhi(dB[m].y);
        }
      }
      for (int k = 16; k < c0B; k += 16) {
        #pragma unroll
        for (int m = 0; m < 8; m++) {
          int ls = k + half + 2 * m;
          int j = __shfl(idxB, ls);
          if (ls < c0B) {
            uint2 v = *(const uint2*)(Tb + (size_t)j * 128 + sl * 4);
            b0 += bflo(v.x); b1 += bfhi(v.x);
            b2 += bflo(v.y); b3 += bfhi(v.y);
          }
        }
      }
      for (int base = begB + 64; base < endB; base += 64) {   // deg>64 (rare)
        int cnt = endB - base; if (cnt > 64) cnt = 64;
        int idx = (lane < cnt) ? csr[base + lane] : 0;
        for (int k = 0; k < cnt; k += 16) {
          #pragma unroll
          for (int m = 0; m < 8; m++) {
            int ls = k + half + 2 * m;
            int j = __shfl(idx, ls);
            if (ls < cnt) {
              uint2 v = *(const uint2*)(Tb + (size_t)j * 128 + sl * 4);
              b0 += bflo(v.x); b1 += bfhi(v.x);
              b2 += bflo(v.y); b3 += bfhi(v.y);
            }
          }
        }
      }
      b0 += __shfl_xor(b0, 32);
      b1 += __shfl_xor(b1, 32);
      b2 += __shfl_xor(b2, 32);
      b3 += __shfl_xor(b3, 32);
      if (half == 0) {
        float inv = (cB > 0) ? (1.0f / (float)cB) : 0.0f;
        float h0 = bflo(rvB.x) + b0 * inv;
        float h1 = bfhi(rvB.x) + b1 * inv;
        float h2 = bflo(rvB.y) + b2 * inv;
        float h3 = bfhi(rvB.y) + b3 * inv;
        uint2 pk;
        pk.x = (unsigned)f2bf(h0) | ((unsigned)f2bf(h1) << 16);
        pk.y = (unsigned)f2bf(h2) | ((unsigned)f2bf(h3) << 16);
        *(uint2*)(Hb + (size_t)(i2 + 1) * 128 + sl * 4) = pk;
        s0 += h0; s1 += h1; s2 += h2; s3 += h3;
        q0 += h0 * h0; q1 += h1 * h1; q2 += h2 * h2; q3 += h3 * h3;
      }
    }

    // 6) rotate pipeline state
    i2 += step;
    begA = r0n; endA = r1n; begB = r1n; endB = r2n;
    idxA = idxA2; idxB = idxB2; rvA = rvA2; rvB = rvB2;
    j2 = k2; r0n = r0nn; r1n = r1nn; r2n = r2nn;
  }

  if (half == 0) {
    sred[wlocal][sl * 8 + 0] = s0; sred[wlocal][sl * 8 + 1] = s1;
    sred[wlocal][sl * 8 + 2] = s2; sred[wlocal][sl * 8 + 3] = s3;
    sred[wlocal][sl * 8 + 4] = q0; sred[wlocal][sl * 8 + 5] = q1;
    sred[wlocal][sl * 8 + 6] = q2; sred[wlocal][sl * 8 + 7] = q3;
  }
  __syncthreads();
  float tot = sred[0][tid] + sred[1][tid] + sred[2][tid] + sred[3][tid];
  int slx = tid >> 3, k2f = tid & 7;
  int f = slx * 4 + (k2f & 3);
  int idx = (k2f >> 2) ? (128 + f) : f;
  atomicAdd(&stats[idx], tot);
}

// ---------------- final: Out = bn_relu(Hb) @ Wout + bout ----------------
__global__ __launch_bounds__(256) void k_gemm_out(
    const unsigned short* __restrict__ Hb, const float* __restrict__ W,
    const float* __restrict__ bias, const float* __restrict__ stats,
    const float* __restrict__ gamma, const float* __restrict__ beta,
    float* __restrict__ Out, int nrows) {
  __shared__ float As[64 * 132];
  __shared__ float sc[128], sh[128];
  int tid = threadIdx.x;
  if (tid < 128) {
    float invn = 1.0f / (float)nrows;
    float mu = stats[tid] * invn;
    float var = stats[128 + tid] * invn - mu * mu;
    float s = rsqrtf(var + BN_EPS) * gamma[tid];
    sc[tid] = s;
    sh[tid] = beta[tid] - mu * s;
  }
  __syncthreads();
  int row0 = blockIdx.x * 64;
  #pragma unroll
  for (int i = 0; i < 4; i++) {
    int g = tid + i * 256;
    int r = g >> 4;
    int c8 = g & 15;
    uint4 raw = make_uint4(0u, 0u, 0u, 0u);
    if (row0 + r < nrows)
      raw = *(const uint4*)(Hb + (size_t)(row0 + r) * 128 + c8 * 8);
    int c = c8 * 8;
    float* dstp = As + r * 132 + c;
    dstp[0] = fmaxf(bflo(raw.x) * sc[c + 0] + sh[c + 0], 0.f);
    dstp[1] = fmaxf(bfhi(raw.x) * sc[c + 1] + sh[c + 1], 0.f);
    dstp[2] = fmaxf(bflo(raw.y) * sc[c + 2] + sh[c + 2], 0.f);
    dstp[3] = fmaxf(bfhi(raw.y) * sc[c + 3] + sh[c + 3], 0.f);
    dstp[4] = fmaxf(bflo(raw.z) * sc[c + 4] + sh[c + 4], 0.f);
    dstp[5] = fmaxf(bfhi(raw.z) * sc[c + 5] + sh[c + 5], 0.f);
    dstp[6] = fmaxf(bflo(raw.w) * sc[c + 6] + sh[c + 6], 0.f);
    dstp[7] = fmaxf(bfhi(raw.w) * sc[c + 7] + sh[c + 7], 0.f);
  }
  __syncthreads();

  int cg = tid & 7;
  int rg = tid >> 3;
  float acc[2][4] = {};
  for (int k = 0; k < 128; k++) {
    float4 w = *(const float4*)(W + k * 32 + cg * 4);
    float a0 = As[(rg * 2 + 0) * 132 + k];
    float a1 = As[(rg * 2 + 1) * 132 + k];
    acc[0][0] += a0 * w.x; acc[0][1] += a0 * w.y; acc[0][2] += a0 * w.z; acc[0][3] += a0 * w.w;
    acc[1][0] += a1 * w.x; acc[1][1] += a1 * w.y; acc[1][2] += a1 * w.z; acc[1][3] += a1 * w.w;
  }
  float4 bv = *(const float4*)(bias + cg * 4);
  #pragma unroll
  for (int i = 0; i < 2; i++) {
    int r = row0 + rg * 2 + i;
    if (r < nrows) {
      float4 o = make_float4(acc[i][0] + bv.x, acc[i][1] + bv.y,
                             acc[i][2] + bv.z, acc[i][3] + bv.w);
      *(float4*)(Out + (size_t)r * 32 + cg * 4) = o;
    }
  }
}

extern "C" void kernel_launch(void* const* d_in, const int* in_sizes, int n_in,
                              void* d_out, int out_size, void* d_ws, size_t ws_size,
                              hipStream_t stream) {
  const float* x    = (const float*)d_in[0];
  const int*   e_sp = (const int*)d_in[1];
  const int*   e_tp = (const int*)d_in[2];
  const float* Wl[4]  = {(const float*)d_in[3],  (const float*)d_in[8],
                         (const float*)d_in[13], (const float*)d_in[18]};
  const float* Wr[4]  = {(const float*)d_in[4],  (const float*)d_in[9],
                         (const float*)d_in[14], (const float*)d_in[19]};
  const float* bb[4]  = {(const float*)d_in[5],  (const float*)d_in[10],
                         (const float*)d_in[15], (const float*)d_in[20]};
  const float* gm[4]  = {(const float*)d_in[6],  (const float*)d_in[11],
                         (const float*)d_in[16], (const float*)d_in[21]};
  const float* bt[4]  = {(const float*)d_in[7],  (const float*)d_in[12],
                         (const float*)d_in[17], (const float*)d_in[22]};
  const float* Wout = (const float*)d_in[23];
  const float* bout = (const float*)d_in[24];

  const int N = in_sizes[0] / 128;
  const int E = in_sizes[1] / 2;
  const int nbins = (N + ((1 << BSHIFT) - 1)) >> BSHIFT;   // 196 for N=100000

  char* ws = (char*)d_ws;
  size_t off = 0;
  auto alloc = [&](size_t bytes) {
    void* p = ws + off;
    off += (bytes + 255) & ~(size_t)255;
    return p;
  };
  unsigned short* Hb = (unsigned short*)alloc((size_t)N * 128 * 2);  // h (bf16)
  unsigned short* xb = (unsigned short*)alloc((size_t)N * 128 * 2);  // x (bf16)
  unsigned short* Rb = (unsigned short*)alloc((size_t)N * 128 * 2);  // r (bf16)
  unsigned short* Tb = (unsigned short*)alloc((size_t)N * 128 * 2);  // t (bf16)
  int* row_sp    = (int*)alloc((size_t)(N + 1) * 4);
  int* row_tp    = (int*)alloc((size_t)(N + 1) * 4);
  int* csr_sp    = (int*)alloc((size_t)E * 4);
  int* csr_tp    = (int*)alloc((size_t)E * 4);
  unsigned int* binbuf = (unsigned int*)alloc((size_t)256 * BINCAP * 4);  // 10.5 MB
  int* binCount  = (int*)alloc(256 * 4);
  int* binBase   = (int*)alloc(257 * 4);
  float* statsB  = (float*)alloc(4 * 256 * 4);
  unsigned short* Wlp[4], *Wrp[4];
  for (int l = 0; l < 4; l++) {
    Wlp[l] = (unsigned short*)alloc(16384 * 2);
    Wrp[l] = (unsigned short*)alloc(16384 * 2);
  }

  const int pb = (E + 8191) / 8192;

  for (int l = 0; l < 4; l++) {
    k_wpack<<<64, 256, 0, stream>>>(Wl[l], Wlp[l]);
    k_wpack<<<64, 256, 0, stream>>>(Wr[l], Wrp[l]);
  }
  k_f2bf_arr<<<(int)(((size_t)N * 16 + 255) / 256), 256, 0, stream>>>(x, xb, (size_t)N * 16);
  hipMemsetAsync(statsB, 0, 4 * 256 * 4, stream);

  // ---- build CSR (spatial) ----
  hipMemsetAsync(binCount, 0, 256 * 4, stream);
  k_bin_pairs<<<pb, 1024, 0, stream>>>(e_sp, e_sp + E, binCount, binbuf, E, nbins);
  k_binscan<<<1, 256, 0, stream>>>(binCount, binBase, row_sp, nbins, N, E);
  k_csr_bin<<<nbins, 1024, 0, stream>>>(binbuf, binCount, binBase, row_sp, csr_sp, N);

  // ---- build CSR (temporal) ----
  hipMemsetAsync(binCount, 0, 256 * 4, stream);
  k_bin_pairs<<<pb, 1024, 0, stream>>>(e_tp, e_tp + E, binCount, binbuf, E, nbins);
  k_binscan<<<1, 256, 0, stream>>>(binCount, binBase, row_tp, nbins, N, E);
  k_csr_bin<<<nbins, 1024, 0, stream>>>(binbuf, binCount, binBase, row_tp, csr_tp, N);

  const int* rowp[4] = {row_sp, row_sp, row_tp, row_tp};
  const int* csr[4]  = {csr_sp, csr_sp, csr_tp, csr_tp};

  const int gblocks = (N + 63) / 64;
  const unsigned short* cur = xb;
  for (int l = 0; l < 4; l++) {
    const float* st = (l == 0) ? statsB : (statsB + (l - 1) * 256);
    const float* g  = (l == 0) ? gm[0] : gm[l - 1];
    const float* be = (l == 0) ? bt[0] : bt[l - 1];
    k_bn_gemm_dual<<<gblocks, 256, 0, stream>>>(cur, Wlp[l], Wrp[l], bb[l],
                                                st, g, be, Tb, Rb, N, l == 0 ? 0 : 1);
    k_aggregate<<<2048, 256, 0, stream>>>(Tb, Rb, Hb, rowp[l], csr[l],
                                          statsB + l * 256, N);
    cur = Hb;
  }
  k_gemm_out<<<gblocks, 256, 0, stream>>>(Hb, Wout, bout, statsB + 3 * 256,
                                          gm[3], bt[3], (float*)d_out, N);
}

// Round 9
// 584.597 us; speedup vs baseline: 4.1016x; 1.0948x over previous
//
#include <hip/hip_runtime.h>

#define BN_EPS 1e-5f
#define BSHIFT 9              // nodes per bin = 512
#define BINCAP 10240          // >22 sigma above mean 8192 edges/bin
#define T_SCALE 16.0f
#define T_INV_SCALE (1.0f / 16.0f)

typedef __attribute__((ext_vector_type(8))) short short8;
typedef __attribute__((ext_vector_type(4))) float floatx4;
typedef __attribute__((ext_vector_type(2))) float floatx2;

__device__ inline unsigned short f2bf(float x) {
  unsigned int u = __float_as_uint(x);
  u += 0x7fffu + ((u >> 16) & 1u);
  return (unsigned short)(u >> 16);
}
__device__ inline float bflo(unsigned int v) { return __uint_as_float(v << 16); }
__device__ inline float bfhi(unsigned int v) { return __uint_as_float(v & 0xffff0000u); }
__device__ inline unsigned char f2fp8(float x) {
  return (unsigned char)(__builtin_amdgcn_cvt_pk_fp8_f32(x, x, 0, false) & 0xff);
}

// ---------------- f32 -> bf16 array ----------------
__global__ void k_f2bf_arr(const float* __restrict__ in, unsigned short* __restrict__ out,
                           long long n8) {
  long long i = blockIdx.x * 256LL + threadIdx.x;
  if (i < n8) {
    float4 a = *(const float4*)(in + i * 8);
    float4 b = *(const float4*)(in + i * 8 + 4);
    ushort4 lo, hi;
    lo.x = f2bf(a.x); lo.y = f2bf(a.y); lo.z = f2bf(a.z); lo.w = f2bf(a.w);
    hi.x = f2bf(b.x); hi.y = f2bf(b.y); hi.z = f2bf(b.z); hi.w = f2bf(b.w);
    *(ushort4*)(out + i * 8) = lo;
    *(ushort4*)(out + i * 8 + 4) = hi;
  }
}

// ---------------- weight pack: W[128][128] f32 -> bf16 fragment layout ----------------
__global__ void k_wpack(const float* __restrict__ W, unsigned short* __restrict__ Wp) {
  int o = blockIdx.x * 256 + threadIdx.x;
  int j = o & 7, l = (o >> 3) & 63, cf = (o >> 9) & 7, ks = o >> 12;
  int k = ks * 32 + (l >> 4) * 8 + j;
  int col = cf * 16 + (l & 15);
  Wp[o] = f2bf(W[k * 128 + col]);
}

// ---------------- CSR build: atomic-free binned counting sort ----------------
// packed entry: (dst & 511) << 23 | src   (valid for N < 2^23)
__global__ __launch_bounds__(1024) void k_bin_pairs(
    const int* __restrict__ src, const int* __restrict__ dst,
    int* __restrict__ binCount, unsigned int* __restrict__ binbuf, int E, int nbins) {
  __shared__ int hist[256], base[256];
  int tid = threadIdx.x;
  int b0 = blockIdx.x * 8192;
  if (tid < 256) hist[tid] = 0;
  __syncthreads();
  int s[8], d[8], rk[8], bn[8];
  #pragma unroll
  for (int i = 0; i < 8; i++) {
    int e = b0 + tid + i * 1024;
    if (e < E) {
      s[i] = src[e];
      d[i] = dst[e];
      bn[i] = d[i] >> BSHIFT;
      rk[i] = atomicAdd(&hist[bn[i]], 1);
    }
  }
  __syncthreads();
  if (tid < nbins && hist[tid] > 0)
    base[tid] = atomicAdd(&binCount[tid], hist[tid]);
  __syncthreads();
  #pragma unroll
  for (int i = 0; i < 8; i++) {
    int e = b0 + tid + i * 1024;
    if (e < E)
      binbuf[(size_t)bn[i] * BINCAP + base[bn[i]] + rk[i]] =
          ((unsigned)(d[i] & 511) << 23) | (unsigned)s[i];
  }
}

__global__ void k_binscan(const int* __restrict__ binCount, int* __restrict__ binBase,
                          int* __restrict__ row_ptr, int nbins, int N, int E) {
  __shared__ int sd[256];
  int tid = threadIdx.x;
  int v = (tid < nbins) ? binCount[tid] : 0;
  sd[tid] = v;
  __syncthreads();
  for (int off = 1; off < 256; off <<= 1) {
    int t = (tid >= off) ? sd[tid - off] : 0;
    __syncthreads();
    sd[tid] += t;
    __syncthreads();
  }
  if (tid < nbins) binBase[tid] = sd[tid] - v;
  if (tid == nbins) binBase[nbins] = sd[nbins - 1];
  if (tid == 0) row_ptr[N] = E;
}

__global__ __launch_bounds__(1024) void k_csr_bin(
    const unsigned int* __restrict__ binbuf, const int* __restrict__ binCount,
    const int* __restrict__ binBase, int* __restrict__ row_ptr,
    int* __restrict__ csr, int N) {
  __shared__ int hist[512];
  __shared__ int incl[512];
  int b = blockIdx.x;
  int tid = threadIdx.x;
  int nE = binCount[b];
  int eb = binBase[b];
  const unsigned int* p = binbuf + (size_t)b * BINCAP;
  if (tid < 512) hist[tid] = 0;
  __syncthreads();
  for (int e = tid; e < nE; e += 1024) {
    int dl = (int)(p[e] >> 23);
    atomicAdd(&hist[dl], 1);
  }
  __syncthreads();
  if (tid < 512) incl[tid] = hist[tid];
  __syncthreads();
  for (int off = 1; off < 512; off <<= 1) {
    int t = 0;
    if (tid < 512 && tid >= off) t = incl[tid - off];
    __syncthreads();
    if (tid < 512) incl[tid] += t;
    __syncthreads();
  }
  int node0 = b << BSHIFT;
  if (tid < 512) {
    int ex = incl[tid] - hist[tid];
    if (node0 + tid < N) row_ptr[node0 + tid] = eb + ex;
    hist[tid] = ex;             // reuse as bin-local cursor
  }
  __syncthreads();
  for (int e = tid; e < nE; e += 1024) {
    unsigned int pr = p[e];
    int dl = (int)(pr >> 23);
    int sv = (int)(pr & 0x7fffffu);
    int r = atomicAdd(&hist[dl], 1);
    csr[eb + r] = sv;
  }
}

// ---------------- fused BN(+ReLU) -> dual MFMA GEMM (bf16 in; T fp8 x16, R bf16) ----------------
__global__ __launch_bounds__(256) void k_bn_gemm_dual(
    const unsigned short* __restrict__ Hb, const unsigned short* __restrict__ Wlp,
    const unsigned short* __restrict__ Wrp, const float* __restrict__ bias,
    const float* __restrict__ stats, const float* __restrict__ gamma,
    const float* __restrict__ beta, unsigned char* __restrict__ Tq,
    unsigned short* __restrict__ Rb, int n, int apply_bn) {
  __shared__ unsigned int As[64 * 64];   // 64 rows x 128 bf16, XOR-swizzled
  __shared__ float sc[128], sh[128];
  int tid = threadIdx.x;
  if (tid < 128) {
    if (apply_bn) {
      float invn = 1.0f / (float)n;
      float mu = stats[tid] * invn;
      float var = stats[128 + tid] * invn - mu * mu;
      float s = rsqrtf(var + BN_EPS) * gamma[tid];
      sc[tid] = s;
      sh[tid] = beta[tid] - mu * s;
    }
  }
  __syncthreads();

  int row0 = blockIdx.x * 64;
  {
    int r = tid >> 2, cbase = (tid & 3) * 32;
    const unsigned short* srcp = Hb + (size_t)(row0 + r) * 128 + cbase;
    bool valid = (row0 + r) < n;
    unsigned int swz = (unsigned)((r & 7) << 2);
    unsigned int ubase = (unsigned)(r * 64 + (cbase >> 1));
    #pragma unroll
    for (int m = 0; m < 4; m++) {
      uint4 raw = make_uint4(0u, 0u, 0u, 0u);
      if (valid) raw = *(const uint4*)(srcp + m * 8);
      uint4 pk;
      if (apply_bn) {
        int c = cbase + m * 8;
        float f0 = fmaxf(bflo(raw.x) * sc[c + 0] + sh[c + 0], 0.f);
        float f1 = fmaxf(bfhi(raw.x) * sc[c + 1] + sh[c + 1], 0.f);
        float f2 = fmaxf(bflo(raw.y) * sc[c + 2] + sh[c + 2], 0.f);
        float f3 = fmaxf(bfhi(raw.y) * sc[c + 3] + sh[c + 3], 0.f);
        float f4 = fmaxf(bflo(raw.z) * sc[c + 4] + sh[c + 4], 0.f);
        float f5 = fmaxf(bfhi(raw.z) * sc[c + 5] + sh[c + 5], 0.f);
        float f6 = fmaxf(bflo(raw.w) * sc[c + 6] + sh[c + 6], 0.f);
        float f7 = fmaxf(bfhi(raw.w) * sc[c + 7] + sh[c + 7], 0.f);
        pk.x = (unsigned)f2bf(f0) | ((unsigned)f2bf(f1) << 16);
        pk.y = (unsigned)f2bf(f2) | ((unsigned)f2bf(f3) << 16);
        pk.z = (unsigned)f2bf(f4) | ((unsigned)f2bf(f5) << 16);
        pk.w = (unsigned)f2bf(f6) | ((unsigned)f2bf(f7) << 16);
      } else {
        pk = raw;   // x already bf16, no BN on layer 0
      }
      *(uint4*)(As + ((ubase + m * 4) ^ swz)) = pk;
    }
  }
  __syncthreads();

  int w = tid >> 6, lane = tid & 63;
  int wrow = (w << 4) + (lane & 15);
  unsigned int aswz = (unsigned)((wrow & 7) << 2);
  floatx4 accT[8] = {}, accR[8] = {};

  #pragma unroll
  for (int ks = 0; ks < 4; ks++) {
    unsigned int aoff = (unsigned)(wrow * 64 + ks * 16 + ((lane >> 4) << 2)) ^ aswz;
    short8 a = *(const short8*)(As + aoff);
    #pragma unroll
    for (int cf = 0; cf < 8; cf++) {
      int wo = ((ks * 8 + cf) * 64 + lane) * 8;
      short8 wl = *(const short8*)(Wlp + wo);
      short8 wr = *(const short8*)(Wrp + wo);
      accT[cf] = __builtin_amdgcn_mfma_f32_16x16x32_bf16(a, wl, accT[cf], 0, 0, 0);
      accR[cf] = __builtin_amdgcn_mfma_f32_16x16x32_bf16(a, wr, accR[cf], 0, 0, 0);
    }
  }

  int colb = lane & 15;
  int rb = row0 + (w << 4) + ((lane >> 4) << 2);
  #pragma unroll
  for (int cf = 0; cf < 8; cf++) {
    int col = cf * 16 + colb;
    float bv = bias[col];
    #pragma unroll
    for (int i = 0; i < 4; i++) {
      int r = rb + i;
      if (r < n) {
        Tq[(size_t)r * 128 + col] = f2fp8(accT[cf][i] * T_SCALE);
        Rb[(size_t)r * 128 + col] = f2bf(accR[cf][i] + bv);
      }
    }
  }
}

// ---------------- aggregate: Hb[i] = bf16(Rb[i] + mean_{j in N(i)} T[j]); BN stats ----------------
// Node-PAIR per wave; T rows are fp8 (x16 scaled): 32 lanes x uint (4B) = 128B/row.
__global__ __launch_bounds__(256) void k_aggregate(
    const unsigned char* __restrict__ Tq, const unsigned short* __restrict__ Rb,
    unsigned short* __restrict__ Hb, const int* __restrict__ row_ptr,
    const int* __restrict__ csr, float* __restrict__ stats, int n) {
  __shared__ float sred[4][256];
  int tid = threadIdx.x;
  int lane = tid & 63;
  int half = lane >> 5;
  int sl = lane & 31;            // features sl*4 .. sl*4+3
  int wlocal = tid >> 6;
  int wid = (blockIdx.x * blockDim.x + tid) >> 6;
  int nw = (gridDim.x * blockDim.x) >> 6;
  float s0 = 0, s1 = 0, s2 = 0, s3 = 0, q0 = 0, q1 = 0, q2 = 0, q3 = 0;

  int i2 = 2 * wid;
  int step = 2 * nw;

  // ---- prologue ----
  int begA = 0, endA = 0, begB = 0, endB = 0;
  int idxA = 0, idxB = 0;
  uint2 rvA = make_uint2(0u, 0u), rvB = make_uint2(0u, 0u);
  if (i2 < n) {
    begA = row_ptr[i2]; endA = row_ptr[i2 + 1];
    if (i2 + 1 < n) { begB = endA; endB = row_ptr[i2 + 2]; }
    int cA = endA - begA; if (cA > 64) cA = 64;
    idxA = (lane < cA) ? csr[begA + lane] : 0;
    if (half == 0) rvA = *(const uint2*)(Rb + (size_t)i2 * 128 + sl * 4);
    if (i2 + 1 < n) {
      int cB = endB - begB; if (cB > 64) cB = 64;
      idxB = (lane < cB) ? csr[begB + lane] : 0;
      if (half == 0) rvB = *(const uint2*)(Rb + (size_t)(i2 + 1) * 128 + sl * 4);
    }
  }
  int j2 = i2 + step;
  int r0n = 0, r1n = 0, r2n = 0;
  if (j2 < n) {
    r0n = row_ptr[j2];
    r1n = row_ptr[j2 + 1];
    r2n = (j2 + 1 < n) ? row_ptr[j2 + 2] : r1n;
  }

  while (i2 < n) {
    int cA = endA - begA;
    int c0A = cA > 64 ? 64 : cA;
    bool hasB = (i2 + 1 < n);
    int cB = hasB ? (endB - begB) : 0;
    int c0B = cB > 64 ? 64 : cB;

    // 1) issue step-0 gathers for A then B (16 rows in flight)
    unsigned dA[8], dB[8];
    #pragma unroll
    for (int m = 0; m < 8; m++) {
      int ls = half + 2 * m;
      int j = __shfl(idxA, ls);
      dA[m] = (2 * m < c0A) ? *(const unsigned*)(Tq + (size_t)j * 128 + sl * 4) : 0u;
    }
    #pragma unroll
    for (int m = 0; m < 8; m++) {
      int ls = half + 2 * m;
      int j = __shfl(idxB, ls);
      dB[m] = (2 * m < c0B) ? *(const unsigned*)(Tq + (size_t)j * 128 + sl * 4) : 0u;
    }

    // 2) next-pair idx + rv prefetch
    int idxA2 = 0, idxB2 = 0;
    uint2 rvA2 = make_uint2(0u, 0u), rvB2 = make_uint2(0u, 0u);
    if (j2 < n) {
      int cA2 = r1n - r0n; if (cA2 > 64) cA2 = 64;
      idxA2 = (lane < cA2) ? csr[r0n + lane] : 0;
      if (half == 0) rvA2 = *(const uint2*)(Rb + (size_t)j2 * 128 + sl * 4);
      if (j2 + 1 < n) {
        int cB2 = r2n - r1n; if (cB2 > 64) cB2 = 64;
        idxB2 = (lane < cB2) ? csr[r1n + lane] : 0;
        if (half == 0) rvB2 = *(const uint2*)(Rb + (size_t)(j2 + 1) * 128 + sl * 4);
      }
    }
    // 3) rowptr prefetch for pair p+2
    int k2 = j2 + step;
    int r0nn = 0, r1nn = 0, r2nn = 0;
    if (k2 < n) {
      r0nn = row_ptr[k2];
      r1nn = row_ptr[k2 + 1];
      r2nn = (k2 + 1 < n) ? row_ptr[k2 + 2] : r1nn;
    }

    // 4) accumulate A (B's loads + prefetches still in flight)
    float a0 = 0, a1 = 0, a2 = 0, a3 = 0;
    #pragma unroll
    for (int m = 0; m < 8; m++) {
      int ls = half + 2 * m;
      if (ls < c0A) {
        floatx2 lo = __builtin_amdgcn_cvt_pk_f32_fp8(dA[m], false);
        floatx2 hi = __builtin_amdgcn_cvt_pk_f32_fp8(dA[m], true);
        a0 += lo.x; a1 += lo.y; a2 += hi.x; a3 += hi.y;
      }
    }
    for (int k = 16; k < c0A; k += 16) {
      #pragma unroll
      for (int m = 0; m < 8; m++) {
        int ls = k + half + 2 * m;
        int j = __shfl(idxA, ls);
        if (ls < c0A) {
          unsigned v = *(const unsigned*)(Tq + (size_t)j * 128 + sl * 4);
          floatx2 lo = __builtin_amdgcn_cvt_pk_f32_fp8(v, false);
          floatx2 hi = __builtin_amdgcn_cvt_pk_f32_fp8(v, true);
          a0 += lo.x; a1 += lo.y; a2 += hi.x; a3 += hi.y;
        }
      }
    }
    for (int base = begA + 64; base < endA; base += 64) {   // deg>64 (rare)
      int cnt = endA - base; if (cnt > 64) cnt = 64;
      int idx = (lane < cnt) ? csr[base + lane] : 0;
      for (int k = 0; k < cnt; k += 16) {
        #pragma unroll
        for (int m = 0; m < 8; m++) {
          int ls = k + half + 2 * m;
          int j = __shfl(idx, ls);
          if (ls < cnt) {
            unsigned v = *(const unsigned*)(Tq + (size_t)j * 128 + sl * 4);
            floatx2 lo = __builtin_amdgcn_cvt_pk_f32_fp8(v, false);
            floatx2 hi = __builtin_amdgcn_cvt_pk_f32_fp8(v, true);
            a0 += lo.x; a1 += lo.y; a2 += hi.x; a3 += hi.y;
          }
        }
      }
    }
    a0 += __shfl_xor(a0, 32);
    a1 += __shfl_xor(a1, 32);
    a2 += __shfl_xor(a2, 32);
    a3 += __shfl_xor(a3, 32);
    if (half == 0) {
      float inv = (cA > 0) ? (T_INV_SCALE / (float)cA) : 0.0f;
      float h0 = bflo(rvA.x) + a0 * inv;
      float h1 = bfhi(rvA.x) + a1 * inv;
      float h2 = bflo(rvA.y) + a2 * inv;
      float h3 = bfhi(rvA.y) + a3 * inv;
      uint2 pk;
      pk.x = (unsigned)f2bf(h0) | ((unsigned)f2bf(h1) << 16);
      pk.y = (unsigned)f2bf(h2) | ((unsigned)f2bf(h3) << 16);
      *(uint2*)(Hb + (size_t)i2 * 128 + sl * 4) = pk;
      s0 += h0; s1 += h1; s2 += h2; s3 += h3;
      q0 += h0 * h0; q1 += h1 * h1; q2 += h2 * h2; q3 += h3 * h3;
    }

    // 5) accumulate B
    if (hasB) {
      float b0 = 0, b1 = 0, b2 = 0, b3 = 0;
      #pragma unroll
      for (int m = 0; m < 8; m++) {
        int ls = half + 2 * m;
        if (ls < c0B) {
          floatx2 lo = __builtin_amdgcn_cvt_pk_f32_fp8(dB[m], false);
          floatx2 hi = __builtin_amdgcn_cvt_pk_f32_fp8(dB[m], true);
          b0 += lo.x; b1 += lo.y; b2 += hi.x; b3 += hi.y;
        }
      }
      for (int k = 16; k < c0B; k += 16) {
        #pragma unroll
        for (int m = 0; m < 8; m++) {
          int ls = k + half + 2 * m;
          int j = __shfl(idxB, ls);
          if (ls < c0B) {
            unsigned v = *(const unsigned*)(Tq + (size_t)j * 128 + sl * 4);
            floatx2 lo = __builtin_amdgcn_cvt_pk_f32_fp8(v, false);
            floatx2 hi = __builtin_amdgcn_cvt_pk_f32_fp8(v, true);
            b0 += lo.x; b1 += lo.y; b2 += hi.x; b3 += hi.y;
          }
        }
      }
      for (int base = begB + 64; base < endB; base += 64) {   // deg>64 (rare)
        int cnt = endB - base; if (cnt > 64) cnt = 64;
        int idx = (lane < cnt) ? csr[base + lane] : 0;
        for (int k = 0; k < cnt; k += 16) {
          #pragma unroll
          for (int m = 0; m < 8; m++) {
            int ls = k + half + 2 * m;
            int j = __shfl(idx, ls);
            if (ls < cnt) {
              unsigned v = *(const unsigned*)(Tq + (size_t)j * 128 + sl * 4);
              floatx2 lo = __builtin_amdgcn_cvt_pk_f32_fp8(v, false);
              floatx2 hi = __builtin_amdgcn_cvt_pk_f32_fp8(v, true);
              b0 += lo.x; b1 += lo.y; b2 += hi.x; b3 += hi.y;
            }
          }
        }
      }
      b0 += __shfl_xor(b0, 32);
      b1 += __shfl_xor(b1, 32);
      b2 += __shfl_xor(b2, 32);
      b3 += __shfl_xor(b3, 32);
      if (half == 0) {
        float inv = (cB > 0) ? (T_INV_SCALE / (float)cB) : 0.0f;
        float h0 = bflo(rvB.x) + b0 * inv;
        float h1 = bfhi(rvB.x) + b1 * inv;
        float h2 = bflo(rvB.y) + b2 * inv;
        float h3 = bfhi(rvB.y) + b3 * inv;
        uint2 pk;
        pk.x = (unsigned)f2bf(h0) | ((unsigned)f2bf(h1) << 16);
        pk.y = (unsigned)f2bf(h2) | ((unsigned)f2bf(h3) << 16);
        *(uint2*)(Hb + (size_t)(i2 + 1) * 128 + sl * 4) = pk;
        s0 += h0; s1 += h1; s2 += h2; s3 += h3;
        q0 += h0 * h0; q1 += h1 * h1; q2 += h2 * h2; q3 += h3 * h3;
      }
    }

    // 6) rotate pipeline state
    i2 += step;
    begA = r0n; endA = r1n; begB = r1n; endB = r2n;
    idxA = idxA2; idxB = idxB2; rvA = rvA2; rvB = rvB2;
    j2 = k2; r0n = r0nn; r1n = r1nn; r2n = r2nn;
  }

  if (half == 0) {
    sred[wlocal][sl * 8 + 0] = s0; sred[wlocal][sl * 8 + 1] = s1;
    sred[wlocal][sl * 8 + 2] = s2; sred[wlocal][sl * 8 + 3] = s3;
    sred[wlocal][sl * 8 + 4] = q0; sred[wlocal][sl * 8 + 5] = q1;
    sred[wlocal][sl * 8 + 6] = q2; sred[wlocal][sl * 8 + 7] = q3;
  }
  __syncthreads();
  float tot = sred[0][tid] + sred[1][tid] + sred[2][tid] + sred[3][tid];
  int slx = tid >> 3, k2f = tid & 7;
  int f = slx * 4 + (k2f & 3);
  int idx = (k2f >> 2) ? (128 + f) : f;
  atomicAdd(&stats[idx], tot);
}

// ---------------- final: Out = bn_relu(Hb) @ Wout + bout ----------------
__global__ __launch_bounds__(256) void k_gemm_out(
    const unsigned short* __restrict__ Hb, const float* __restrict__ W,
    const float* __restrict__ bias, const float* __restrict__ stats,
    const float* __restrict__ gamma, const float* __restrict__ beta,
    float* __restrict__ Out, int nrows) {
  __shared__ float As[64 * 132];
  __shared__ float sc[128], sh[128];
  int tid = threadIdx.x;
  if (tid < 128) {
    float invn = 1.0f / (float)nrows;
    float mu = stats[tid] * invn;
    float var = stats[128 + tid] * invn - mu * mu;
    float s = rsqrtf(var + BN_EPS) * gamma[tid];
    sc[tid] = s;
    sh[tid] = beta[tid] - mu * s;
  }
  __syncthreads();
  int row0 = blockIdx.x * 64;
  #pragma unroll
  for (int i = 0; i < 4; i++) {
    int g = tid + i * 256;
    int r = g >> 4;
    int c8 = g & 15;
    uint4 raw = make_uint4(0u, 0u, 0u, 0u);
    if (row0 + r < nrows)
      raw = *(const uint4*)(Hb + (size_t)(row0 + r) * 128 + c8 * 8);
    int c = c8 * 8;
    float* dstp = As + r * 132 + c;
    dstp[0] = fmaxf(bflo(raw.x) * sc[c + 0] + sh[c + 0], 0.f);
    dstp[1] = fmaxf(bfhi(raw.x) * sc[c + 1] + sh[c + 1], 0.f);
    dstp[2] = fmaxf(bflo(raw.y) * sc[c + 2] + sh[c + 2], 0.f);
    dstp[3] = fmaxf(bfhi(raw.y) * sc[c + 3] + sh[c + 3], 0.f);
    dstp[4] = fmaxf(bflo(raw.z) * sc[c + 4] + sh[c + 4], 0.f);
    dstp[5] = fmaxf(bfhi(raw.z) * sc[c + 5] + sh[c + 5], 0.f);
    dstp[6] = fmaxf(bflo(raw.w) * sc[c + 6] + sh[c + 6], 0.f);
    dstp[7] = fmaxf(bfhi(raw.w) * sc[c + 7] + sh[c + 7], 0.f);
  }
  __syncthreads();

  int cg = tid & 7;
  int rg = tid >> 3;
  float acc[2][4] = {};
  for (int k = 0; k < 128; k++) {
    float4 w = *(const float4*)(W + k * 32 + cg * 4);
    float a0 = As[(rg * 2 + 0) * 132 + k];
    float a1 = As[(rg * 2 + 1) * 132 + k];
    acc[0][0] += a0 * w.x; acc[0][1] += a0 * w.y; acc[0][2] += a0 * w.z; acc[0][3] += a0 * w.w;
    acc[1][0] += a1 * w.x; acc[1][1] += a1 * w.y; acc[1][2] += a1 * w.z; acc[1][3] += a1 * w.w;
  }
  float4 bv = *(const float4*)(bias + cg * 4);
  #pragma unroll
  for (int i = 0; i < 2; i++) {
    int r = row0 + rg * 2 + i;
    if (r < nrows) {
      float4 o = make_float4(acc[i][0] + bv.x, acc[i][1] + bv.y,
                             acc[i][2] + bv.z, acc[i][3] + bv.w);
      *(float4*)(Out + (size_t)r * 32 + cg * 4) = o;
    }
  }
}

extern "C" void kernel_launch(void* const* d_in, const int* in_sizes, int n_in,
                              void* d_out, int out_size, void* d_ws, size_t ws_size,
                              hipStream_t stream) {
  const float* x    = (const float*)d_in[0];
  const int*   e_sp = (const int*)d_in[1];
  const int*   e_tp = (const int*)d_in[2];
  const float* Wl[4]  = {(const float*)d_in[3],  (const float*)d_in[8],
                         (const float*)d_in[13], (const float*)d_in[18]};
  const float* Wr[4]  = {(const float*)d_in[4],  (const float*)d_in[9],
                         (const float*)d_in[14], (const float*)d_in[19]};
  const float* bb[4]  = {(const float*)d_in[5],  (const float*)d_in[10],
                         (const float*)d_in[15], (const float*)d_in[20]};
  const float* gm[4]  = {(const float*)d_in[6],  (const float*)d_in[11],
                         (const float*)d_in[16], (const float*)d_in[21]};
  const float* bt[4]  = {(const float*)d_in[7],  (const float*)d_in[12],
                         (const float*)d_in[17], (const float*)d_in[22]};
  const float* Wout = (const float*)d_in[23];
  const float* bout = (const float*)d_in[24];

  const int N = in_sizes[0] / 128;
  const int E = in_sizes[1] / 2;
  const int nbins = (N + ((1 << BSHIFT) - 1)) >> BSHIFT;   // 196 for N=100000

  char* ws = (char*)d_ws;
  size_t off = 0;
  auto alloc = [&](size_t bytes) {
    void* p = ws + off;
    off += (bytes + 255) & ~(size_t)255;
    return p;
  };
  unsigned short* Hb = (unsigned short*)alloc((size_t)N * 128 * 2);  // h (bf16)
  unsigned short* xb = (unsigned short*)alloc((size_t)N * 128 * 2);  // x (bf16)
  unsigned short* Rb = (unsigned short*)alloc((size_t)N * 128 * 2);  // r (bf16)
  unsigned char*  Tq = (unsigned char*)alloc((size_t)N * 128);       // t (fp8 e4m3, x16)
  int* row_sp    = (int*)alloc((size_t)(N + 1) * 4);
  int* row_tp    = (int*)alloc((size_t)(N + 1) * 4);
  int* csr_sp    = (int*)alloc((size_t)E * 4);
  int* csr_tp    = (int*)alloc((size_t)E * 4);
  unsigned int* binbuf = (unsigned int*)alloc((size_t)256 * BINCAP * 4);  // 10.5 MB
  int* binCount  = (int*)alloc(256 * 4);
  int* binBase   = (int*)alloc(257 * 4);
  float* statsB  = (float*)alloc(4 * 256 * 4);
  unsigned short* Wlp[4], *Wrp[4];
  for (int l = 0; l < 4; l++) {
    Wlp[l] = (unsigned short*)alloc(16384 * 2);
    Wrp[l] = (unsigned short*)alloc(16384 * 2);
  }

  const int pb = (E + 8191) / 8192;

  for (int l = 0; l < 4; l++) {
    k_wpack<<<64, 256, 0, stream>>>(Wl[l], Wlp[l]);
    k_wpack<<<64, 256, 0, stream>>>(Wr[l], Wrp[l]);
  }
  k_f2bf_arr<<<(int)(((size_t)N * 16 + 255) / 256), 256, 0, stream>>>(x, xb, (size_t)N * 16);
  hipMemsetAsync(statsB, 0, 4 * 256 * 4, stream);

  // ---- build CSR (spatial) ----
  hipMemsetAsync(binCount, 0, 256 * 4, stream);
  k_bin_pairs<<<pb, 1024, 0, stream>>>(e_sp, e_sp + E, binCount, binbuf, E, nbins);
  k_binscan<<<1, 256, 0, stream>>>(binCount, binBase, row_sp, nbins, N, E);
  k_csr_bin<<<nbins, 1024, 0, stream>>>(binbuf, binCount, binBase, row_sp, csr_sp, N);

  // ---- build CSR (temporal) ----
  hipMemsetAsync(binCount, 0, 256 * 4, stream);
  k_bin_pairs<<<pb, 1024, 0, stream>>>(e_tp, e_tp + E, binCount, binbuf, E, nbins);
  k_binscan<<<1, 256, 0, stream>>>(binCount, binBase, row_tp, nbins, N, E);
  k_csr_bin<<<nbins, 1024, 0, stream>>>(binbuf, binCount, binBase, row_tp, csr_tp, N);

  const int* rowp[4] = {row_sp, row_sp, row_tp, row_tp};
  const int* csr[4]  = {csr_sp, csr_sp, csr_tp, csr_tp};

  const int gblocks = (N + 63) / 64;
  const unsigned short* cur = xb;
  for (int l = 0; l < 4; l++) {
    const float* st = (l == 0) ? statsB : (statsB + (l - 1) * 256);
    const float* g  = (l == 0) ? gm[0] : gm[l - 1];
    const float* be = (l == 0) ? bt[0] : bt[l - 1];
    k_bn_gemm_dual<<<gblocks, 256, 0, stream>>>(cur, Wlp[l], Wrp[l], bb[l],
                                                st, g, be, Tq, Rb, N, l == 0 ? 0 : 1);
    k_aggregate<<<2048, 256, 0, stream>>>(Tq, Rb, Hb, rowp[l], csr[l],
                                          statsB + l * 256, N);
    cur = Hb;
  }
  k_gemm_out<<<gblocks, 256, 0, stream>>>(Hb, Wout, bout, statsB + 3 * 256,
                                          gm[3], bt[3], (float*)d_out, N);
}